// Round 5
// baseline (615.631 us; speedup 1.0000x reference)
//
#include <hip/hip_runtime.h>
#include <math.h>

#define NN 50000
#define EE 800000
#define ET (EE + NN)
#define HID 128
#define NSTORE 50
#define NBL 196                      // ceil(NN/256)
#define CVT_B 12500                  // NN*64/256
#define CNT_B 3125                   // EE/256
#define SCT_B 3321                   // ceil(ET/256)
#define SSB 64                       // store-sum partial blocks

typedef unsigned short ushort_t;
typedef unsigned long long u64;
typedef __attribute__((ext_vector_type(8))) short bf8;
typedef __attribute__((ext_vector_type(4))) float f4;
typedef __attribute__((ext_vector_type(4))) unsigned int u4;

__device__ __forceinline__ float b2f(ushort_t u) {
    union { unsigned int i; float f; } v; v.i = ((unsigned int)u) << 16; return v.f;
}
__device__ __forceinline__ ushort_t f2b(float f) {
    union { float f; unsigned int i; } v; v.f = f;
    unsigned int r = (v.i + 0x7fffu + ((v.i >> 16) & 1u)) >> 16;
    return (ushort_t)r;
}
__device__ __forceinline__ void b2f2(unsigned int u, float& lo, float& hi) {
    union { unsigned int i; float f; } a, c;
    a.i = u << 16; c.i = u & 0xffff0000u;
    lo = a.f; hi = c.f;
}
__device__ __forceinline__ unsigned int pk2(float lo, float hi) {
    return (unsigned int)f2b(lo) | ((unsigned int)f2b(hi) << 16);
}

// ---------------------------------------------------------------- build: bf16 cvt (BW) + edge count (latency), fused
// packed[dst]: bits 44+: degree count; bits 0..43: sum(ew) in 2^24 fixed point.
__global__ __launch_bounds__(256) void k_build(const float* __restrict__ x, const float* __restrict__ inW,
                                               const float* __restrict__ gWl, const float* __restrict__ gWr,
                                               const int* __restrict__ ei, const float* __restrict__ ew,
                                               ushort_t* __restrict__ xb, ushort_t* __restrict__ inWt,
                                               ushort_t* __restrict__ Wlt, ushort_t* __restrict__ Wrt,
                                               u64* __restrict__ packed, int* __restrict__ rank) {
    int b = blockIdx.x, t = threadIdx.x;
    if (b < CVT_B) {
        int i = b * 256 + t;
        xb[i] = f2b(x[i]);
        if (i < 128 * 64) {               // inWt[c*64+k] = inW[k*128+c]
            int c = i >> 6, k = i & 63;
            inWt[i] = f2b(inW[k * 128 + c]);
        }
        if (i < 3 * 128 * 128) {          // Wlt[l][n*128+k] = W[l][k*128+n]
            int l = i >> 14, r = i & 16383, nn2 = r >> 7, k = r & 127;
            Wlt[i] = f2b(gWl[(size_t)l * 16384 + k * 128 + nn2]);
            Wrt[i] = f2b(gWr[(size_t)l * 16384 + k * 128 + nn2]);
        }
    } else {
        int i = (b - CVT_B) * 256 + t;
        if (i < EE) {
            int dst = ei[EE + i];
            unsigned int wfix = __float2uint_rn(ew[i] * 16777216.0f);
            u64 old = atomicAdd(&packed[dst], (1ULL << 44) | (u64)wfix);
            rank[i] = (int)(old >> 44);
        }
    }
}

// per-256-chunk sums of (deg+1)
__global__ __launch_bounds__(256) void k_psum(const u64* __restrict__ packed, int* __restrict__ bsum) {
    int t = threadIdx.x, bidx = blockIdx.x;
    int i = bidx * 256 + t;
    int v = (i < NN) ? (int)(packed[i] >> 44) + 1 : 0;
#pragma unroll
    for (int d = 1; d < 64; d <<= 1) v += __shfl_xor(v, d);
    __shared__ int ws4[4];
    if ((t & 63) == 0) ws4[t >> 6] = v;
    __syncthreads();
    if (t == 0) bsum[bidx] = ws4[0] + ws4[1] + ws4[2] + ws4[3];
}

__global__ __launch_bounds__(256) void k_scanb(const int* __restrict__ bsum,
                                               int* __restrict__ bbase, int* __restrict__ offs) {
    __shared__ int s[256];
    int t = threadIdx.x;
    int v = (t < NBL) ? bsum[t] : 0;
    s[t] = v;
    __syncthreads();
    for (int d = 1; d < 256; d <<= 1) {
        int u = (t >= d) ? s[t - d] : 0;
        __syncthreads();
        s[t] += u;
        __syncthreads();
    }
    if (t < NBL) bbase[t] = s[t] - v;    // exclusive base
    if (t == 0) offs[NN] = ET;
}

__global__ __launch_bounds__(256) void k_offs(const u64* __restrict__ packed,
                                              const int* __restrict__ bbase, int* __restrict__ offs) {
    __shared__ int wsum4[4];
    int t = threadIdx.x, bidx = blockIdx.x;
    int i = bidx * 256 + t;
    int v = (i < NN) ? (int)(packed[i] >> 44) + 1 : 0;
    int lane = t & 63, w = t >> 6;
    int sc = v;
#pragma unroll
    for (int d = 1; d < 64; d <<= 1) {
        int u = __shfl_up(sc, d);
        if (lane >= d) sc += u;
    }
    if (lane == 63) wsum4[w] = sc;
    __syncthreads();
    int wo = 0;
    for (int k = 0; k < w; ++k) wo += wsum4[k];
    if (i < NN) offs[i] = bbase[bidx] + wo + sc - v;
}

// ---------------------------------------------------------------- scatter (no atomics, low VGPR, high occupancy)
__global__ __launch_bounds__(256) void k_scatter(const int* __restrict__ ei, const float* __restrict__ ew,
                                                 const int* __restrict__ offs, const u64* __restrict__ packed,
                                                 const int* __restrict__ rank, int2* __restrict__ csr) {
    int i = blockIdx.x * 256 + threadIdx.x;
    if (i < EE) {
        int src = ei[i], dst = ei[EE + i];
        int pos = offs[dst] + rank[i];
        int2 v; v.x = src; v.y = __float_as_int(ew[i]);
        csr[pos] = v;
    } else if (i < ET) {
        int nd = i - EE;
        u64 p = packed[nd];
        int deg = (int)(p >> 44);
        float wsf = (float)(p & ((1ULL << 44) - 1)) * (1.0f / 16777216.0f);
        float la = wsf / fmaxf((float)deg, 1.0f);
        int pos = offs[nd + 1] - 1;
        int2 v; v.x = nd; v.y = __float_as_int(la);
        csr[pos] = v;
    }
}

// ---------------------------------------------------------------- input proj: GELU + LN fused, K=64
__global__ __launch_bounds__(256) void k_inproj(const ushort_t* __restrict__ A,
                                                const ushort_t* __restrict__ Wt,
                                                const float* __restrict__ bias,
                                                const float* __restrict__ g,
                                                const float* __restrict__ be,
                                                float* __restrict__ h,
                                                ushort_t* __restrict__ hb) {
    const int K = 64;
    __shared__ float s1[2][128], s2[2][128];
    int lane = threadIdx.x & 63, w = threadIdx.x >> 6;
    int rw = w >> 1, cw = w & 1;
    int q = lane >> 4, l16 = lane & 15;
    int row0 = blockIdx.x * 128 + rw * 64;
    int col0 = cw * 64;
    bf8 z; for (int t = 0; t < 8; ++t) z[t] = 0;

    bf8 bfr[2][4];
#pragma unroll
    for (int kk = 0; kk < 2; ++kk)
#pragma unroll
        for (int j = 0; j < 4; ++j)
            bfr[kk][j] = *(const bf8*)(Wt + (size_t)(col0 + j * 16 + l16) * K + kk * 32 + q * 8);

    f4 acc[4][4];
#pragma unroll
    for (int i = 0; i < 4; ++i)
#pragma unroll
        for (int j = 0; j < 4; ++j) acc[i][j] = (f4)(0.f);

#pragma unroll
    for (int kk = 0; kk < 2; ++kk) {
        bf8 af[4];
#pragma unroll
        for (int i = 0; i < 4; ++i) {
            int r = row0 + i * 16 + l16;
            af[i] = (r < NN) ? *(const bf8*)(A + (size_t)r * K + kk * 32 + q * 8) : z;
        }
#pragma unroll
        for (int i = 0; i < 4; ++i)
#pragma unroll
            for (int j = 0; j < 4; ++j)
                acc[i][j] = __builtin_amdgcn_mfma_f32_16x16x32_bf16(af[i], bfr[kk][j], acc[i][j], 0, 0, 0);
    }
#pragma unroll
    for (int i = 0; i < 4; ++i) {
#pragma unroll
        for (int j = 0; j < 4; ++j) {
            float bv = bias[col0 + j * 16 + l16];
#pragma unroll
            for (int r = 0; r < 4; ++r) {
                float v = acc[i][j][r] + bv;
                v = 0.5f * v * (1.f + erff(v * 0.70710678118654752f));
                acc[i][j][r] = v;
            }
        }
    }
#pragma unroll
    for (int i = 0; i < 4; ++i) {
#pragma unroll
        for (int r = 0; r < 4; ++r) {
            float sm = acc[i][0][r] + acc[i][1][r] + acc[i][2][r] + acc[i][3][r];
            float sq = acc[i][0][r] * acc[i][0][r] + acc[i][1][r] * acc[i][1][r]
                     + acc[i][2][r] * acc[i][2][r] + acc[i][3][r] * acc[i][3][r];
#pragma unroll
            for (int k = 1; k < 16; k <<= 1) { sm += __shfl_xor(sm, k); sq += __shfl_xor(sq, k); }
            if (l16 == 0) {
                int rl = rw * 64 + i * 16 + q * 4 + r;
                s1[cw][rl] = sm; s2[cw][rl] = sq;
            }
        }
    }
    __syncthreads();
#pragma unroll
    for (int i = 0; i < 4; ++i) {
#pragma unroll
        for (int r = 0; r < 4; ++r) {
            int rl = rw * 64 + i * 16 + q * 4 + r;
            int gr = blockIdx.x * 128 + rl;
            if (gr >= NN) continue;
            float sm = s1[0][rl] + s1[1][rl];
            float sq = s2[0][rl] + s2[1][rl];
            float mu = sm * (1.f / 128.f);
            float var = sq * (1.f / 128.f) - mu * mu;
            float rinv = rsqrtf(var + 1e-5f);
#pragma unroll
            for (int j = 0; j < 4; ++j) {
                int gc = col0 + j * 16 + l16;
                float v = (acc[i][j][r] - mu) * rinv * g[gc] + be[gc];
                h[(size_t)gr * HID + gc] = v;
                hb[(size_t)gr * HID + gc] = f2b(v);
            }
        }
    }
}

// ---------------------------------------------------------------- bf16 MFMA dual GEMM (K=128)
__global__ __launch_bounds__(256) void k_gemm2(const ushort_t* __restrict__ A,
                                               const ushort_t* __restrict__ Wt0,
                                               const ushort_t* __restrict__ Wt1,
                                               const float* __restrict__ b0,
                                               const float* __restrict__ b1,
                                               ushort_t* __restrict__ o0,
                                               ushort_t* __restrict__ o1, int n) {
    const int K = 128;
    const ushort_t* Wt = blockIdx.y ? Wt1 : Wt0;
    const float* bias = blockIdx.y ? b1 : b0;
    ushort_t* outb = blockIdx.y ? o1 : o0;
    int lane = threadIdx.x & 63, w = threadIdx.x >> 6;
    int rw = w >> 1, cw = w & 1;
    int q = lane >> 4, l16 = lane & 15;
    int row0 = blockIdx.x * 128 + rw * 64;
    int col0 = cw * 64;
    bf8 z; for (int t = 0; t < 8; ++t) z[t] = 0;

    bf8 bfr[4][4];
#pragma unroll
    for (int kk = 0; kk < 4; ++kk)
#pragma unroll
        for (int j = 0; j < 4; ++j)
            bfr[kk][j] = *(const bf8*)(Wt + (size_t)(col0 + j * 16 + l16) * K + kk * 32 + q * 8);

    f4 acc[4][4];
#pragma unroll
    for (int i = 0; i < 4; ++i)
#pragma unroll
        for (int j = 0; j < 4; ++j) acc[i][j] = (f4)(0.f);

#pragma unroll
    for (int kk = 0; kk < 4; ++kk) {
        bf8 af[4];
#pragma unroll
        for (int i = 0; i < 4; ++i) {
            int r = row0 + i * 16 + l16;
            af[i] = (r < n) ? *(const bf8*)(A + (size_t)r * K + kk * 32 + q * 8) : z;
        }
#pragma unroll
        for (int i = 0; i < 4; ++i)
#pragma unroll
            for (int j = 0; j < 4; ++j)
                acc[i][j] = __builtin_amdgcn_mfma_f32_16x16x32_bf16(af[i], bfr[kk][j], acc[i][j], 0, 0, 0);
    }
#pragma unroll
    for (int i = 0; i < 4; ++i) {
        int gr0 = row0 + i * 16 + q * 4;
#pragma unroll
        for (int j = 0; j < 4; ++j) {
            int gc = col0 + j * 16 + l16;
            float bv = bias[gc];
#pragma unroll
            for (int r = 0; r < 4; ++r) {
                int gr = gr0 + r;
                if (gr < n) outb[(size_t)gr * HID + gc] = f2b(acc[i][j][r] + bv);
            }
        }
    }
}

// ---------------------------------------------------------------- GATv2 attention
// wave per dst node; 16 lanes = one edge (lane = head, DH=8 in-lane); 4 edges/step.
__global__ __launch_bounds__(256) void k_attn(const ushort_t* __restrict__ xl,
                                              const ushort_t* __restrict__ xr,
                                              float* __restrict__ h,
                                              ushort_t* __restrict__ hb,
                                              const int* __restrict__ offs,
                                              const int2* __restrict__ csr,
                                              const float* __restrict__ We,
                                              const float* __restrict__ att,
                                              const float* __restrict__ gbias,
                                              const float* __restrict__ g,
                                              const float* __restrict__ b) {
    int wid = (blockIdx.x * 256 + threadIdx.x) >> 6;
    int lane = threadIdx.x & 63;
    if (wid >= NN) return;
    int hd = lane & 15;          // head index (16 heads; DH=8 in-lane)
    int grp = lane >> 4;         // edge subgroup 0..3
    int dbase = hd * 8;
    size_t base = (size_t)wid * HID;

    float xr8[8], at8[8], we8[8];
    {
        u4 uxr = *(const u4*)(xr + base + dbase);
        b2f2(uxr.x, xr8[0], xr8[1]); b2f2(uxr.y, xr8[2], xr8[3]);
        b2f2(uxr.z, xr8[4], xr8[5]); b2f2(uxr.w, xr8[6], xr8[7]);
        f4 a0 = *(const f4*)(att + dbase), a1 = *(const f4*)(att + dbase + 4);
        at8[0] = a0.x; at8[1] = a0.y; at8[2] = a0.z; at8[3] = a0.w;
        at8[4] = a1.x; at8[5] = a1.y; at8[6] = a1.z; at8[7] = a1.w;
        f4 w0 = *(const f4*)(We + dbase), w1 = *(const f4*)(We + dbase + 4);
        we8[0] = w0.x; we8[1] = w0.y; we8[2] = w0.z; we8[3] = w0.w;
        we8[4] = w1.x; we8[5] = w1.y; we8[6] = w1.z; we8[7] = w1.w;
    }
    int p0 = offs[wid], p1 = offs[wid + 1];
    float Z = 0.f;
    float acc[8];
#pragma unroll
    for (int q = 0; q < 8; ++q) acc[q] = 0.f;

#define QUAD(EJ, MASKED)                                                        \
    {                                                                           \
        int ei_ = (EJ) + grp;                                                   \
        int s_ = __shfl(sv, ei_);                                               \
        float ea_ = __shfl(evl, ei_);                                           \
        bool val_ = MASKED ? (ei_ < mm) : true;                                 \
        u4 ux_ = *(const u4*)(xl + (size_t)s_ * HID + dbase);                   \
        float x_[8];                                                            \
        b2f2(ux_.x, x_[0], x_[1]); b2f2(ux_.y, x_[2], x_[3]);                   \
        b2f2(ux_.z, x_[4], x_[5]); b2f2(ux_.w, x_[6], x_[7]);                   \
        float lg_ = 0.f;                                                        \
        _Pragma("unroll")                                                       \
        for (int q_ = 0; q_ < 8; ++q_) {                                        \
            float t_ = x_[q_] + xr8[q_] + ea_ * we8[q_];                        \
            t_ = (t_ > 0.f) ? t_ : 0.2f * t_;                                   \
            lg_ = fmaf(at8[q_], t_, lg_);                                       \
        }                                                                       \
        float w_ = val_ ? __expf(lg_) : 0.f;                                    \
        Z += w_;                                                                \
        _Pragma("unroll")                                                       \
        for (int q_ = 0; q_ < 8; ++q_) acc[q_] = fmaf(w_, x_[q_], acc[q_]);     \
    }

    for (int cb = p0; cb < p1; cb += 64) {
        int mm = min(64, p1 - cb);
        int2 m2 = (lane < mm) ? csr[cb + lane] : make_int2(0, 0);
        int sv = m2.x;
        float evl = __int_as_float(m2.y);
        int j = 0;
        for (; j + 8 <= mm; j += 8) { QUAD(j, false) QUAD(j + 4, false) }
        for (; j < mm; j += 4) QUAD(j, true)
    }
#undef QUAD

    // combine the 4 edge subgroups
    Z += __shfl_xor(Z, 16); Z += __shfl_xor(Z, 32);
#pragma unroll
    for (int q = 0; q < 8; ++q) {
        acc[q] += __shfl_xor(acc[q], 16);
        acc[q] += __shfl_xor(acc[q], 32);
    }
    float inv = 1.f / (Z + 1e-16f);

    // residual + LN over the 128 dims held by the 16 head-lanes
    f4 hv0 = *(const f4*)(h + base + dbase);
    f4 hv1 = *(const f4*)(h + base + dbase + 4);
    float hres[8] = {hv0.x, hv0.y, hv0.z, hv0.w, hv1.x, hv1.y, hv1.z, hv1.w};
    f4 gb0 = *(const f4*)(gbias + dbase), gb1 = *(const f4*)(gbias + dbase + 4);
    float gb8[8] = {gb0.x, gb0.y, gb0.z, gb0.w, gb1.x, gb1.y, gb1.z, gb1.w};
    float o[8], sm = 0.f, sq = 0.f;
#pragma unroll
    for (int q = 0; q < 8; ++q) {
        o[q] = acc[q] * inv + gb8[q] + hres[q];
        sm += o[q]; sq += o[q] * o[q];
    }
#pragma unroll
    for (int k = 1; k < 16; k <<= 1) { sm += __shfl_xor(sm, k); sq += __shfl_xor(sq, k); }
    float mu = sm * (1.f / 128.f);
    float var = sq * (1.f / 128.f) - mu * mu;
    float rinv = rsqrtf(var + 1e-5f);
    f4 g0 = *(const f4*)(g + dbase), g1 = *(const f4*)(g + dbase + 4);
    float g8[8] = {g0.x, g0.y, g0.z, g0.w, g1.x, g1.y, g1.z, g1.w};
    f4 b0 = *(const f4*)(b + dbase), b1 = *(const f4*)(b + dbase + 4);
    float b8[8] = {b0.x, b0.y, b0.z, b0.w, b1.x, b1.y, b1.z, b1.w};
    float v8[8];
#pragma unroll
    for (int q = 0; q < 8; ++q) v8[q] = (o[q] - mu) * rinv * g8[q] + b8[q];
    if (grp == 0) {
        f4 s0 = {v8[0], v8[1], v8[2], v8[3]};
        f4 s1 = {v8[4], v8[5], v8[6], v8[7]};
        *(f4*)(h + base + dbase) = s0;
        *(f4*)(h + base + dbase + 4) = s1;
        u4 hu;
        hu.x = pk2(v8[0], v8[1]); hu.y = pk2(v8[2], v8[3]);
        hu.z = pk2(v8[4], v8[5]); hu.w = pk2(v8[6], v8[7]);
        *(u4*)(hb + base + dbase) = hu;
    }
}

// ---------------------------------------------------------------- per-store partial sums (no global atomics)
__global__ __launch_bounds__(256) void k_store_sum(const float* __restrict__ h,
                                                   const int* __restrict__ mask,
                                                   float* __restrict__ psums,   // [SSB][NSTORE*HID]
                                                   int* __restrict__ pcnts) {   // [SSB][NSTORE]
    __shared__ float ls[NSTORE * HID];
    __shared__ int lc[NSTORE];
    int t = threadIdx.x, bidx = blockIdx.x;
    for (int i = t; i < NSTORE * HID; i += 256) ls[i] = 0.f;
    if (t < NSTORE) lc[t] = 0;
    __syncthreads();
    int wid = bidx * 4 + (t >> 6);
    int lane = t & 63;
    int nw = SSB * 4;
    int d0 = lane * 2, d1 = d0 + 1;
    for (int node = wid; node < NN; node += nw) {
        int s = mask[node];
        size_t base = (size_t)node * HID;
        atomicAdd(&ls[s * HID + d0], h[base + d0]);
        atomicAdd(&ls[s * HID + d1], h[base + d1]);
        if (lane == 0) atomicAdd(&lc[s], 1);
    }
    __syncthreads();
    for (int i = t; i < NSTORE * HID; i += 256) psums[(size_t)bidx * (NSTORE * HID) + i] = ls[i];
    if (t < NSTORE) pcnts[bidx * NSTORE + t] = lc[t];
}

// ---------------------------------------------------------------- gate (reduces partials)
__global__ __launch_bounds__(128) void k_gate(const float* __restrict__ psums,
                                              const int* __restrict__ pcnts,
                                              const float* __restrict__ ctxW,
                                              const float* __restrict__ ctxb,
                                              float* __restrict__ gm) {
    __shared__ float mloc[HID];
    __shared__ float csh;
    int s = blockIdx.x, t = threadIdx.x;
    float sum = 0.f;
    for (int b = 0; b < SSB; ++b) sum += psums[(size_t)b * (NSTORE * HID) + s * HID + t];
    if (t == 0) {
        int c = 0;
        for (int b = 0; b < SSB; ++b) c += pcnts[b * NSTORE + s];
        csh = fmaxf((float)c, 1.f);
    }
    __syncthreads();
    float mk = sum / csh;
    mloc[t] = mk;
    __syncthreads();
    float acc = ctxb[t];
    for (int j = 0; j < HID; ++j) acc += mloc[j] * ctxW[j * HID + t];
    float gate = 1.f / (1.f + __expf(-acc));
    gm[s * HID + t] = gate * mk;
}

// ---------------------------------------------------------------- final: out = LN(h + gm[store])
__global__ __launch_bounds__(256) void k_final(const float* __restrict__ h,
                                               const int* __restrict__ mask,
                                               const float* __restrict__ gm,
                                               const float* __restrict__ g,
                                               const float* __restrict__ b,
                                               float* __restrict__ out) {
    int wid = (blockIdx.x * 256 + threadIdx.x) >> 6;
    int lane = threadIdx.x & 63;
    if (wid >= NN) return;
    size_t base = (size_t)wid * HID;
    int s = mask[wid];
    int d0 = lane * 2, d1 = d0 + 1;
    float v0 = h[base + d0] + gm[s * HID + d0];
    float v1 = h[base + d1] + gm[s * HID + d1];
    float sm = v0 + v1, sq = v0 * v0 + v1 * v1;
#pragma unroll
    for (int k = 1; k < 64; k <<= 1) { sm += __shfl_xor(sm, k); sq += __shfl_xor(sq, k); }
    float mu = sm * (1.f / 128.f);
    float var = sq * (1.f / 128.f) - mu * mu;
    float r = rsqrtf(var + 1e-5f);
    out[base + d0] = (v0 - mu) * r * g[d0] + b[d0];
    out[base + d1] = (v1 - mu) * r * g[d1] + b[d1];
}

// ---------------------------------------------------------------- launch
extern "C" void kernel_launch(void* const* d_in, const int* in_sizes, int n_in,
                              void* d_out, int out_size, void* d_ws, size_t ws_size,
                              hipStream_t stream) {
    const float* x      = (const float*)d_in[0];
    const int*   ei     = (const int*)d_in[1];
    const float* ew     = (const float*)d_in[2];
    const int*   smask  = (const int*)d_in[3];
    const float* inW    = (const float*)d_in[4];
    const float* inb    = (const float*)d_in[5];
    const float* ing    = (const float*)d_in[6];
    const float* inbeta = (const float*)d_in[7];
    const float* gWl    = (const float*)d_in[8];
    const float* gbl    = (const float*)d_in[9];
    const float* gWr    = (const float*)d_in[10];
    const float* gbr    = (const float*)d_in[11];
    const float* gWe    = (const float*)d_in[12];
    const float* gatt   = (const float*)d_in[13];
    const float* gbias  = (const float*)d_in[14];
    const float* blkg   = (const float*)d_in[15];
    const float* blkb   = (const float*)d_in[16];
    const float* ctxW   = (const float*)d_in[17];
    const float* ctxb   = (const float*)d_in[18];
    const float* fing   = (const float*)d_in[19];
    const float* finb   = (const float*)d_in[20];
    float* out = (float*)d_out;

    float* ws = (float*)d_ws;
    size_t o = 0;
    float*    h      = ws + o;              o += (size_t)NN * HID;
    int2*     csr    = (int2*)(ws + o);     o += (size_t)ET * 2;
    float*    gm     = ws + o;              o += NSTORE * HID;
    int*      offs   = (int*)(ws + o);      o += 50004;
    int*      rank   = (int*)(ws + o);      o += EE;
    ushort_t* xb     = (ushort_t*)(ws + o); o += (size_t)NN * 64 / 2;
    ushort_t* hb     = (ushort_t*)(ws + o); o += (size_t)NN * HID / 2;
    ushort_t* xlb    = (ushort_t*)(ws + o); o += (size_t)NN * HID / 2;
    ushort_t* xrb    = (ushort_t*)(ws + o); o += (size_t)NN * HID / 2;
    ushort_t* inWt   = (ushort_t*)(ws + o); o += 128 * 64 / 2;
    ushort_t* Wlt    = (ushort_t*)(ws + o); o += 3 * 128 * 128 / 2;
    ushort_t* Wrt    = (ushort_t*)(ws + o); o += 3 * 128 * 128 / 2;
    int*      bsum   = (int*)(ws + o);      o += 256;
    int*      bbase  = (int*)(ws + o);      o += 256;
    float*    psums  = ws + o;              o += (size_t)SSB * NSTORE * HID;
    int*      pcnts  = (int*)(ws + o);      o += SSB * NSTORE;
    // zero-init region (single memset); packed must be 8B-aligned (o is even here)
    if (o & 1) ++o;
    float*    zbase  = ws + o;
    u64*      packed = (u64*)(ws + o);      o += (size_t)NN * 2;
    size_t zbytes = (size_t)(NN * 2) * 4;

    hipMemsetAsync((void*)zbase, 0, zbytes, stream);

    const int WB = NN / 4;                    // wave-per-node kernels
    const int GB = (NN + 127) / 128;          // 128-row GEMM tiles

    k_build<<<CVT_B + CNT_B, 256, 0, stream>>>(x, inW, gWl, gWr, ei, ew,
                                               xb, inWt, Wlt, Wrt, packed, rank);
    k_psum<<<NBL, 256, 0, stream>>>(packed, bsum);
    k_scanb<<<1, 256, 0, stream>>>(bsum, bbase, offs);
    k_offs<<<NBL, 256, 0, stream>>>(packed, bbase, offs);
    k_scatter<<<SCT_B, 256, 0, stream>>>(ei, ew, offs, packed, rank, csr);
    k_inproj<<<GB, 256, 0, stream>>>(xb, inWt, inb, ing, inbeta, h, hb);

    for (int l = 0; l < 3; ++l) {
        dim3 gg(GB, 2);
        k_gemm2<<<gg, 256, 0, stream>>>(hb, Wlt + (size_t)l * HID * HID, Wrt + (size_t)l * HID * HID,
                                        gbl + l * HID, gbr + l * HID, xlb, xrb, NN);
        k_attn<<<WB, 256, 0, stream>>>(xlb, xrb, h, hb, offs, csr,
                                       gWe + l * HID, gatt + l * HID, gbias + l * HID,
                                       blkg + l * HID, blkb + l * HID);
    }

    k_store_sum<<<SSB, 256, 0, stream>>>(h, smask, psums, pcnts);
    k_gate<<<NSTORE, 128, 0, stream>>>(psums, pcnts, ctxW, ctxb, gm);
    k_final<<<WB, 256, 0, stream>>>(h, smask, gm, fing, finb, out);
}

// Round 6
// 604.942 us; speedup vs baseline: 1.0177x; 1.0177x over previous
//
#include <hip/hip_runtime.h>
#include <math.h>

#define NN 50000
#define EE 800000
#define ET (EE + NN)
#define HID 128
#define NSTORE 50
#define NBL 196                      // ceil(NN/256)
#define CVT_B 12500                  // NN*64/256
#define CNT_B 3125                   // EE/256
#define SCT_B 3321                   // ceil(ET/256)
#define SSB 512                      // store-sum partial blocks (2 blocks/CU)

typedef unsigned short ushort_t;
typedef unsigned long long u64;
typedef __attribute__((ext_vector_type(8))) short bf8;
typedef __attribute__((ext_vector_type(4))) float f4;
typedef __attribute__((ext_vector_type(4))) unsigned int u4;

__device__ __forceinline__ float b2f(ushort_t u) {
    union { unsigned int i; float f; } v; v.i = ((unsigned int)u) << 16; return v.f;
}
__device__ __forceinline__ ushort_t f2b(float f) {
    union { float f; unsigned int i; } v; v.f = f;
    unsigned int r = (v.i + 0x7fffu + ((v.i >> 16) & 1u)) >> 16;
    return (ushort_t)r;
}
__device__ __forceinline__ void b2f2(unsigned int u, float& lo, float& hi) {
    union { unsigned int i; float f; } a, c;
    a.i = u << 16; c.i = u & 0xffff0000u;
    lo = a.f; hi = c.f;
}
__device__ __forceinline__ unsigned int pk2(float lo, float hi) {
    return (unsigned int)f2b(lo) | ((unsigned int)f2b(hi) << 16);
}

// ---------------------------------------------------------------- build: bf16 cvt (BW) + edge count (latency), fused
// packed[dst]: bits 44+: degree count; bits 0..43: sum(ew) in 2^24 fixed point.
__global__ __launch_bounds__(256) void k_build(const float* __restrict__ x, const float* __restrict__ inW,
                                               const float* __restrict__ gWl, const float* __restrict__ gWr,
                                               const int* __restrict__ ei, const float* __restrict__ ew,
                                               ushort_t* __restrict__ xb, ushort_t* __restrict__ inWt,
                                               ushort_t* __restrict__ Wlt, ushort_t* __restrict__ Wrt,
                                               u64* __restrict__ packed, int* __restrict__ rank) {
    int b = blockIdx.x, t = threadIdx.x;
    if (b < CVT_B) {
        int i = b * 256 + t;
        xb[i] = f2b(x[i]);
        if (i < 128 * 64) {               // inWt[c*64+k] = inW[k*128+c]
            int c = i >> 6, k = i & 63;
            inWt[i] = f2b(inW[k * 128 + c]);
        }
        if (i < 3 * 128 * 128) {          // Wlt[l][n*128+k] = W[l][k*128+n]
            int l = i >> 14, r = i & 16383, nn2 = r >> 7, k = r & 127;
            Wlt[i] = f2b(gWl[(size_t)l * 16384 + k * 128 + nn2]);
            Wrt[i] = f2b(gWr[(size_t)l * 16384 + k * 128 + nn2]);
        }
    } else {
        int i = (b - CVT_B) * 256 + t;
        if (i < EE) {
            int dst = ei[EE + i];
            unsigned int wfix = __float2uint_rn(ew[i] * 16777216.0f);
            u64 old = atomicAdd(&packed[dst], (1ULL << 44) | (u64)wfix);
            rank[i] = (int)(old >> 44);
        }
    }
}

// per-256-chunk sums of (deg+1)
__global__ __launch_bounds__(256) void k_psum(const u64* __restrict__ packed, int* __restrict__ bsum) {
    int t = threadIdx.x, bidx = blockIdx.x;
    int i = bidx * 256 + t;
    int v = (i < NN) ? (int)(packed[i] >> 44) + 1 : 0;
#pragma unroll
    for (int d = 1; d < 64; d <<= 1) v += __shfl_xor(v, d);
    __shared__ int ws4[4];
    if ((t & 63) == 0) ws4[t >> 6] = v;
    __syncthreads();
    if (t == 0) bsum[bidx] = ws4[0] + ws4[1] + ws4[2] + ws4[3];
}

__global__ __launch_bounds__(256) void k_scanb(const int* __restrict__ bsum,
                                               int* __restrict__ bbase, int* __restrict__ offs) {
    __shared__ int s[256];
    int t = threadIdx.x;
    int v = (t < NBL) ? bsum[t] : 0;
    s[t] = v;
    __syncthreads();
    for (int d = 1; d < 256; d <<= 1) {
        int u = (t >= d) ? s[t - d] : 0;
        __syncthreads();
        s[t] += u;
        __syncthreads();
    }
    if (t < NBL) bbase[t] = s[t] - v;    // exclusive base
    if (t == 0) offs[NN] = ET;
}

__global__ __launch_bounds__(256) void k_offs(const u64* __restrict__ packed,
                                              const int* __restrict__ bbase, int* __restrict__ offs) {
    __shared__ int wsum4[4];
    int t = threadIdx.x, bidx = blockIdx.x;
    int i = bidx * 256 + t;
    int v = (i < NN) ? (int)(packed[i] >> 44) + 1 : 0;
    int lane = t & 63, w = t >> 6;
    int sc = v;
#pragma unroll
    for (int d = 1; d < 64; d <<= 1) {
        int u = __shfl_up(sc, d);
        if (lane >= d) sc += u;
    }
    if (lane == 63) wsum4[w] = sc;
    __syncthreads();
    int wo = 0;
    for (int k = 0; k < w; ++k) wo += wsum4[k];
    if (i < NN) offs[i] = bbase[bidx] + wo + sc - v;
}

// ---------------------------------------------------------------- scatter (no atomics, low VGPR, high occupancy)
__global__ __launch_bounds__(256) void k_scatter(const int* __restrict__ ei, const float* __restrict__ ew,
                                                 const int* __restrict__ offs, const u64* __restrict__ packed,
                                                 const int* __restrict__ rank, int2* __restrict__ csr) {
    int i = blockIdx.x * 256 + threadIdx.x;
    if (i < EE) {
        int src = ei[i], dst = ei[EE + i];
        int pos = offs[dst] + rank[i];
        int2 v; v.x = src; v.y = __float_as_int(ew[i]);
        csr[pos] = v;
    } else if (i < ET) {
        int nd = i - EE;
        u64 p = packed[nd];
        int deg = (int)(p >> 44);
        float wsf = (float)(p & ((1ULL << 44) - 1)) * (1.0f / 16777216.0f);
        float la = wsf / fmaxf((float)deg, 1.0f);
        int pos = offs[nd + 1] - 1;
        int2 v; v.x = nd; v.y = __float_as_int(la);
        csr[pos] = v;
    }
}

// ---------------------------------------------------------------- input proj: GELU + LN fused, K=64
__global__ __launch_bounds__(256) void k_inproj(const ushort_t* __restrict__ A,
                                                const ushort_t* __restrict__ Wt,
                                                const float* __restrict__ bias,
                                                const float* __restrict__ g,
                                                const float* __restrict__ be,
                                                float* __restrict__ h,
                                                ushort_t* __restrict__ hb) {
    const int K = 64;
    __shared__ float s1[2][128], s2[2][128];
    int lane = threadIdx.x & 63, w = threadIdx.x >> 6;
    int rw = w >> 1, cw = w & 1;
    int q = lane >> 4, l16 = lane & 15;
    int row0 = blockIdx.x * 128 + rw * 64;
    int col0 = cw * 64;
    bf8 z; for (int t = 0; t < 8; ++t) z[t] = 0;

    bf8 bfr[2][4];
#pragma unroll
    for (int kk = 0; kk < 2; ++kk)
#pragma unroll
        for (int j = 0; j < 4; ++j)
            bfr[kk][j] = *(const bf8*)(Wt + (size_t)(col0 + j * 16 + l16) * K + kk * 32 + q * 8);

    f4 acc[4][4];
#pragma unroll
    for (int i = 0; i < 4; ++i)
#pragma unroll
        for (int j = 0; j < 4; ++j) acc[i][j] = (f4)(0.f);

#pragma unroll
    for (int kk = 0; kk < 2; ++kk) {
        bf8 af[4];
#pragma unroll
        for (int i = 0; i < 4; ++i) {
            int r = row0 + i * 16 + l16;
            af[i] = (r < NN) ? *(const bf8*)(A + (size_t)r * K + kk * 32 + q * 8) : z;
        }
#pragma unroll
        for (int i = 0; i < 4; ++i)
#pragma unroll
            for (int j = 0; j < 4; ++j)
                acc[i][j] = __builtin_amdgcn_mfma_f32_16x16x32_bf16(af[i], bfr[kk][j], acc[i][j], 0, 0, 0);
    }
#pragma unroll
    for (int i = 0; i < 4; ++i) {
#pragma unroll
        for (int j = 0; j < 4; ++j) {
            float bv = bias[col0 + j * 16 + l16];
#pragma unroll
            for (int r = 0; r < 4; ++r) {
                float v = acc[i][j][r] + bv;
                v = 0.5f * v * (1.f + erff(v * 0.70710678118654752f));
                acc[i][j][r] = v;
            }
        }
    }
#pragma unroll
    for (int i = 0; i < 4; ++i) {
#pragma unroll
        for (int r = 0; r < 4; ++r) {
            float sm = acc[i][0][r] + acc[i][1][r] + acc[i][2][r] + acc[i][3][r];
            float sq = acc[i][0][r] * acc[i][0][r] + acc[i][1][r] * acc[i][1][r]
                     + acc[i][2][r] * acc[i][2][r] + acc[i][3][r] * acc[i][3][r];
#pragma unroll
            for (int k = 1; k < 16; k <<= 1) { sm += __shfl_xor(sm, k); sq += __shfl_xor(sq, k); }
            if (l16 == 0) {
                int rl = rw * 64 + i * 16 + q * 4 + r;
                s1[cw][rl] = sm; s2[cw][rl] = sq;
            }
        }
    }
    __syncthreads();
#pragma unroll
    for (int i = 0; i < 4; ++i) {
#pragma unroll
        for (int r = 0; r < 4; ++r) {
            int rl = rw * 64 + i * 16 + q * 4 + r;
            int gr = blockIdx.x * 128 + rl;
            if (gr >= NN) continue;
            float sm = s1[0][rl] + s1[1][rl];
            float sq = s2[0][rl] + s2[1][rl];
            float mu = sm * (1.f / 128.f);
            float var = sq * (1.f / 128.f) - mu * mu;
            float rinv = rsqrtf(var + 1e-5f);
#pragma unroll
            for (int j = 0; j < 4; ++j) {
                int gc = col0 + j * 16 + l16;
                float v = (acc[i][j][r] - mu) * rinv * g[gc] + be[gc];
                h[(size_t)gr * HID + gc] = v;
                hb[(size_t)gr * HID + gc] = f2b(v);
            }
        }
    }
}

// ---------------------------------------------------------------- bf16 MFMA dual GEMM (K=128)
__global__ __launch_bounds__(256) void k_gemm2(const ushort_t* __restrict__ A,
                                               const ushort_t* __restrict__ Wt0,
                                               const ushort_t* __restrict__ Wt1,
                                               const float* __restrict__ b0,
                                               const float* __restrict__ b1,
                                               ushort_t* __restrict__ o0,
                                               ushort_t* __restrict__ o1, int n) {
    const int K = 128;
    const ushort_t* Wt = blockIdx.y ? Wt1 : Wt0;
    const float* bias = blockIdx.y ? b1 : b0;
    ushort_t* outb = blockIdx.y ? o1 : o0;
    int lane = threadIdx.x & 63, w = threadIdx.x >> 6;
    int rw = w >> 1, cw = w & 1;
    int q = lane >> 4, l16 = lane & 15;
    int row0 = blockIdx.x * 128 + rw * 64;
    int col0 = cw * 64;
    bf8 z; for (int t = 0; t < 8; ++t) z[t] = 0;

    bf8 bfr[4][4];
#pragma unroll
    for (int kk = 0; kk < 4; ++kk)
#pragma unroll
        for (int j = 0; j < 4; ++j)
            bfr[kk][j] = *(const bf8*)(Wt + (size_t)(col0 + j * 16 + l16) * K + kk * 32 + q * 8);

    f4 acc[4][4];
#pragma unroll
    for (int i = 0; i < 4; ++i)
#pragma unroll
        for (int j = 0; j < 4; ++j) acc[i][j] = (f4)(0.f);

#pragma unroll
    for (int kk = 0; kk < 4; ++kk) {
        bf8 af[4];
#pragma unroll
        for (int i = 0; i < 4; ++i) {
            int r = row0 + i * 16 + l16;
            af[i] = (r < n) ? *(const bf8*)(A + (size_t)r * K + kk * 32 + q * 8) : z;
        }
#pragma unroll
        for (int i = 0; i < 4; ++i)
#pragma unroll
            for (int j = 0; j < 4; ++j)
                acc[i][j] = __builtin_amdgcn_mfma_f32_16x16x32_bf16(af[i], bfr[kk][j], acc[i][j], 0, 0, 0);
    }
#pragma unroll
    for (int i = 0; i < 4; ++i) {
        int gr0 = row0 + i * 16 + q * 4;
#pragma unroll
        for (int j = 0; j < 4; ++j) {
            int gc = col0 + j * 16 + l16;
            float bv = bias[gc];
#pragma unroll
            for (int r = 0; r < 4; ++r) {
                int gr = gr0 + r;
                if (gr < n) outb[(size_t)gr * HID + gc] = f2b(acc[i][j][r] + bv);
            }
        }
    }
}

// ---------------------------------------------------------------- GATv2 attention
// wave per dst node; 16 lanes = one edge (lane = head, DH=8 in-lane); 4 edges/step.
__global__ __launch_bounds__(256) void k_attn(const ushort_t* __restrict__ xl,
                                              const ushort_t* __restrict__ xr,
                                              float* __restrict__ h,
                                              ushort_t* __restrict__ hb,
                                              const int* __restrict__ offs,
                                              const int2* __restrict__ csr,
                                              const float* __restrict__ We,
                                              const float* __restrict__ att,
                                              const float* __restrict__ gbias,
                                              const float* __restrict__ g,
                                              const float* __restrict__ b) {
    int wid = (blockIdx.x * 256 + threadIdx.x) >> 6;
    int lane = threadIdx.x & 63;
    if (wid >= NN) return;
    int hd = lane & 15;          // head index (16 heads; DH=8 in-lane)
    int grp = lane >> 4;         // edge subgroup 0..3
    int dbase = hd * 8;
    size_t base = (size_t)wid * HID;

    float xr8[8], at8[8], we8[8];
    {
        u4 uxr = *(const u4*)(xr + base + dbase);
        b2f2(uxr.x, xr8[0], xr8[1]); b2f2(uxr.y, xr8[2], xr8[3]);
        b2f2(uxr.z, xr8[4], xr8[5]); b2f2(uxr.w, xr8[6], xr8[7]);
        f4 a0 = *(const f4*)(att + dbase), a1 = *(const f4*)(att + dbase + 4);
        at8[0] = a0.x; at8[1] = a0.y; at8[2] = a0.z; at8[3] = a0.w;
        at8[4] = a1.x; at8[5] = a1.y; at8[6] = a1.z; at8[7] = a1.w;
        f4 w0 = *(const f4*)(We + dbase), w1 = *(const f4*)(We + dbase + 4);
        we8[0] = w0.x; we8[1] = w0.y; we8[2] = w0.z; we8[3] = w0.w;
        we8[4] = w1.x; we8[5] = w1.y; we8[6] = w1.z; we8[7] = w1.w;
    }
    int p0 = offs[wid], p1 = offs[wid + 1];
    float Z = 0.f;
    float acc[8];
#pragma unroll
    for (int q = 0; q < 8; ++q) acc[q] = 0.f;

#define QUAD(EJ, MASKED)                                                        \
    {                                                                           \
        int ei_ = (EJ) + grp;                                                   \
        int s_ = __shfl(sv, ei_);                                               \
        float ea_ = __shfl(evl, ei_);                                           \
        bool val_ = MASKED ? (ei_ < mm) : true;                                 \
        u4 ux_ = *(const u4*)(xl + (size_t)s_ * HID + dbase);                   \
        float x_[8];                                                            \
        b2f2(ux_.x, x_[0], x_[1]); b2f2(ux_.y, x_[2], x_[3]);                   \
        b2f2(ux_.z, x_[4], x_[5]); b2f2(ux_.w, x_[6], x_[7]);                   \
        float lg_ = 0.f;                                                        \
        _Pragma("unroll")                                                       \
        for (int q_ = 0; q_ < 8; ++q_) {                                        \
            float t_ = x_[q_] + xr8[q_] + ea_ * we8[q_];                        \
            t_ = (t_ > 0.f) ? t_ : 0.2f * t_;                                   \
            lg_ = fmaf(at8[q_], t_, lg_);                                       \
        }                                                                       \
        float w_ = val_ ? __expf(lg_) : 0.f;                                    \
        Z += w_;                                                                \
        _Pragma("unroll")                                                       \
        for (int q_ = 0; q_ < 8; ++q_) acc[q_] = fmaf(w_, x_[q_], acc[q_]);     \
    }

    for (int cb = p0; cb < p1; cb += 64) {
        int mm = min(64, p1 - cb);
        int2 m2 = (lane < mm) ? csr[cb + lane] : make_int2(0, 0);
        int sv = m2.x;
        float evl = __int_as_float(m2.y);
        int j = 0;
        for (; j + 8 <= mm; j += 8) { QUAD(j, false) QUAD(j + 4, false) }
        for (; j < mm; j += 4) QUAD(j, true)
    }
#undef QUAD

    // combine the 4 edge subgroups
    Z += __shfl_xor(Z, 16); Z += __shfl_xor(Z, 32);
#pragma unroll
    for (int q = 0; q < 8; ++q) {
        acc[q] += __shfl_xor(acc[q], 16);
        acc[q] += __shfl_xor(acc[q], 32);
    }
    float inv = 1.f / (Z + 1e-16f);

    // residual + LN over the 128 dims held by the 16 head-lanes
    f4 hv0 = *(const f4*)(h + base + dbase);
    f4 hv1 = *(const f4*)(h + base + dbase + 4);
    float hres[8] = {hv0.x, hv0.y, hv0.z, hv0.w, hv1.x, hv1.y, hv1.z, hv1.w};
    f4 gb0 = *(const f4*)(gbias + dbase), gb1 = *(const f4*)(gbias + dbase + 4);
    float gb8[8] = {gb0.x, gb0.y, gb0.z, gb0.w, gb1.x, gb1.y, gb1.z, gb1.w};
    float o[8], sm = 0.f, sq = 0.f;
#pragma unroll
    for (int q = 0; q < 8; ++q) {
        o[q] = acc[q] * inv + gb8[q] + hres[q];
        sm += o[q]; sq += o[q] * o[q];
    }
#pragma unroll
    for (int k = 1; k < 16; k <<= 1) { sm += __shfl_xor(sm, k); sq += __shfl_xor(sq, k); }
    float mu = sm * (1.f / 128.f);
    float var = sq * (1.f / 128.f) - mu * mu;
    float rinv = rsqrtf(var + 1e-5f);
    f4 g0 = *(const f4*)(g + dbase), g1 = *(const f4*)(g + dbase + 4);
    float g8[8] = {g0.x, g0.y, g0.z, g0.w, g1.x, g1.y, g1.z, g1.w};
    f4 b0 = *(const f4*)(b + dbase), b1 = *(const f4*)(b + dbase + 4);
    float b8[8] = {b0.x, b0.y, b0.z, b0.w, b1.x, b1.y, b1.z, b1.w};
    float v8[8];
#pragma unroll
    for (int q = 0; q < 8; ++q) v8[q] = (o[q] - mu) * rinv * g8[q] + b8[q];
    if (grp == 0) {
        f4 s0 = {v8[0], v8[1], v8[2], v8[3]};
        f4 s1 = {v8[4], v8[5], v8[6], v8[7]};
        *(f4*)(h + base + dbase) = s0;
        *(f4*)(h + base + dbase + 4) = s1;
        u4 hu;
        hu.x = pk2(v8[0], v8[1]); hu.y = pk2(v8[2], v8[3]);
        hu.z = pk2(v8[4], v8[5]); hu.w = pk2(v8[6], v8[7]);
        *(u4*)(hb + base + dbase) = hu;
    }
}

// ---------------------------------------------------------------- per-store partial sums (no global atomics)
__global__ __launch_bounds__(256) void k_store_sum(const float* __restrict__ h,
                                                   const int* __restrict__ mask,
                                                   float* __restrict__ psums,   // [SSB][NSTORE*HID]
                                                   int* __restrict__ pcnts) {   // [SSB][NSTORE]
    __shared__ float ls[NSTORE * HID];
    __shared__ int lc[NSTORE];
    int t = threadIdx.x, bidx = blockIdx.x;
    for (int i = t; i < NSTORE * HID; i += 256) ls[i] = 0.f;
    if (t < NSTORE) lc[t] = 0;
    __syncthreads();
    int wid = bidx * 4 + (t >> 6);
    int lane = t & 63;
    int nw = SSB * 4;
    int d0 = lane * 2;
    for (int node = wid; node < NN; node += nw) {
        int s = mask[node];
        float2 hv = *(const float2*)(h + (size_t)node * HID + d0);
        atomicAdd(&ls[s * HID + d0], hv.x);
        atomicAdd(&ls[s * HID + d0 + 1], hv.y);
        if (lane == 0) atomicAdd(&lc[s], 1);
    }
    __syncthreads();
    for (int i = t; i < NSTORE * HID; i += 256) psums[(size_t)bidx * (NSTORE * HID) + i] = ls[i];
    if (t < NSTORE) pcnts[bidx * NSTORE + t] = lc[t];
}

// ---------------------------------------------------------------- gate (reduces partials)
__global__ __launch_bounds__(128) void k_gate(const float* __restrict__ psums,
                                              const int* __restrict__ pcnts,
                                              const float* __restrict__ ctxW,
                                              const float* __restrict__ ctxb,
                                              float* __restrict__ gm) {
    __shared__ float mloc[HID];
    __shared__ float csh;
    int s = blockIdx.x, t = threadIdx.x;
    float s0 = 0.f, s1 = 0.f, s2 = 0.f, s3 = 0.f;
    for (int b = 0; b < SSB; b += 4) {
        s0 += psums[(size_t)(b + 0) * (NSTORE * HID) + s * HID + t];
        s1 += psums[(size_t)(b + 1) * (NSTORE * HID) + s * HID + t];
        s2 += psums[(size_t)(b + 2) * (NSTORE * HID) + s * HID + t];
        s3 += psums[(size_t)(b + 3) * (NSTORE * HID) + s * HID + t];
    }
    float sum = (s0 + s1) + (s2 + s3);
    if (t == 0) {
        int c = 0;
        for (int b = 0; b < SSB; ++b) c += pcnts[b * NSTORE + s];
        csh = fmaxf((float)c, 1.f);
    }
    __syncthreads();
    float mk = sum / csh;
    mloc[t] = mk;
    __syncthreads();
    float acc = ctxb[t];
    for (int j = 0; j < HID; ++j) acc += mloc[j] * ctxW[j * HID + t];
    float gate = 1.f / (1.f + __expf(-acc));
    gm[s * HID + t] = gate * mk;
}

// ---------------------------------------------------------------- final: out = LN(h + gm[store])
__global__ __launch_bounds__(256) void k_final(const float* __restrict__ h,
                                               const int* __restrict__ mask,
                                               const float* __restrict__ gm,
                                               const float* __restrict__ g,
                                               const float* __restrict__ b,
                                               float* __restrict__ out) {
    int wid = (blockIdx.x * 256 + threadIdx.x) >> 6;
    int lane = threadIdx.x & 63;
    if (wid >= NN) return;
    size_t base = (size_t)wid * HID;
    int s = mask[wid];
    int d0 = lane * 2, d1 = d0 + 1;
    float v0 = h[base + d0] + gm[s * HID + d0];
    float v1 = h[base + d1] + gm[s * HID + d1];
    float sm = v0 + v1, sq = v0 * v0 + v1 * v1;
#pragma unroll
    for (int k = 1; k < 64; k <<= 1) { sm += __shfl_xor(sm, k); sq += __shfl_xor(sq, k); }
    float mu = sm * (1.f / 128.f);
    float var = sq * (1.f / 128.f) - mu * mu;
    float r = rsqrtf(var + 1e-5f);
    out[base + d0] = (v0 - mu) * r * g[d0] + b[d0];
    out[base + d1] = (v1 - mu) * r * g[d1] + b[d1];
}

// ---------------------------------------------------------------- launch
extern "C" void kernel_launch(void* const* d_in, const int* in_sizes, int n_in,
                              void* d_out, int out_size, void* d_ws, size_t ws_size,
                              hipStream_t stream) {
    const float* x      = (const float*)d_in[0];
    const int*   ei     = (const int*)d_in[1];
    const float* ew     = (const float*)d_in[2];
    const int*   smask  = (const int*)d_in[3];
    const float* inW    = (const float*)d_in[4];
    const float* inb    = (const float*)d_in[5];
    const float* ing    = (const float*)d_in[6];
    const float* inbeta = (const float*)d_in[7];
    const float* gWl    = (const float*)d_in[8];
    const float* gbl    = (const float*)d_in[9];
    const float* gWr    = (const float*)d_in[10];
    const float* gbr    = (const float*)d_in[11];
    const float* gWe    = (const float*)d_in[12];
    const float* gatt   = (const float*)d_in[13];
    const float* gbias  = (const float*)d_in[14];
    const float* blkg   = (const float*)d_in[15];
    const float* blkb   = (const float*)d_in[16];
    const float* ctxW   = (const float*)d_in[17];
    const float* ctxb   = (const float*)d_in[18];
    const float* fing   = (const float*)d_in[19];
    const float* finb   = (const float*)d_in[20];
    float* out = (float*)d_out;

    float* ws = (float*)d_ws;
    size_t o = 0;
    float*    h      = ws + o;              o += (size_t)NN * HID;
    int2*     csr    = (int2*)(ws + o);     o += (size_t)ET * 2;
    float*    gm     = ws + o;              o += NSTORE * HID;
    int*      offs   = (int*)(ws + o);      o += 50004;
    int*      rank   = (int*)(ws + o);      o += EE;
    ushort_t* xb     = (ushort_t*)(ws + o); o += (size_t)NN * 64 / 2;
    ushort_t* hb     = (ushort_t*)(ws + o); o += (size_t)NN * HID / 2;
    ushort_t* xlb    = (ushort_t*)(ws + o); o += (size_t)NN * HID / 2;
    ushort_t* xrb    = (ushort_t*)(ws + o); o += (size_t)NN * HID / 2;
    ushort_t* inWt   = (ushort_t*)(ws + o); o += 128 * 64 / 2;
    ushort_t* Wlt    = (ushort_t*)(ws + o); o += 3 * 128 * 128 / 2;
    ushort_t* Wrt    = (ushort_t*)(ws + o); o += 3 * 128 * 128 / 2;
    int*      bsum   = (int*)(ws + o);      o += 256;
    int*      bbase  = (int*)(ws + o);      o += 256;
    float*    psums  = ws + o;              o += (size_t)SSB * NSTORE * HID;
    int*      pcnts  = (int*)(ws + o);      o += SSB * NSTORE;
    // zero-init region (single memset); packed must be 8B-aligned (o is even here)
    if (o & 1) ++o;
    float*    zbase  = ws + o;
    u64*      packed = (u64*)(ws + o);      o += (size_t)NN * 2;
    size_t zbytes = (size_t)(NN * 2) * 4;

    hipMemsetAsync((void*)zbase, 0, zbytes, stream);

    const int WB = NN / 4;                    // wave-per-node kernels
    const int GB = (NN + 127) / 128;          // 128-row GEMM tiles

    k_build<<<CVT_B + CNT_B, 256, 0, stream>>>(x, inW, gWl, gWr, ei, ew,
                                               xb, inWt, Wlt, Wrt, packed, rank);
    k_psum<<<NBL, 256, 0, stream>>>(packed, bsum);
    k_scanb<<<1, 256, 0, stream>>>(bsum, bbase, offs);
    k_offs<<<NBL, 256, 0, stream>>>(packed, bbase, offs);
    k_scatter<<<SCT_B, 256, 0, stream>>>(ei, ew, offs, packed, rank, csr);
    k_inproj<<<GB, 256, 0, stream>>>(xb, inWt, inb, ing, inbeta, h, hb);

    for (int l = 0; l < 3; ++l) {
        dim3 gg(GB, 2);
        k_gemm2<<<gg, 256, 0, stream>>>(hb, Wlt + (size_t)l * HID * HID, Wrt + (size_t)l * HID * HID,
                                        gbl + l * HID, gbr + l * HID, xlb, xrb, NN);
        k_attn<<<WB, 256, 0, stream>>>(xlb, xrb, h, hb, offs, csr,
                                       gWe + l * HID, gatt + l * HID, gbias + l * HID,
                                       blkg + l * HID, blkb + l * HID);
    }

    k_store_sum<<<SSB, 256, 0, stream>>>(h, smask, psums, pcnts);
    k_gate<<<NSTORE, 128, 0, stream>>>(psums, pcnts, ctxW, ctxb, gm);
    k_final<<<WB, 256, 0, stream>>>(h, smask, gm, fing, finb, out);
}

// Round 7
// 542.796 us; speedup vs baseline: 1.1342x; 1.1145x over previous
//
#include <hip/hip_runtime.h>
#include <math.h>

#define NN 50000
#define EE 800000
#define ET (EE + NN)
#define HID 128
#define NSTORE 50
#define NBL 196                      // ceil(NN/256)
#define CVT_B 12500                  // NN*64/256
#define CNT_B 3125                   // EE/256
#define SCT_B 3321                   // ceil(ET/256)
#define GEMB 391                     // ceil(NN/128) gemm tiles
#define SSB 512                      // store-sum partial blocks (2 blocks/CU)

typedef unsigned short ushort_t;
typedef unsigned long long u64;
typedef __attribute__((ext_vector_type(8))) short bf8;
typedef __attribute__((ext_vector_type(4))) float f4;
typedef __attribute__((ext_vector_type(4))) unsigned int u4;

__device__ __forceinline__ float b2f(ushort_t u) {
    union { unsigned int i; float f; } v; v.i = ((unsigned int)u) << 16; return v.f;
}
__device__ __forceinline__ ushort_t f2b(float f) {
    union { float f; unsigned int i; } v; v.f = f;
    unsigned int r = (v.i + 0x7fffu + ((v.i >> 16) & 1u)) >> 16;
    return (ushort_t)r;
}
__device__ __forceinline__ void b2f2(unsigned int u, float& lo, float& hi) {
    union { unsigned int i; float f; } a, c;
    a.i = u << 16; c.i = u & 0xffff0000u;
    lo = a.f; hi = c.f;
}
__device__ __forceinline__ unsigned int pk2(float lo, float hi) {
    return (unsigned int)f2b(lo) | ((unsigned int)f2b(hi) << 16);
}

// ---------------------------------------------------------------- build: bf16 cvt (BW) + edge count (latency), fused
// packed[dst]: bits 44+: degree count; bits 0..43: sum(ew) in 2^24 fixed point.
__global__ __launch_bounds__(256) void k_build(const float* __restrict__ x, const float* __restrict__ inW,
                                               const float* __restrict__ gWl, const float* __restrict__ gWr,
                                               const int* __restrict__ ei, const float* __restrict__ ew,
                                               ushort_t* __restrict__ xb, ushort_t* __restrict__ inWt,
                                               ushort_t* __restrict__ Wlt, ushort_t* __restrict__ Wrt,
                                               u64* __restrict__ packed, int* __restrict__ rank) {
    int b = blockIdx.x, t = threadIdx.x;
    if (b < CVT_B) {
        int i = b * 256 + t;
        xb[i] = f2b(x[i]);
        if (i < 128 * 64) {               // inWt[c*64+k] = inW[k*128+c]
            int c = i >> 6, k = i & 63;
            inWt[i] = f2b(inW[k * 128 + c]);
        }
        if (i < 3 * 128 * 128) {          // Wlt[l][n*128+k] = W[l][k*128+n]
            int l = i >> 14, r = i & 16383, nn2 = r >> 7, k = r & 127;
            Wlt[i] = f2b(gWl[(size_t)l * 16384 + k * 128 + nn2]);
            Wrt[i] = f2b(gWr[(size_t)l * 16384 + k * 128 + nn2]);
        }
    } else {
        int i = (b - CVT_B) * 256 + t;
        if (i < EE) {
            int dst = ei[EE + i];
            unsigned int wfix = __float2uint_rn(ew[i] * 16777216.0f);
            u64 old = atomicAdd(&packed[dst], (1ULL << 44) | (u64)wfix);
            rank[i] = (int)(old >> 44);
        }
    }
}

// per-256-chunk sums of (deg+1)
__global__ __launch_bounds__(256) void k_psum(const u64* __restrict__ packed, int* __restrict__ bsum) {
    int t = threadIdx.x, bidx = blockIdx.x;
    int i = bidx * 256 + t;
    int v = (i < NN) ? (int)(packed[i] >> 44) + 1 : 0;
#pragma unroll
    for (int d = 1; d < 64; d <<= 1) v += __shfl_xor(v, d);
    __shared__ int ws4[4];
    if ((t & 63) == 0) ws4[t >> 6] = v;
    __syncthreads();
    if (t == 0) bsum[bidx] = ws4[0] + ws4[1] + ws4[2] + ws4[3];
}

__global__ __launch_bounds__(256) void k_scanb(const int* __restrict__ bsum,
                                               int* __restrict__ bbase, int* __restrict__ offs) {
    __shared__ int s[256];
    int t = threadIdx.x;
    int v = (t < NBL) ? bsum[t] : 0;
    s[t] = v;
    __syncthreads();
    for (int d = 1; d < 256; d <<= 1) {
        int u = (t >= d) ? s[t - d] : 0;
        __syncthreads();
        s[t] += u;
        __syncthreads();
    }
    if (t < NBL) bbase[t] = s[t] - v;    // exclusive base
    if (t == 0) offs[NN] = ET;
}

__global__ __launch_bounds__(256) void k_offs(const u64* __restrict__ packed,
                                              const int* __restrict__ bbase, int* __restrict__ offs) {
    __shared__ int wsum4[4];
    int t = threadIdx.x, bidx = blockIdx.x;
    int i = bidx * 256 + t;
    int v = (i < NN) ? (int)(packed[i] >> 44) + 1 : 0;
    int lane = t & 63, w = t >> 6;
    int sc = v;
#pragma unroll
    for (int d = 1; d < 64; d <<= 1) {
        int u = __shfl_up(sc, d);
        if (lane >= d) sc += u;
    }
    if (lane == 63) wsum4[w] = sc;
    __syncthreads();
    int wo = 0;
    for (int k = 0; k < w; ++k) wo += wsum4[k];
    if (i < NN) offs[i] = bbase[bidx] + wo + sc - v;
}

// ---------------------------------------------------------------- input proj: GELU + LN fused, K=64
__global__ __launch_bounds__(256) void k_inproj(const ushort_t* __restrict__ A,
                                                const ushort_t* __restrict__ Wt,
                                                const float* __restrict__ bias,
                                                const float* __restrict__ g,
                                                const float* __restrict__ be,
                                                float* __restrict__ h,
                                                ushort_t* __restrict__ hb) {
    const int K = 64;
    __shared__ float s1[2][128], s2[2][128];
    int lane = threadIdx.x & 63, w = threadIdx.x >> 6;
    int rw = w >> 1, cw = w & 1;
    int q = lane >> 4, l16 = lane & 15;
    int row0 = blockIdx.x * 128 + rw * 64;
    int col0 = cw * 64;
    bf8 z; for (int t = 0; t < 8; ++t) z[t] = 0;

    bf8 bfr[2][4];
#pragma unroll
    for (int kk = 0; kk < 2; ++kk)
#pragma unroll
        for (int j = 0; j < 4; ++j)
            bfr[kk][j] = *(const bf8*)(Wt + (size_t)(col0 + j * 16 + l16) * K + kk * 32 + q * 8);

    f4 acc[4][4];
#pragma unroll
    for (int i = 0; i < 4; ++i)
#pragma unroll
        for (int j = 0; j < 4; ++j) acc[i][j] = (f4)(0.f);

#pragma unroll
    for (int kk = 0; kk < 2; ++kk) {
        bf8 af[4];
#pragma unroll
        for (int i = 0; i < 4; ++i) {
            int r = row0 + i * 16 + l16;
            af[i] = (r < NN) ? *(const bf8*)(A + (size_t)r * K + kk * 32 + q * 8) : z;
        }
#pragma unroll
        for (int i = 0; i < 4; ++i)
#pragma unroll
            for (int j = 0; j < 4; ++j)
                acc[i][j] = __builtin_amdgcn_mfma_f32_16x16x32_bf16(af[i], bfr[kk][j], acc[i][j], 0, 0, 0);
    }
#pragma unroll
    for (int i = 0; i < 4; ++i) {
#pragma unroll
        for (int j = 0; j < 4; ++j) {
            float bv = bias[col0 + j * 16 + l16];
#pragma unroll
            for (int r = 0; r < 4; ++r) {
                float v = acc[i][j][r] + bv;
                v = 0.5f * v * (1.f + erff(v * 0.70710678118654752f));
                acc[i][j][r] = v;
            }
        }
    }
#pragma unroll
    for (int i = 0; i < 4; ++i) {
#pragma unroll
        for (int r = 0; r < 4; ++r) {
            float sm = acc[i][0][r] + acc[i][1][r] + acc[i][2][r] + acc[i][3][r];
            float sq = acc[i][0][r] * acc[i][0][r] + acc[i][1][r] * acc[i][1][r]
                     + acc[i][2][r] * acc[i][2][r] + acc[i][3][r] * acc[i][3][r];
#pragma unroll
            for (int k = 1; k < 16; k <<= 1) { sm += __shfl_xor(sm, k); sq += __shfl_xor(sq, k); }
            if (l16 == 0) {
                int rl = rw * 64 + i * 16 + q * 4 + r;
                s1[cw][rl] = sm; s2[cw][rl] = sq;
            }
        }
    }
    __syncthreads();
#pragma unroll
    for (int i = 0; i < 4; ++i) {
#pragma unroll
        for (int r = 0; r < 4; ++r) {
            int rl = rw * 64 + i * 16 + q * 4 + r;
            int gr = blockIdx.x * 128 + rl;
            if (gr >= NN) continue;
            float sm = s1[0][rl] + s1[1][rl];
            float sq = s2[0][rl] + s2[1][rl];
            float mu = sm * (1.f / 128.f);
            float var = sq * (1.f / 128.f) - mu * mu;
            float rinv = rsqrtf(var + 1e-5f);
#pragma unroll
            for (int j = 0; j < 4; ++j) {
                int gc = col0 + j * 16 + l16;
                float v = (acc[i][j][r] - mu) * rinv * g[gc] + be[gc];
                h[(size_t)gr * HID + gc] = v;
                hb[(size_t)gr * HID + gc] = f2b(v);
            }
        }
    }
}

// ---------------------------------------------------------------- bf16 MFMA dual GEMM (K=128) + optional fused scatter
// blocks [0,GEMB): xlb = hb@Wl^T+bl ; [GEMB,2*GEMB): xrb = hb@Wr^T+br ;
// blocks >= 2*GEMB: CSR scatter (layer 0 launch only). Scatter blocks run at
// this kernel's 96-VGPR budget -> ~20 waves/CU occupancy, hidden behind MFMA waves.
__global__ __launch_bounds__(256) void k_gemm2(const ushort_t* __restrict__ A,
                                               const ushort_t* __restrict__ Wt0,
                                               const ushort_t* __restrict__ Wt1,
                                               const float* __restrict__ b0,
                                               const float* __restrict__ b1,
                                               ushort_t* __restrict__ o0,
                                               ushort_t* __restrict__ o1, int n,
                                               const int* __restrict__ ei,
                                               const float* __restrict__ ew,
                                               const int* __restrict__ offs,
                                               const u64* __restrict__ packed,
                                               const int* __restrict__ rank,
                                               int2* __restrict__ csr) {
    int bid = blockIdx.x;
    if (bid >= 2 * GEMB) {
        int i = (bid - 2 * GEMB) * 256 + threadIdx.x;
        if (i < EE) {
            int src = ei[i], dst = ei[EE + i];
            int pos = offs[dst] + rank[i];
            int2 v; v.x = src; v.y = __float_as_int(ew[i]);
            csr[pos] = v;
        } else if (i < ET) {
            int nd = i - EE;
            u64 p = packed[nd];
            int deg = (int)(p >> 44);
            float wsf = (float)(p & ((1ULL << 44) - 1)) * (1.0f / 16777216.0f);
            float la = wsf / fmaxf((float)deg, 1.0f);
            int pos = offs[nd + 1] - 1;
            int2 v; v.x = nd; v.y = __float_as_int(la);
            csr[pos] = v;
        }
        return;
    }
    const int K = 128;
    int by = (bid >= GEMB) ? 1 : 0;
    int bx = by ? bid - GEMB : bid;
    const ushort_t* Wt = by ? Wt1 : Wt0;
    const float* bias = by ? b1 : b0;
    ushort_t* outb = by ? o1 : o0;
    int lane = threadIdx.x & 63, w = threadIdx.x >> 6;
    int rw = w >> 1, cw = w & 1;
    int q = lane >> 4, l16 = lane & 15;
    int row0 = bx * 128 + rw * 64;
    int col0 = cw * 64;
    bf8 z; for (int t = 0; t < 8; ++t) z[t] = 0;

    bf8 bfr[4][4];
#pragma unroll
    for (int kk = 0; kk < 4; ++kk)
#pragma unroll
        for (int j = 0; j < 4; ++j)
            bfr[kk][j] = *(const bf8*)(Wt + (size_t)(col0 + j * 16 + l16) * K + kk * 32 + q * 8);

    f4 acc[4][4];
#pragma unroll
    for (int i = 0; i < 4; ++i)
#pragma unroll
        for (int j = 0; j < 4; ++j) acc[i][j] = (f4)(0.f);

#pragma unroll
    for (int kk = 0; kk < 4; ++kk) {
        bf8 af[4];
#pragma unroll
        for (int i = 0; i < 4; ++i) {
            int r = row0 + i * 16 + l16;
            af[i] = (r < n) ? *(const bf8*)(A + (size_t)r * K + kk * 32 + q * 8) : z;
        }
#pragma unroll
        for (int i = 0; i < 4; ++i)
#pragma unroll
            for (int j = 0; j < 4; ++j)
                acc[i][j] = __builtin_amdgcn_mfma_f32_16x16x32_bf16(af[i], bfr[kk][j], acc[i][j], 0, 0, 0);
    }
#pragma unroll
    for (int i = 0; i < 4; ++i) {
        int gr0 = row0 + i * 16 + q * 4;
#pragma unroll
        for (int j = 0; j < 4; ++j) {
            int gc = col0 + j * 16 + l16;
            float bv = bias[gc];
#pragma unroll
            for (int r = 0; r < 4; ++r) {
                int gr = gr0 + r;
                if (gr < n) outb[(size_t)gr * HID + gc] = f2b(acc[i][j][r] + bv);
            }
        }
    }
}

// ---------------------------------------------------------------- GATv2 attention
// wave per dst node; 16 lanes = one edge (lane = head, DH=8 in-lane); 4 edges/step.
__global__ __launch_bounds__(256) void k_attn(const ushort_t* __restrict__ xl,
                                              const ushort_t* __restrict__ xr,
                                              float* __restrict__ h,
                                              ushort_t* __restrict__ hb,
                                              const int* __restrict__ offs,
                                              const int2* __restrict__ csr,
                                              const float* __restrict__ We,
                                              const float* __restrict__ att,
                                              const float* __restrict__ gbias,
                                              const float* __restrict__ g,
                                              const float* __restrict__ b) {
    int wid = (blockIdx.x * 256 + threadIdx.x) >> 6;
    int lane = threadIdx.x & 63;
    if (wid >= NN) return;
    int hd = lane & 15;          // head index (16 heads; DH=8 in-lane)
    int grp = lane >> 4;         // edge subgroup 0..3
    int dbase = hd * 8;
    size_t base = (size_t)wid * HID;

    float xr8[8], at8[8], we8[8];
    {
        u4 uxr = *(const u4*)(xr + base + dbase);
        b2f2(uxr.x, xr8[0], xr8[1]); b2f2(uxr.y, xr8[2], xr8[3]);
        b2f2(uxr.z, xr8[4], xr8[5]); b2f2(uxr.w, xr8[6], xr8[7]);
        f4 a0 = *(const f4*)(att + dbase), a1 = *(const f4*)(att + dbase + 4);
        at8[0] = a0.x; at8[1] = a0.y; at8[2] = a0.z; at8[3] = a0.w;
        at8[4] = a1.x; at8[5] = a1.y; at8[6] = a1.z; at8[7] = a1.w;
        f4 w0 = *(const f4*)(We + dbase), w1 = *(const f4*)(We + dbase + 4);
        we8[0] = w0.x; we8[1] = w0.y; we8[2] = w0.z; we8[3] = w0.w;
        we8[4] = w1.x; we8[5] = w1.y; we8[6] = w1.z; we8[7] = w1.w;
    }
    int p0 = offs[wid], p1 = offs[wid + 1];
    float Z = 0.f;
    float acc[8];
#pragma unroll
    for (int q = 0; q < 8; ++q) acc[q] = 0.f;

#define QUAD(EJ, MASKED)                                                        \
    {                                                                           \
        int ei_ = (EJ) + grp;                                                   \
        int s_ = __shfl(sv, ei_);                                               \
        float ea_ = __shfl(evl, ei_);                                           \
        bool val_ = MASKED ? (ei_ < mm) : true;                                 \
        u4 ux_ = *(const u4*)(xl + (size_t)s_ * HID + dbase);                   \
        float x_[8];                                                            \
        b2f2(ux_.x, x_[0], x_[1]); b2f2(ux_.y, x_[2], x_[3]);                   \
        b2f2(ux_.z, x_[4], x_[5]); b2f2(ux_.w, x_[6], x_[7]);                   \
        float lg_ = 0.f;                                                        \
        _Pragma("unroll")                                                       \
        for (int q_ = 0; q_ < 8; ++q_) {                                        \
            float t_ = x_[q_] + xr8[q_] + ea_ * we8[q_];                        \
            t_ = (t_ > 0.f) ? t_ : 0.2f * t_;                                   \
            lg_ = fmaf(at8[q_], t_, lg_);                                       \
        }                                                                       \
        float w_ = val_ ? __expf(lg_) : 0.f;                                    \
        Z += w_;                                                                \
        _Pragma("unroll")                                                       \
        for (int q_ = 0; q_ < 8; ++q_) acc[q_] = fmaf(w_, x_[q_], acc[q_]);     \
    }

    for (int cb = p0; cb < p1; cb += 64) {
        int mm = min(64, p1 - cb);
        int2 m2 = (lane < mm) ? csr[cb + lane] : make_int2(0, 0);
        int sv = m2.x;
        float evl = __int_as_float(m2.y);
        int j = 0;
        for (; j + 8 <= mm; j += 8) { QUAD(j, false) QUAD(j + 4, false) }
        for (; j < mm; j += 4) QUAD(j, true)
    }
#undef QUAD

    // combine the 4 edge subgroups
    Z += __shfl_xor(Z, 16); Z += __shfl_xor(Z, 32);
#pragma unroll
    for (int q = 0; q < 8; ++q) {
        acc[q] += __shfl_xor(acc[q], 16);
        acc[q] += __shfl_xor(acc[q], 32);
    }
    float inv = 1.f / (Z + 1e-16f);

    // residual + LN over the 128 dims held by the 16 head-lanes
    f4 hv0 = *(const f4*)(h + base + dbase);
    f4 hv1 = *(const f4*)(h + base + dbase + 4);
    float hres[8] = {hv0.x, hv0.y, hv0.z, hv0.w, hv1.x, hv1.y, hv1.z, hv1.w};
    f4 gb0 = *(const f4*)(gbias + dbase), gb1 = *(const f4*)(gbias + dbase + 4);
    float gb8[8] = {gb0.x, gb0.y, gb0.z, gb0.w, gb1.x, gb1.y, gb1.z, gb1.w};
    float o[8], sm = 0.f, sq = 0.f;
#pragma unroll
    for (int q = 0; q < 8; ++q) {
        o[q] = acc[q] * inv + gb8[q] + hres[q];
        sm += o[q]; sq += o[q] * o[q];
    }
#pragma unroll
    for (int k = 1; k < 16; k <<= 1) { sm += __shfl_xor(sm, k); sq += __shfl_xor(sq, k); }
    float mu = sm * (1.f / 128.f);
    float var = sq * (1.f / 128.f) - mu * mu;
    float rinv = rsqrtf(var + 1e-5f);
    f4 g0 = *(const f4*)(g + dbase), g1 = *(const f4*)(g + dbase + 4);
    float g8[8] = {g0.x, g0.y, g0.z, g0.w, g1.x, g1.y, g1.z, g1.w};
    f4 b0 = *(const f4*)(b + dbase), b1 = *(const f4*)(b + dbase + 4);
    float b8[8] = {b0.x, b0.y, b0.z, b0.w, b1.x, b1.y, b1.z, b1.w};
    float v8[8];
#pragma unroll
    for (int q = 0; q < 8; ++q) v8[q] = (o[q] - mu) * rinv * g8[q] + b8[q];
    if (grp == 0) {
        f4 s0 = {v8[0], v8[1], v8[2], v8[3]};
        f4 s1 = {v8[4], v8[5], v8[6], v8[7]};
        *(f4*)(h + base + dbase) = s0;
        *(f4*)(h + base + dbase + 4) = s1;
        u4 hu;
        hu.x = pk2(v8[0], v8[1]); hu.y = pk2(v8[2], v8[3]);
        hu.z = pk2(v8[4], v8[5]); hu.w = pk2(v8[6], v8[7]);
        *(u4*)(hb + base + dbase) = hu;
    }
}

// ---------------------------------------------------------------- per-store partial sums (no global atomics)
__global__ __launch_bounds__(256) void k_store_sum(const float* __restrict__ h,
                                                   const int* __restrict__ mask,
                                                   float* __restrict__ psums,   // [SSB][NSTORE*HID]
                                                   int* __restrict__ pcnts) {   // [SSB][NSTORE]
    __shared__ float ls[NSTORE * HID];
    __shared__ int lc[NSTORE];
    int t = threadIdx.x, bidx = blockIdx.x;
    for (int i = t; i < NSTORE * HID; i += 256) ls[i] = 0.f;
    if (t < NSTORE) lc[t] = 0;
    __syncthreads();
    int wid = bidx * 4 + (t >> 6);
    int lane = t & 63;
    int nw = SSB * 4;
    int d0 = lane * 2;
    for (int node = wid; node < NN; node += nw) {
        int s = mask[node];
        float2 hv = *(const float2*)(h + (size_t)node * HID + d0);
        atomicAdd(&ls[s * HID + d0], hv.x);
        atomicAdd(&ls[s * HID + d0 + 1], hv.y);
        if (lane == 0) atomicAdd(&lc[s], 1);
    }
    __syncthreads();
    for (int i = t; i < NSTORE * HID; i += 256) psums[(size_t)bidx * (NSTORE * HID) + i] = ls[i];
    if (t < NSTORE) pcnts[bidx * NSTORE + t] = lc[t];
}

// ---------------------------------------------------------------- gate (parallel reduction of partials)
// block = store s; 256 threads: d = t&127, half = t>>7 covers SSB/2 partials each.
__global__ __launch_bounds__(256) void k_gate(const float* __restrict__ psums,
                                              const int* __restrict__ pcnts,
                                              const float* __restrict__ ctxW,
                                              const float* __restrict__ ctxb,
                                              float* __restrict__ gm) {
    __shared__ float h1[HID];
    __shared__ float mloc[HID];
    __shared__ int cw4[4];
    int s = blockIdx.x, t = threadIdx.x;
    int d = t & 127, half = t >> 7;
    float s0 = 0.f, s1 = 0.f, s2 = 0.f, s3 = 0.f;
    for (int b = half * 4; b < SSB; b += 8) {
        s0 += psums[(size_t)(b + 0) * (NSTORE * HID) + s * HID + d];
        s1 += psums[(size_t)(b + 1) * (NSTORE * HID) + s * HID + d];
        s2 += psums[(size_t)(b + 2) * (NSTORE * HID) + s * HID + d];
        s3 += psums[(size_t)(b + 3) * (NSTORE * HID) + s * HID + d];
    }
    float sum = (s0 + s1) + (s2 + s3);
    // counts: 512 partial counts reduced wave-parallel (2 loads/thread)
    int c = pcnts[t * NSTORE + s] + pcnts[(t + 256) * NSTORE + s];
#pragma unroll
    for (int k = 1; k < 64; k <<= 1) c += __shfl_xor(c, k);
    if ((t & 63) == 0) cw4[t >> 6] = c;
    if (half) h1[d] = sum;
    __syncthreads();
    if (half == 0) {
        float tot = sum + h1[d];
        float cnt = fmaxf((float)(cw4[0] + cw4[1] + cw4[2] + cw4[3]), 1.f);
        mloc[d] = tot / cnt;
    }
    __syncthreads();
    if (half == 0) {
        float acc = ctxb[d];
        for (int j = 0; j < HID; ++j) acc += mloc[j] * ctxW[j * HID + d];
        float gate = 1.f / (1.f + __expf(-acc));
        gm[s * HID + d] = gate * mloc[d];
    }
}

// ---------------------------------------------------------------- final: out = LN(h + gm[store])
__global__ __launch_bounds__(256) void k_final(const float* __restrict__ h,
                                               const int* __restrict__ mask,
                                               const float* __restrict__ gm,
                                               const float* __restrict__ g,
                                               const float* __restrict__ b,
                                               float* __restrict__ out) {
    int wid = (blockIdx.x * 256 + threadIdx.x) >> 6;
    int lane = threadIdx.x & 63;
    if (wid >= NN) return;
    size_t base = (size_t)wid * HID;
    int s = mask[wid];
    int d0 = lane * 2, d1 = d0 + 1;
    float v0 = h[base + d0] + gm[s * HID + d0];
    float v1 = h[base + d1] + gm[s * HID + d1];
    float sm = v0 + v1, sq = v0 * v0 + v1 * v1;
#pragma unroll
    for (int k = 1; k < 64; k <<= 1) { sm += __shfl_xor(sm, k); sq += __shfl_xor(sq, k); }
    float mu = sm * (1.f / 128.f);
    float var = sq * (1.f / 128.f) - mu * mu;
    float r = rsqrtf(var + 1e-5f);
    out[base + d0] = (v0 - mu) * r * g[d0] + b[d0];
    out[base + d1] = (v1 - mu) * r * g[d1] + b[d1];
}

// ---------------------------------------------------------------- launch
extern "C" void kernel_launch(void* const* d_in, const int* in_sizes, int n_in,
                              void* d_out, int out_size, void* d_ws, size_t ws_size,
                              hipStream_t stream) {
    const float* x      = (const float*)d_in[0];
    const int*   ei     = (const int*)d_in[1];
    const float* ew     = (const float*)d_in[2];
    const int*   smask  = (const int*)d_in[3];
    const float* inW    = (const float*)d_in[4];
    const float* inb    = (const float*)d_in[5];
    const float* ing    = (const float*)d_in[6];
    const float* inbeta = (const float*)d_in[7];
    const float* gWl    = (const float*)d_in[8];
    const float* gbl    = (const float*)d_in[9];
    const float* gWr    = (const float*)d_in[10];
    const float* gbr    = (const float*)d_in[11];
    const float* gWe    = (const float*)d_in[12];
    const float* gatt   = (const float*)d_in[13];
    const float* gbias  = (const float*)d_in[14];
    const float* blkg   = (const float*)d_in[15];
    const float* blkb   = (const float*)d_in[16];
    const float* ctxW   = (const float*)d_in[17];
    const float* ctxb   = (const float*)d_in[18];
    const float* fing   = (const float*)d_in[19];
    const float* finb   = (const float*)d_in[20];
    float* out = (float*)d_out;

    float* ws = (float*)d_ws;
    size_t o = 0;
    float*    h      = ws + o;              o += (size_t)NN * HID;
    int2*     csr    = (int2*)(ws + o);     o += (size_t)ET * 2;
    float*    gm     = ws + o;              o += NSTORE * HID;
    int*      offs   = (int*)(ws + o);      o += 50004;
    int*      rank   = (int*)(ws + o);      o += EE;
    ushort_t* xb     = (ushort_t*)(ws + o); o += (size_t)NN * 64 / 2;
    ushort_t* hb     = (ushort_t*)(ws + o); o += (size_t)NN * HID / 2;
    ushort_t* xlb    = (ushort_t*)(ws + o); o += (size_t)NN * HID / 2;
    ushort_t* xrb    = (ushort_t*)(ws + o); o += (size_t)NN * HID / 2;
    ushort_t* inWt   = (ushort_t*)(ws + o); o += 128 * 64 / 2;
    ushort_t* Wlt    = (ushort_t*)(ws + o); o += 3 * 128 * 128 / 2;
    ushort_t* Wrt    = (ushort_t*)(ws + o); o += 3 * 128 * 128 / 2;
    int*      bsum   = (int*)(ws + o);      o += 256;
    int*      bbase  = (int*)(ws + o);      o += 256;
    float*    psums  = ws + o;              o += (size_t)SSB * NSTORE * HID;
    int*      pcnts  = (int*)(ws + o);      o += SSB * NSTORE;
    // zero-init region (single memset); packed must be 8B-aligned (o is even here)
    if (o & 1) ++o;
    float*    zbase  = ws + o;
    u64*      packed = (u64*)(ws + o);      o += (size_t)NN * 2;
    size_t zbytes = (size_t)(NN * 2) * 4;

    hipMemsetAsync((void*)zbase, 0, zbytes, stream);

    const int WB = NN / 4;                    // wave-per-node kernels

    k_build<<<CVT_B + CNT_B, 256, 0, stream>>>(x, inW, gWl, gWr, ei, ew,
                                               xb, inWt, Wlt, Wrt, packed, rank);
    k_psum<<<NBL, 256, 0, stream>>>(packed, bsum);
    k_scanb<<<1, 256, 0, stream>>>(bsum, bbase, offs);
    k_offs<<<NBL, 256, 0, stream>>>(packed, bbase, offs);
    k_inproj<<<GEMB, 256, 0, stream>>>(xb, inWt, inb, ing, inbeta, h, hb);

    for (int l = 0; l < 3; ++l) {
        int nb = 2 * GEMB + (l == 0 ? SCT_B : 0);   // layer 0 carries the CSR scatter blocks
        k_gemm2<<<nb, 256, 0, stream>>>(hb, Wlt + (size_t)l * HID * HID, Wrt + (size_t)l * HID * HID,
                                        gbl + l * HID, gbr + l * HID, xlb, xrb, NN,
                                        ei, ew, offs, packed, rank, csr);
        k_attn<<<WB, 256, 0, stream>>>(xlb, xrb, h, hb, offs, csr,
                                       gWe + l * HID, gatt + l * HID, gbias + l * HID,
                                       blkg + l * HID, blkb + l * HID);
    }

    k_store_sum<<<SSB, 256, 0, stream>>>(h, smask, psums, pcnts);
    k_gate<<<NSTORE, 256, 0, stream>>>(psums, pcnts, ctxW, ctxb, gm);
    k_final<<<WB, 256, 0, stream>>>(h, smask, gm, fing, finb, out);
}

// Round 8
// 518.514 us; speedup vs baseline: 1.1873x; 1.0468x over previous
//
#include <hip/hip_runtime.h>
#include <math.h>

#define NN 50000
#define EE 800000
#define ET (EE + NN)
#define HID 128
#define NSTORE 50
#define NBL 196                      // ceil(NN/256)
#define CNT_B 3125                   // EE/256
#define WCV_B 192                    // 3*128*128/256 weight cvt blocks
#define SCT_B 3321                   // ceil(ET/256)
#define GEMB 391                     // ceil(NN/128) gemm tiles
#define SSB 512                      // store-sum partial blocks (2 blocks/CU)

typedef unsigned short ushort_t;
typedef unsigned long long u64;
typedef __attribute__((ext_vector_type(8))) short bf8;
typedef __attribute__((ext_vector_type(4))) float f4;
typedef __attribute__((ext_vector_type(2))) float f2;
typedef __attribute__((ext_vector_type(4))) unsigned int u4;

__device__ __forceinline__ ushort_t f2b(float f) {
    union { float f; unsigned int i; } v; v.f = f;
    unsigned int r = (v.i + 0x7fffu + ((v.i >> 16) & 1u)) >> 16;
    return (ushort_t)r;
}
__device__ __forceinline__ f2 b2f2v(unsigned int u) {
    union { unsigned int i; float f; } lo, hi;
    lo.i = u << 16; hi.i = u & 0xffff0000u;
    f2 r; r.x = lo.f; r.y = hi.f; return r;
}
__device__ __forceinline__ unsigned int pk2(float lo, float hi) {
    return (unsigned int)f2b(lo) | ((unsigned int)f2b(hi) << 16);
}
__device__ __forceinline__ f2 max2(f2 a, f2 b) {
#if __has_builtin(__builtin_elementwise_max)
    return __builtin_elementwise_max(a, b);
#else
    f2 r; r.x = fmaxf(a.x, b.x); r.y = fmaxf(a.y, b.y); return r;
#endif
}

// ---------------------------------------------------------------- build (fused): edge count (latency, FIRST) +
// weight cvt + input projection (MFMA, reads fp32 x directly — no xb buffer).
// packed[dst]: bits 44+: degree; bits 0..43: sum(ew) in 2^24 fixed point.
__global__ __launch_bounds__(256) void k_build(const float* __restrict__ x, const float* __restrict__ inW,
                                               const float* __restrict__ gWl, const float* __restrict__ gWr,
                                               const int* __restrict__ ei, const float* __restrict__ ew,
                                               const float* __restrict__ inb, const float* __restrict__ ing,
                                               const float* __restrict__ inbeta,
                                               ushort_t* __restrict__ Wlt, ushort_t* __restrict__ Wrt,
                                               u64* __restrict__ packed, int* __restrict__ rank,
                                               float* __restrict__ h, ushort_t* __restrict__ hb) {
    int b = blockIdx.x, t = threadIdx.x;
    if (b < CNT_B) {                  // ---- edge count: 1 packed u64 atomic per edge
        int i = b * 256 + t;
        int dst = ei[EE + i];
        unsigned int wfix = __float2uint_rn(ew[i] * 16777216.0f);
        u64 old = atomicAdd(&packed[dst], (1ULL << 44) | (u64)wfix);
        rank[i] = (int)(old >> 44);
        return;
    }
    if (b < CNT_B + WCV_B) {          // ---- weight transpose+cvt: Wlt[l][n*128+k] = W[l][k*128+n]
        int i = (b - CNT_B) * 256 + t;
        int l = i >> 14, r = i & 16383, nn2 = r >> 7, k = r & 127;
        Wlt[i] = f2b(gWl[(size_t)l * 16384 + k * 128 + nn2]);
        Wrt[i] = f2b(gWr[(size_t)l * 16384 + k * 128 + nn2]);
        return;
    }
    // ---- input projection: GELU(x@inW + b) then LN, K=64, inline f32->bf16 cvt
    __shared__ float s1[2][128], s2[2][128];
    int bidx = b - CNT_B - WCV_B;
    int lane = t & 63, w = t >> 6;
    int rw = w >> 1, cw = w & 1;
    int q = lane >> 4, l16 = lane & 15;
    int row0 = bidx * 128 + rw * 64;
    int col0 = cw * 64;

    bf8 bfr[2][4];
#pragma unroll
    for (int kk = 0; kk < 2; ++kk)
#pragma unroll
        for (int j = 0; j < 4; ++j) {
            int col = col0 + j * 16 + l16;
            int k0 = kk * 32 + q * 8;
            bf8 f;
#pragma unroll
            for (int e = 0; e < 8; ++e) f[e] = (short)f2b(inW[(size_t)(k0 + e) * HID + col]);
            bfr[kk][j] = f;
        }

    f4 acc[4][4];
#pragma unroll
    for (int i = 0; i < 4; ++i)
#pragma unroll
        for (int j = 0; j < 4; ++j) acc[i][j] = (f4)(0.f);

#pragma unroll
    for (int kk = 0; kk < 2; ++kk) {
        bf8 af[4];
#pragma unroll
        for (int i = 0; i < 4; ++i) {
            int r = row0 + i * 16 + l16;
            bf8 f;
            if (r < NN) {
                const float* xp = x + (size_t)r * 64 + kk * 32 + q * 8;
                f4 lo = *(const f4*)xp, hi = *(const f4*)(xp + 4);
                f[0] = (short)f2b(lo.x); f[1] = (short)f2b(lo.y);
                f[2] = (short)f2b(lo.z); f[3] = (short)f2b(lo.w);
                f[4] = (short)f2b(hi.x); f[5] = (short)f2b(hi.y);
                f[6] = (short)f2b(hi.z); f[7] = (short)f2b(hi.w);
            } else {
                for (int e = 0; e < 8; ++e) f[e] = 0;
            }
            af[i] = f;
        }
#pragma unroll
        for (int i = 0; i < 4; ++i)
#pragma unroll
            for (int j = 0; j < 4; ++j)
                acc[i][j] = __builtin_amdgcn_mfma_f32_16x16x32_bf16(af[i], bfr[kk][j], acc[i][j], 0, 0, 0);
    }
#pragma unroll
    for (int i = 0; i < 4; ++i) {
#pragma unroll
        for (int j = 0; j < 4; ++j) {
            float bv = inb[col0 + j * 16 + l16];
#pragma unroll
            for (int r = 0; r < 4; ++r) {
                float v = acc[i][j][r] + bv;
                v = 0.5f * v * (1.f + erff(v * 0.70710678118654752f));
                acc[i][j][r] = v;
            }
        }
    }
#pragma unroll
    for (int i = 0; i < 4; ++i) {
#pragma unroll
        for (int r = 0; r < 4; ++r) {
            float sm = acc[i][0][r] + acc[i][1][r] + acc[i][2][r] + acc[i][3][r];
            float sq = acc[i][0][r] * acc[i][0][r] + acc[i][1][r] * acc[i][1][r]
                     + acc[i][2][r] * acc[i][2][r] + acc[i][3][r] * acc[i][3][r];
#pragma unroll
            for (int k = 1; k < 16; k <<= 1) { sm += __shfl_xor(sm, k); sq += __shfl_xor(sq, k); }
            if (l16 == 0) {
                int rl = rw * 64 + i * 16 + q * 4 + r;
                s1[cw][rl] = sm; s2[cw][rl] = sq;
            }
        }
    }
    __syncthreads();
#pragma unroll
    for (int i = 0; i < 4; ++i) {
#pragma unroll
        for (int r = 0; r < 4; ++r) {
            int rl = rw * 64 + i * 16 + q * 4 + r;
            int gr = bidx * 128 + rl;
            if (gr >= NN) continue;
            float sm = s1[0][rl] + s1[1][rl];
            float sq = s2[0][rl] + s2[1][rl];
            float mu = sm * (1.f / 128.f);
            float var = sq * (1.f / 128.f) - mu * mu;
            float rinv = rsqrtf(var + 1e-5f);
#pragma unroll
            for (int j = 0; j < 4; ++j) {
                int gc = col0 + j * 16 + l16;
                float v = (acc[i][j][r] - mu) * rinv * ing[gc] + inbeta[gc];
                h[(size_t)gr * HID + gc] = v;
                hb[(size_t)gr * HID + gc] = f2b(v);
            }
        }
    }
}

// per-256-chunk sums of (deg+1)
__global__ __launch_bounds__(256) void k_psum(const u64* __restrict__ packed, int* __restrict__ bsum) {
    int t = threadIdx.x, bidx = blockIdx.x;
    int i = bidx * 256 + t;
    int v = (i < NN) ? (int)(packed[i] >> 44) + 1 : 0;
#pragma unroll
    for (int d = 1; d < 64; d <<= 1) v += __shfl_xor(v, d);
    __shared__ int ws4[4];
    if ((t & 63) == 0) ws4[t >> 6] = v;
    __syncthreads();
    if (t == 0) bsum[bidx] = ws4[0] + ws4[1] + ws4[2] + ws4[3];
}

__global__ __launch_bounds__(256) void k_scanb(const int* __restrict__ bsum,
                                               int* __restrict__ bbase, int* __restrict__ offs) {
    __shared__ int s[256];
    int t = threadIdx.x;
    int v = (t < NBL) ? bsum[t] : 0;
    s[t] = v;
    __syncthreads();
    for (int d = 1; d < 256; d <<= 1) {
        int u = (t >= d) ? s[t - d] : 0;
        __syncthreads();
        s[t] += u;
        __syncthreads();
    }
    if (t < NBL) bbase[t] = s[t] - v;    // exclusive base
    if (t == 0) offs[NN] = ET;
}

__global__ __launch_bounds__(256) void k_offs(const u64* __restrict__ packed,
                                              const int* __restrict__ bbase, int* __restrict__ offs) {
    __shared__ int wsum4[4];
    int t = threadIdx.x, bidx = blockIdx.x;
    int i = bidx * 256 + t;
    int v = (i < NN) ? (int)(packed[i] >> 44) + 1 : 0;
    int lane = t & 63, w = t >> 6;
    int sc = v;
#pragma unroll
    for (int d = 1; d < 64; d <<= 1) {
        int u = __shfl_up(sc, d);
        if (lane >= d) sc += u;
    }
    if (lane == 63) wsum4[w] = sc;
    __syncthreads();
    int wo = 0;
    for (int k = 0; k < w; ++k) wo += wsum4[k];
    if (i < NN) offs[i] = bbase[bidx] + wo + sc - v;
}

// ---------------------------------------------------------------- bf16 MFMA dual GEMM (K=128) + optional fused scatter
// blocks [0,GEMB): xlb ; [GEMB,2*GEMB): xrb ; >= 2*GEMB: CSR scatter (layer 0).
__global__ __launch_bounds__(256) void k_gemm2(const ushort_t* __restrict__ A,
                                               const ushort_t* __restrict__ Wt0,
                                               const ushort_t* __restrict__ Wt1,
                                               const float* __restrict__ b0,
                                               const float* __restrict__ b1,
                                               ushort_t* __restrict__ o0,
                                               ushort_t* __restrict__ o1, int n,
                                               const int* __restrict__ ei,
                                               const float* __restrict__ ew,
                                               const int* __restrict__ offs,
                                               const u64* __restrict__ packed,
                                               const int* __restrict__ rank,
                                               int2* __restrict__ csr) {
    int bid = blockIdx.x;
    if (bid >= 2 * GEMB) {
        int i = (bid - 2 * GEMB) * 256 + threadIdx.x;
        if (i < EE) {
            int src = ei[i], dst = ei[EE + i];
            int pos = offs[dst] + rank[i];
            int2 v; v.x = src; v.y = __float_as_int(ew[i]);
            csr[pos] = v;
        } else if (i < ET) {
            int nd = i - EE;
            u64 p = packed[nd];
            int deg = (int)(p >> 44);
            float wsf = (float)(p & ((1ULL << 44) - 1)) * (1.0f / 16777216.0f);
            float la = wsf / fmaxf((float)deg, 1.0f);
            int pos = offs[nd + 1] - 1;
            int2 v; v.x = nd; v.y = __float_as_int(la);
            csr[pos] = v;
        }
        return;
    }
    const int K = 128;
    int by = (bid >= GEMB) ? 1 : 0;
    int bx = by ? bid - GEMB : bid;
    const ushort_t* Wt = by ? Wt1 : Wt0;
    const float* bias = by ? b1 : b0;
    ushort_t* outb = by ? o1 : o0;
    int lane = threadIdx.x & 63, w = threadIdx.x >> 6;
    int rw = w >> 1, cw = w & 1;
    int q = lane >> 4, l16 = lane & 15;
    int row0 = bx * 128 + rw * 64;
    int col0 = cw * 64;
    bf8 z; for (int t = 0; t < 8; ++t) z[t] = 0;

    bf8 bfr[4][4];
#pragma unroll
    for (int kk = 0; kk < 4; ++kk)
#pragma unroll
        for (int j = 0; j < 4; ++j)
            bfr[kk][j] = *(const bf8*)(Wt + (size_t)(col0 + j * 16 + l16) * K + kk * 32 + q * 8);

    f4 acc[4][4];
#pragma unroll
    for (int i = 0; i < 4; ++i)
#pragma unroll
        for (int j = 0; j < 4; ++j) acc[i][j] = (f4)(0.f);

#pragma unroll
    for (int kk = 0; kk < 4; ++kk) {
        bf8 af[4];
#pragma unroll
        for (int i = 0; i < 4; ++i) {
            int r = row0 + i * 16 + l16;
            af[i] = (r < n) ? *(const bf8*)(A + (size_t)r * K + kk * 32 + q * 8) : z;
        }
#pragma unroll
        for (int i = 0; i < 4; ++i)
#pragma unroll
            for (int j = 0; j < 4; ++j)
                acc[i][j] = __builtin_amdgcn_mfma_f32_16x16x32_bf16(af[i], bfr[kk][j], acc[i][j], 0, 0, 0);
    }
#pragma unroll
    for (int i = 0; i < 4; ++i) {
        int gr0 = row0 + i * 16 + q * 4;
#pragma unroll
        for (int j = 0; j < 4; ++j) {
            int gc = col0 + j * 16 + l16;
            float bv = bias[gc];
#pragma unroll
            for (int r = 0; r < 4; ++r) {
                int gr = gr0 + r;
                if (gr < n) outb[(size_t)gr * HID + gc] = f2b(acc[i][j][r] + bv);
            }
        }
    }
}

// ---------------------------------------------------------------- GATv2 attention (packed-f32 VALU)
// wave per dst node; 16 lanes = one edge (lane = head, DH=8 in-lane); 4 edges/step.
__global__ __launch_bounds__(256) void k_attn(const ushort_t* __restrict__ xl,
                                              const ushort_t* __restrict__ xr,
                                              float* __restrict__ h,
                                              ushort_t* __restrict__ hb,
                                              const int* __restrict__ offs,
                                              const int2* __restrict__ csr,
                                              const float* __restrict__ We,
                                              const float* __restrict__ att,
                                              const float* __restrict__ gbias,
                                              const float* __restrict__ g,
                                              const float* __restrict__ b) {
    int wid = (blockIdx.x * 256 + threadIdx.x) >> 6;
    int lane = threadIdx.x & 63;
    if (wid >= NN) return;
    int hd = lane & 15;          // head index (16 heads; DH=8 in-lane)
    int grp = lane >> 4;         // edge subgroup 0..3
    int dbase = hd * 8;
    size_t base = (size_t)wid * HID;

    f2 xr2[4], at2[4], we2[4];
    {
        u4 uxr = *(const u4*)(xr + base + dbase);
        xr2[0] = b2f2v(uxr.x); xr2[1] = b2f2v(uxr.y);
        xr2[2] = b2f2v(uxr.z); xr2[3] = b2f2v(uxr.w);
        f4 a0 = *(const f4*)(att + dbase), a1 = *(const f4*)(att + dbase + 4);
        at2[0].x = a0.x; at2[0].y = a0.y; at2[1].x = a0.z; at2[1].y = a0.w;
        at2[2].x = a1.x; at2[2].y = a1.y; at2[3].x = a1.z; at2[3].y = a1.w;
        f4 w0 = *(const f4*)(We + dbase), w1 = *(const f4*)(We + dbase + 4);
        we2[0].x = w0.x; we2[0].y = w0.y; we2[1].x = w0.z; we2[1].y = w0.w;
        we2[2].x = w1.x; we2[2].y = w1.y; we2[3].x = w1.z; we2[3].y = w1.w;
    }
    int p0 = offs[wid], p1 = offs[wid + 1];
    float Z = 0.f;
    f2 acc2[4];
#pragma unroll
    for (int q = 0; q < 4; ++q) { acc2[q].x = 0.f; acc2[q].y = 0.f; }

#define QUAD(EJ, MASKED)                                                        \
    {                                                                           \
        int ei_ = (EJ) + grp;                                                   \
        int s_ = __shfl(sv, ei_);                                               \
        float ea_ = __shfl(evl, ei_);                                           \
        bool val_ = MASKED ? (ei_ < mm) : true;                                 \
        u4 ux_ = *(const u4*)(xl + (size_t)s_ * HID + dbase);                   \
        f2 x2_[4];                                                              \
        x2_[0] = b2f2v(ux_.x); x2_[1] = b2f2v(ux_.y);                           \
        x2_[2] = b2f2v(ux_.z); x2_[3] = b2f2v(ux_.w);                           \
        f2 lg2_; lg2_.x = 0.f; lg2_.y = 0.f;                                    \
        _Pragma("unroll")                                                       \
        for (int q_ = 0; q_ < 4; ++q_) {                                        \
            f2 t_ = (x2_[q_] + xr2[q_]) + ea_ * we2[q_];                        \
            t_ = max2(t_, t_ * 0.2f);                                           \
            lg2_ += at2[q_] * t_;                                               \
        }                                                                       \
        float w_ = val_ ? __expf(lg2_.x + lg2_.y) : 0.f;                        \
        Z += w_;                                                                \
        _Pragma("unroll")                                                       \
        for (int q_ = 0; q_ < 4; ++q_) acc2[q_] += w_ * x2_[q_];                \
    }

    for (int cb = p0; cb < p1; cb += 64) {
        int mm = min(64, p1 - cb);
        int2 m2 = (lane < mm) ? csr[cb + lane] : make_int2(0, 0);
        int sv = m2.x;
        float evl = __int_as_float(m2.y);
        int j = 0;
        for (; j + 8 <= mm; j += 8) { QUAD(j, false) QUAD(j + 4, false) }
        for (; j < mm; j += 4) QUAD(j, true)
    }
#undef QUAD

    // combine the 4 edge subgroups
    Z += __shfl_xor(Z, 16); Z += __shfl_xor(Z, 32);
#pragma unroll
    for (int q = 0; q < 4; ++q) {
        acc2[q].x += __shfl_xor(acc2[q].x, 16);
        acc2[q].x += __shfl_xor(acc2[q].x, 32);
        acc2[q].y += __shfl_xor(acc2[q].y, 16);
        acc2[q].y += __shfl_xor(acc2[q].y, 32);
    }
    float inv = 1.f / (Z + 1e-16f);
    float acc[8] = {acc2[0].x, acc2[0].y, acc2[1].x, acc2[1].y,
                    acc2[2].x, acc2[2].y, acc2[3].x, acc2[3].y};

    // residual + LN over the 128 dims held by the 16 head-lanes
    f4 hv0 = *(const f4*)(h + base + dbase);
    f4 hv1 = *(const f4*)(h + base + dbase + 4);
    float hres[8] = {hv0.x, hv0.y, hv0.z, hv0.w, hv1.x, hv1.y, hv1.z, hv1.w};
    f4 gb0 = *(const f4*)(gbias + dbase), gb1 = *(const f4*)(gbias + dbase + 4);
    float gb8[8] = {gb0.x, gb0.y, gb0.z, gb0.w, gb1.x, gb1.y, gb1.z, gb1.w};
    float o[8], sm = 0.f, sq = 0.f;
#pragma unroll
    for (int q = 0; q < 8; ++q) {
        o[q] = acc[q] * inv + gb8[q] + hres[q];
        sm += o[q]; sq += o[q] * o[q];
    }
#pragma unroll
    for (int k = 1; k < 16; k <<= 1) { sm += __shfl_xor(sm, k); sq += __shfl_xor(sq, k); }
    float mu = sm * (1.f / 128.f);
    float var = sq * (1.f / 128.f) - mu * mu;
    float rinv = rsqrtf(var + 1e-5f);
    f4 g0 = *(const f4*)(g + dbase), g1 = *(const f4*)(g + dbase + 4);
    float g8[8] = {g0.x, g0.y, g0.z, g0.w, g1.x, g1.y, g1.z, g1.w};
    f4 b0 = *(const f4*)(b + dbase), b1 = *(const f4*)(b + dbase + 4);
    float b8[8] = {b0.x, b0.y, b0.z, b0.w, b1.x, b1.y, b1.z, b1.w};
    float v8[8];
#pragma unroll
    for (int q = 0; q < 8; ++q) v8[q] = (o[q] - mu) * rinv * g8[q] + b8[q];
    if (grp == 0) {
        f4 s0 = {v8[0], v8[1], v8[2], v8[3]};
        f4 s1 = {v8[4], v8[5], v8[6], v8[7]};
        *(f4*)(h + base + dbase) = s0;
        *(f4*)(h + base + dbase + 4) = s1;
        u4 hu;
        hu.x = pk2(v8[0], v8[1]); hu.y = pk2(v8[2], v8[3]);
        hu.z = pk2(v8[4], v8[5]); hu.w = pk2(v8[6], v8[7]);
        *(u4*)(hb + base + dbase) = hu;
    }
}

// ---------------------------------------------------------------- per-store partial sums (no global atomics)
__global__ __launch_bounds__(256) void k_store_sum(const float* __restrict__ h,
                                                   const int* __restrict__ mask,
                                                   float* __restrict__ psums,   // [SSB][NSTORE*HID]
                                                   int* __restrict__ pcnts) {   // [SSB][NSTORE]
    __shared__ float ls[NSTORE * HID];
    __shared__ int lc[NSTORE];
    int t = threadIdx.x, bidx = blockIdx.x;
    for (int i = t; i < NSTORE * HID; i += 256) ls[i] = 0.f;
    if (t < NSTORE) lc[t] = 0;
    __syncthreads();
    int wid = bidx * 4 + (t >> 6);
    int lane = t & 63;
    int nw = SSB * 4;
    int d0 = lane * 2;
    for (int node = wid; node < NN; node += nw) {
        int s = mask[node];
        float2 hv = *(const float2*)(h + (size_t)node * HID + d0);
        atomicAdd(&ls[s * HID + d0], hv.x);
        atomicAdd(&ls[s * HID + d0 + 1], hv.y);
        if (lane == 0) atomicAdd(&lc[s], 1);
    }
    __syncthreads();
    for (int i = t; i < NSTORE * HID; i += 256) psums[(size_t)bidx * (NSTORE * HID) + i] = ls[i];
    if (t < NSTORE) pcnts[bidx * NSTORE + t] = lc[t];
}

// ---------------------------------------------------------------- gate (parallel reduction of partials)
__global__ __launch_bounds__(256) void k_gate(const float* __restrict__ psums,
                                              const int* __restrict__ pcnts,
                                              const float* __restrict__ ctxW,
                                              const float* __restrict__ ctxb,
                                              float* __restrict__ gm) {
    __shared__ float h1[HID];
    __shared__ float mloc[HID];
    __shared__ int cw4[4];
    int s = blockIdx.x, t = threadIdx.x;
    int d = t & 127, half = t >> 7;
    float s0 = 0.f, s1 = 0.f, s2 = 0.f, s3 = 0.f;
    for (int b = half * 4; b < SSB; b += 8) {
        s0 += psums[(size_t)(b + 0) * (NSTORE * HID) + s * HID + d];
        s1 += psums[(size_t)(b + 1) * (NSTORE * HID) + s * HID + d];
        s2 += psums[(size_t)(b + 2) * (NSTORE * HID) + s * HID + d];
        s3 += psums[(size_t)(b + 3) * (NSTORE * HID) + s * HID + d];
    }
    float sum = (s0 + s1) + (s2 + s3);
    int c = pcnts[t * NSTORE + s] + pcnts[(t + 256) * NSTORE + s];
#pragma unroll
    for (int k = 1; k < 64; k <<= 1) c += __shfl_xor(c, k);
    if ((t & 63) == 0) cw4[t >> 6] = c;
    if (half) h1[d] = sum;
    __syncthreads();
    if (half == 0) {
        float tot = sum + h1[d];
        float cnt = fmaxf((float)(cw4[0] + cw4[1] + cw4[2] + cw4[3]), 1.f);
        mloc[d] = tot / cnt;
    }
    __syncthreads();
    if (half == 0) {
        float acc = ctxb[d];
        for (int j = 0; j < HID; ++j) acc += mloc[j] * ctxW[j * HID + d];
        float gate = 1.f / (1.f + __expf(-acc));
        gm[s * HID + d] = gate * mloc[d];
    }
}

// ---------------------------------------------------------------- final: out = LN(h + gm[store])
__global__ __launch_bounds__(256) void k_final(const float* __restrict__ h,
                                               const int* __restrict__ mask,
                                               const float* __restrict__ gm,
                                               const float* __restrict__ g,
                                               const float* __restrict__ b,
                                               float* __restrict__ out) {
    int wid = (blockIdx.x * 256 + threadIdx.x) >> 6;
    int lane = threadIdx.x & 63;
    if (wid >= NN) return;
    size_t base = (size_t)wid * HID;
    int s = mask[wid];
    int d0 = lane * 2, d1 = d0 + 1;
    float v0 = h[base + d0] + gm[s * HID + d0];
    float v1 = h[base + d1] + gm[s * HID + d1];
    float sm = v0 + v1, sq = v0 * v0 + v1 * v1;
#pragma unroll
    for (int k = 1; k < 64; k <<= 1) { sm += __shfl_xor(sm, k); sq += __shfl_xor(sq, k); }
    float mu = sm * (1.f / 128.f);
    float var = sq * (1.f / 128.f) - mu * mu;
    float r = rsqrtf(var + 1e-5f);
    out[base + d0] = (v0 - mu) * r * g[d0] + b[d0];
    out[base + d1] = (v1 - mu) * r * g[d1] + b[d1];
}

// ---------------------------------------------------------------- launch
extern "C" void kernel_launch(void* const* d_in, const int* in_sizes, int n_in,
                              void* d_out, int out_size, void* d_ws, size_t ws_size,
                              hipStream_t stream) {
    const float* x      = (const float*)d_in[0];
    const int*   ei     = (const int*)d_in[1];
    const float* ew     = (const float*)d_in[2];
    const int*   smask  = (const int*)d_in[3];
    const float* inW    = (const float*)d_in[4];
    const float* inb    = (const float*)d_in[5];
    const float* ing    = (const float*)d_in[6];
    const float* inbeta = (const float*)d_in[7];
    const float* gWl    = (const float*)d_in[8];
    const float* gbl    = (const float*)d_in[9];
    const float* gWr    = (const float*)d_in[10];
    const float* gbr    = (const float*)d_in[11];
    const float* gWe    = (const float*)d_in[12];
    const float* gatt   = (const float*)d_in[13];
    const float* gbias  = (const float*)d_in[14];
    const float* blkg   = (const float*)d_in[15];
    const float* blkb   = (const float*)d_in[16];
    const float* ctxW   = (const float*)d_in[17];
    const float* ctxb   = (const float*)d_in[18];
    const float* fing   = (const float*)d_in[19];
    const float* finb   = (const float*)d_in[20];
    float* out = (float*)d_out;

    float* ws = (float*)d_ws;
    size_t o = 0;
    float*    h      = ws + o;              o += (size_t)NN * HID;
    int2*     csr    = (int2*)(ws + o);     o += (size_t)ET * 2;
    float*    gm     = ws + o;              o += NSTORE * HID;
    int*      offs   = (int*)(ws + o);      o += 50004;
    int*      rank   = (int*)(ws + o);      o += EE;
    ushort_t* hb     = (ushort_t*)(ws + o); o += (size_t)NN * HID / 2;
    ushort_t* xlb    = (ushort_t*)(ws + o); o += (size_t)NN * HID / 2;
    ushort_t* xrb    = (ushort_t*)(ws + o); o += (size_t)NN * HID / 2;
    ushort_t* Wlt    = (ushort_t*)(ws + o); o += 3 * 128 * 128 / 2;
    ushort_t* Wrt    = (ushort_t*)(ws + o); o += 3 * 128 * 128 / 2;
    int*      bsum   = (int*)(ws + o);      o += 256;
    int*      bbase  = (int*)(ws + o);      o += 256;
    float*    psums  = ws + o;              o += (size_t)SSB * NSTORE * HID;
    int*      pcnts  = (int*)(ws + o);      o += SSB * NSTORE;
    if (o & 1) ++o;
    float*    zbase  = ws + o;
    u64*      packed = (u64*)(ws + o);      o += (size_t)NN * 2;
    size_t zbytes = (size_t)(NN * 2) * 4;

    hipMemsetAsync((void*)zbase, 0, zbytes, stream);

    const int WB = NN / 4;                    // wave-per-node kernels

    k_build<<<CNT_B + WCV_B + GEMB, 256, 0, stream>>>(x, inW, gWl, gWr, ei, ew,
                                                      inb, ing, inbeta,
                                                      Wlt, Wrt, packed, rank, h, hb);
    k_psum<<<NBL, 256, 0, stream>>>(packed, bsum);
    k_scanb<<<1, 256, 0, stream>>>(bsum, bbase, offs);
    k_offs<<<NBL, 256, 0, stream>>>(packed, bbase, offs);

    for (int l = 0; l < 3; ++l) {
        int nb = 2 * GEMB + (l == 0 ? SCT_B : 0);   // layer 0 carries the CSR scatter blocks
        k_gemm2<<<nb, 256, 0, stream>>>(hb, Wlt + (size_t)l * HID * HID, Wrt + (size_t)l * HID * HID,
                                        gbl + l * HID, gbr + l * HID, xlb, xrb, NN,
                                        ei, ew, offs, packed, rank, csr);
        k_attn<<<WB, 256, 0, stream>>>(xlb, xrb, h, hb, offs, csr,
                                       gWe + l * HID, gatt + l * HID, gbias + l * HID,
                                       blkg + l * HID, blkb + l * HID);
    }

    k_store_sum<<<SSB, 256, 0, stream>>>(h, smask, psums, pcnts);
    k_gate<<<NSTORE, 256, 0, stream>>>(psums, pcnts, ctxW, ctxb, gm);
    k_final<<<WB, 256, 0, stream>>>(h, smask, gm, fing, finb, out);
}

// Round 10
// 518.159 us; speedup vs baseline: 1.1881x; 1.0007x over previous
//
#include <hip/hip_runtime.h>
#include <math.h>

#define NN 50000
#define EE 800000
#define ET (EE + NN)
#define HID 128
#define NSTORE 50
#define NBL 196                      // ceil(NN/256)
#define CNT_B 3125                   // EE/256
#define WCV_B 192                    // 3*128*128/256 weight cvt blocks
#define SCT_B 3321                   // ceil(ET/256)
#define GEMB 391                     // ceil(NN/128) gemm tiles
#define SSB 512                      // store-sum partial blocks (2 blocks/CU)

typedef unsigned short ushort_t;
typedef unsigned long long u64;
typedef __attribute__((ext_vector_type(8))) short bf8;
typedef __attribute__((ext_vector_type(4))) float f4;
typedef __attribute__((ext_vector_type(2))) float f2;
typedef __attribute__((ext_vector_type(4))) unsigned int u4;

__device__ __forceinline__ ushort_t f2b(float f) {
    union { float f; unsigned int i; } v; v.f = f;
    unsigned int r = (v.i + 0x7fffu + ((v.i >> 16) & 1u)) >> 16;
    return (ushort_t)r;
}
__device__ __forceinline__ f2 b2f2v(unsigned int u) {
    union { unsigned int i; float f; } lo, hi;
    lo.i = u << 16; hi.i = u & 0xffff0000u;
    f2 r; r.x = lo.f; r.y = hi.f; return r;
}
__device__ __forceinline__ unsigned int pk2(float lo, float hi) {
    return (unsigned int)f2b(lo) | ((unsigned int)f2b(hi) << 16);
}
__device__ __forceinline__ f2 max2(f2 a, f2 b) {
#if __has_builtin(__builtin_elementwise_max)
    return __builtin_elementwise_max(a, b);
#else
    f2 r; r.x = fmaxf(a.x, b.x); r.y = fmaxf(a.y, b.y); return r;
#endif
}

// ---------------------------------------------------------------- edge count (standalone, low VGPR, high occupancy)
// packed[dst]: bits 44+: degree; bits 0..43: sum(ew) in 2^24 fixed point.
__global__ __launch_bounds__(256) void k_count(const int* __restrict__ ei, const float* __restrict__ ew,
                                               u64* __restrict__ packed, int* __restrict__ rank) {
    int i = blockIdx.x * 256 + threadIdx.x;     // grid = CNT_B covers EE exactly
    int dst = ei[EE + i];
    unsigned int wfix = __float2uint_rn(ew[i] * 16777216.0f);
    u64 old = atomicAdd(&packed[dst], (1ULL << 44) | (u64)wfix);
    rank[i] = (int)(old >> 44);
}

// ---------------------------------------------------------------- prep: weight cvt + input projection (MFMA)
// blocks [0,WCV_B): Wlt[l][n*128+k] = W[l][k*128+n] ; blocks [WCV_B,..): inproj GELU+LN.
__global__ __launch_bounds__(256) void k_prep(const float* __restrict__ x, const float* __restrict__ inW,
                                              const float* __restrict__ gWl, const float* __restrict__ gWr,
                                              const float* __restrict__ inb, const float* __restrict__ ing,
                                              const float* __restrict__ inbeta,
                                              ushort_t* __restrict__ Wlt, ushort_t* __restrict__ Wrt,
                                              float* __restrict__ h, ushort_t* __restrict__ hb) {
    int b = blockIdx.x, t = threadIdx.x;
    if (b < WCV_B) {                  // ---- weight transpose+cvt
        int i = b * 256 + t;
        int l = i >> 14, r = i & 16383, nn2 = r >> 7, k = r & 127;
        Wlt[i] = f2b(gWl[(size_t)l * 16384 + k * 128 + nn2]);
        Wrt[i] = f2b(gWr[(size_t)l * 16384 + k * 128 + nn2]);
        return;
    }
    // ---- input projection: GELU(x@inW + b) then LN, K=64, inline f32->bf16 cvt
    __shared__ float s1[2][128], s2[2][128];
    int bidx = b - WCV_B;
    int lane = t & 63, w = t >> 6;
    int rw = w >> 1, cw = w & 1;
    int q = lane >> 4, l16 = lane & 15;
    int row0 = bidx * 128 + rw * 64;
    int col0 = cw * 64;

    bf8 bfr[2][4];
#pragma unroll
    for (int kk = 0; kk < 2; ++kk)
#pragma unroll
        for (int j = 0; j < 4; ++j) {
            int col = col0 + j * 16 + l16;
            int k0 = kk * 32 + q * 8;
            bf8 f;
#pragma unroll
            for (int e = 0; e < 8; ++e) f[e] = (short)f2b(inW[(size_t)(k0 + e) * HID + col]);
            bfr[kk][j] = f;
        }

    f4 acc[4][4];
#pragma unroll
    for (int i = 0; i < 4; ++i)
#pragma unroll
        for (int j = 0; j < 4; ++j) acc[i][j] = (f4)(0.f);

#pragma unroll
    for (int kk = 0; kk < 2; ++kk) {
        bf8 af[4];
#pragma unroll
        for (int i = 0; i < 4; ++i) {
            int r = row0 + i * 16 + l16;
            bf8 f;
            if (r < NN) {
                const float* xp = x + (size_t)r * 64 + kk * 32 + q * 8;
                f4 lo = *(const f4*)xp, hi = *(const f4*)(xp + 4);
                f[0] = (short)f2b(lo.x); f[1] = (short)f2b(lo.y);
                f[2] = (short)f2b(lo.z); f[3] = (short)f2b(lo.w);
                f[4] = (short)f2b(hi.x); f[5] = (short)f2b(hi.y);
                f[6] = (short)f2b(hi.z); f[7] = (short)f2b(hi.w);
            } else {
                for (int e = 0; e < 8; ++e) f[e] = 0;
            }
            af[i] = f;
        }
#pragma unroll
        for (int i = 0; i < 4; ++i)
#pragma unroll
            for (int j = 0; j < 4; ++j)
                acc[i][j] = __builtin_amdgcn_mfma_f32_16x16x32_bf16(af[i], bfr[kk][j], acc[i][j], 0, 0, 0);
    }
#pragma unroll
    for (int i = 0; i < 4; ++i) {
#pragma unroll
        for (int j = 0; j < 4; ++j) {
            float bv = inb[col0 + j * 16 + l16];
#pragma unroll
            for (int r = 0; r < 4; ++r) {
                float v = acc[i][j][r] + bv;
                v = 0.5f * v * (1.f + erff(v * 0.70710678118654752f));
                acc[i][j][r] = v;
            }
        }
    }
#pragma unroll
    for (int i = 0; i < 4; ++i) {
#pragma unroll
        for (int r = 0; r < 4; ++r) {
            float sm = acc[i][0][r] + acc[i][1][r] + acc[i][2][r] + acc[i][3][r];
            float sq = acc[i][0][r] * acc[i][0][r] + acc[i][1][r] * acc[i][1][r]
                     + acc[i][2][r] * acc[i][2][r] + acc[i][3][r] * acc[i][3][r];
#pragma unroll
            for (int k = 1; k < 16; k <<= 1) { sm += __shfl_xor(sm, k); sq += __shfl_xor(sq, k); }
            if (l16 == 0) {
                int rl = rw * 64 + i * 16 + q * 4 + r;
                s1[cw][rl] = sm; s2[cw][rl] = sq;
            }
        }
    }
    __syncthreads();
#pragma unroll
    for (int i = 0; i < 4; ++i) {
#pragma unroll
        for (int r = 0; r < 4; ++r) {
            int rl = rw * 64 + i * 16 + q * 4 + r;
            int gr = bidx * 128 + rl;
            if (gr >= NN) continue;
            float sm = s1[0][rl] + s1[1][rl];
            float sq = s2[0][rl] + s2[1][rl];
            float mu = sm * (1.f / 128.f);
            float var = sq * (1.f / 128.f) - mu * mu;
            float rinv = rsqrtf(var + 1e-5f);
#pragma unroll
            for (int j = 0; j < 4; ++j) {
                int gc = col0 + j * 16 + l16;
                float v = (acc[i][j][r] - mu) * rinv * ing[gc] + inbeta[gc];
                h[(size_t)gr * HID + gc] = v;
                hb[(size_t)gr * HID + gc] = f2b(v);
            }
        }
    }
}

// per-256-chunk sums of (deg+1)
__global__ __launch_bounds__(256) void k_psum(const u64* __restrict__ packed, int* __restrict__ bsum) {
    int t = threadIdx.x, bidx = blockIdx.x;
    int i = bidx * 256 + t;
    int v = (i < NN) ? (int)(packed[i] >> 44) + 1 : 0;
#pragma unroll
    for (int d = 1; d < 64; d <<= 1) v += __shfl_xor(v, d);
    __shared__ int ws4[4];
    if ((t & 63) == 0) ws4[t >> 6] = v;
    __syncthreads();
    if (t == 0) bsum[bidx] = ws4[0] + ws4[1] + ws4[2] + ws4[3];
}

__global__ __launch_bounds__(256) void k_scanb(const int* __restrict__ bsum,
                                               int* __restrict__ bbase, int* __restrict__ offs) {
    __shared__ int s[256];
    int t = threadIdx.x;
    int v = (t < NBL) ? bsum[t] : 0;
    s[t] = v;
    __syncthreads();
    for (int d = 1; d < 256; d <<= 1) {
        int u = (t >= d) ? s[t - d] : 0;
        __syncthreads();
        s[t] += u;
        __syncthreads();
    }
    if (t < NBL) bbase[t] = s[t] - v;    // exclusive base
    if (t == 0) offs[NN] = ET;
}

__global__ __launch_bounds__(256) void k_offs(const u64* __restrict__ packed,
                                              const int* __restrict__ bbase, int* __restrict__ offs) {
    __shared__ int wsum4[4];
    int t = threadIdx.x, bidx = blockIdx.x;
    int i = bidx * 256 + t;
    int v = (i < NN) ? (int)(packed[i] >> 44) + 1 : 0;
    int lane = t & 63, w = t >> 6;
    int sc = v;
#pragma unroll
    for (int d = 1; d < 64; d <<= 1) {
        int u = __shfl_up(sc, d);
        if (lane >= d) sc += u;
    }
    if (lane == 63) wsum4[w] = sc;
    __syncthreads();
    int wo = 0;
    for (int k = 0; k < w; ++k) wo += wsum4[k];
    if (i < NN) offs[i] = bbase[bidx] + wo + sc - v;
}

// ---------------------------------------------------------------- bf16 MFMA dual GEMM (K=128) + optional fused scatter
// blocks [0,GEMB): xlb ; [GEMB,2*GEMB): xrb ; >= 2*GEMB: CSR scatter (layer 0).
__global__ __launch_bounds__(256) void k_gemm2(const ushort_t* __restrict__ A,
                                               const ushort_t* __restrict__ Wt0,
                                               const ushort_t* __restrict__ Wt1,
                                               const float* __restrict__ b0,
                                               const float* __restrict__ b1,
                                               ushort_t* __restrict__ o0,
                                               ushort_t* __restrict__ o1, int n,
                                               const int* __restrict__ ei,
                                               const float* __restrict__ ew,
                                               const int* __restrict__ offs,
                                               const u64* __restrict__ packed,
                                               const int* __restrict__ rank,
                                               int2* __restrict__ csr) {
    int bid = blockIdx.x;
    if (bid >= 2 * GEMB) {
        int i = (bid - 2 * GEMB) * 256 + threadIdx.x;
        if (i < EE) {
            int src = ei[i], dst = ei[EE + i];
            int pos = offs[dst] + rank[i];
            int2 v; v.x = src; v.y = __float_as_int(ew[i]);
            csr[pos] = v;
        } else if (i < ET) {
            int nd = i - EE;
            u64 p = packed[nd];
            int deg = (int)(p >> 44);
            float wsf = (float)(p & ((1ULL << 44) - 1)) * (1.0f / 16777216.0f);
            float la = wsf / fmaxf((float)deg, 1.0f);
            int pos = offs[nd + 1] - 1;
            int2 v; v.x = nd; v.y = __float_as_int(la);
            csr[pos] = v;
        }
        return;
    }
    const int K = 128;
    int by = (bid >= GEMB) ? 1 : 0;
    int bx = by ? bid - GEMB : bid;
    const ushort_t* Wt = by ? Wt1 : Wt0;
    const float* bias = by ? b1 : b0;
    ushort_t* outb = by ? o1 : o0;
    int lane = threadIdx.x & 63, w = threadIdx.x >> 6;
    int rw = w >> 1, cw = w & 1;
    int q = lane >> 4, l16 = lane & 15;
    int row0 = bx * 128 + rw * 64;
    int col0 = cw * 64;
    bf8 z; for (int t = 0; t < 8; ++t) z[t] = 0;

    bf8 bfr[4][4];
#pragma unroll
    for (int kk = 0; kk < 4; ++kk)
#pragma unroll
        for (int j = 0; j < 4; ++j)
            bfr[kk][j] = *(const bf8*)(Wt + (size_t)(col0 + j * 16 + l16) * K + kk * 32 + q * 8);

    f4 acc[4][4];
#pragma unroll
    for (int i = 0; i < 4; ++i)
#pragma unroll
        for (int j = 0; j < 4; ++j) acc[i][j] = (f4)(0.f);

#pragma unroll
    for (int kk = 0; kk < 4; ++kk) {
        bf8 af[4];
#pragma unroll
        for (int i = 0; i < 4; ++i) {
            int r = row0 + i * 16 + l16;
            af[i] = (r < n) ? *(const bf8*)(A + (size_t)r * K + kk * 32 + q * 8) : z;
        }
#pragma unroll
        for (int i = 0; i < 4; ++i)
#pragma unroll
            for (int j = 0; j < 4; ++j)
                acc[i][j] = __builtin_amdgcn_mfma_f32_16x16x32_bf16(af[i], bfr[kk][j], acc[i][j], 0, 0, 0);
    }
#pragma unroll
    for (int i = 0; i < 4; ++i) {
        int gr0 = row0 + i * 16 + q * 4;
#pragma unroll
        for (int j = 0; j < 4; ++j) {
            int gc = col0 + j * 16 + l16;
            float bv = bias[gc];
#pragma unroll
            for (int r = 0; r < 4; ++r) {
                int gr = gr0 + r;
                if (gr < n) outb[(size_t)gr * HID + gc] = f2b(acc[i][j][r] + bv);
            }
        }
    }
}

// ---------------------------------------------------------------- GATv2 attention (packed-f32 VALU)
__global__ __launch_bounds__(256) void k_attn(const ushort_t* __restrict__ xl,
                                              const ushort_t* __restrict__ xr,
                                              float* __restrict__ h,
                                              ushort_t* __restrict__ hb,
                                              const int* __restrict__ offs,
                                              const int2* __restrict__ csr,
                                              const float* __restrict__ We,
                                              const float* __restrict__ att,
                                              const float* __restrict__ gbias,
                                              const float* __restrict__ g,
                                              const float* __restrict__ b) {
    int wid = (blockIdx.x * 256 + threadIdx.x) >> 6;
    int lane = threadIdx.x & 63;
    if (wid >= NN) return;
    int hd = lane & 15;          // head index (16 heads; DH=8 in-lane)
    int grp = lane >> 4;         // edge subgroup 0..3
    int dbase = hd * 8;
    size_t base = (size_t)wid * HID;

    f2 xr2[4], at2[4], we2[4];
    {
        u4 uxr = *(const u4*)(xr + base + dbase);
        xr2[0] = b2f2v(uxr.x); xr2[1] = b2f2v(uxr.y);
        xr2[2] = b2f2v(uxr.z); xr2[3] = b2f2v(uxr.w);
        f4 a0 = *(const f4*)(att + dbase), a1 = *(const f4*)(att + dbase + 4);
        at2[0].x = a0.x; at2[0].y = a0.y; at2[1].x = a0.z; at2[1].y = a0.w;
        at2[2].x = a1.x; at2[2].y = a1.y; at2[3].x = a1.z; at2[3].y = a1.w;
        f4 w0 = *(const f4*)(We + dbase), w1 = *(const f4*)(We + dbase + 4);
        we2[0].x = w0.x; we2[0].y = w0.y; we2[1].x = w0.z; we2[1].y = w0.w;
        we2[2].x = w1.x; we2[2].y = w1.y; we2[3].x = w1.z; we2[3].y = w1.w;
    }
    int p0 = offs[wid], p1 = offs[wid + 1];
    float Z = 0.f;
    f2 acc2[4];
#pragma unroll
    for (int q = 0; q < 4; ++q) { acc2[q].x = 0.f; acc2[q].y = 0.f; }

#define QUAD(EJ, MASKED)                                                        \
    {                                                                           \
        int ei_ = (EJ) + grp;                                                   \
        int s_ = __shfl(sv, ei_);                                               \
        float ea_ = __shfl(evl, ei_);                                           \
        bool val_ = MASKED ? (ei_ < mm) : true;                                 \
        u4 ux_ = *(const u4*)(xl + (size_t)s_ * HID + dbase);                   \
        f2 x2_[4];                                                              \
        x2_[0] = b2f2v(ux_.x); x2_[1] = b2f2v(ux_.y);                           \
        x2_[2] = b2f2v(ux_.z); x2_[3] = b2f2v(ux_.w);                           \
        f2 lg2_; lg2_.x = 0.f; lg2_.y = 0.f;                                    \
        _Pragma("unroll")                                                       \
        for (int q_ = 0; q_ < 4; ++q_) {                                        \
            f2 t_ = (x2_[q_] + xr2[q_]) + ea_ * we2[q_];                        \
            t_ = max2(t_, t_ * 0.2f);                                           \
            lg2_ += at2[q_] * t_;                                               \
        }                                                                       \
        float w_ = val_ ? __expf(lg2_.x + lg2_.y) : 0.f;                        \
        Z += w_;                                                                \
        _Pragma("unroll")                                                       \
        for (int q_ = 0; q_ < 4; ++q_) acc2[q_] += w_ * x2_[q_];                \
    }

    for (int cb = p0; cb < p1; cb += 64) {
        int mm = min(64, p1 - cb);
        int2 m2 = (lane < mm) ? csr[cb + lane] : make_int2(0, 0);
        int sv = m2.x;
        float evl = __int_as_float(m2.y);
        int j = 0;
        for (; j + 8 <= mm; j += 8) { QUAD(j, false) QUAD(j + 4, false) }
        for (; j < mm; j += 4) QUAD(j, true)
    }
#undef QUAD

    Z += __shfl_xor(Z, 16); Z += __shfl_xor(Z, 32);
#pragma unroll
    for (int q = 0; q < 4; ++q) {
        acc2[q].x += __shfl_xor(acc2[q].x, 16);
        acc2[q].x += __shfl_xor(acc2[q].x, 32);
        acc2[q].y += __shfl_xor(acc2[q].y, 16);
        acc2[q].y += __shfl_xor(acc2[q].y, 32);
    }
    float inv = 1.f / (Z + 1e-16f);
    float acc[8] = {acc2[0].x, acc2[0].y, acc2[1].x, acc2[1].y,
                    acc2[2].x, acc2[2].y, acc2[3].x, acc2[3].y};

    f4 hv0 = *(const f4*)(h + base + dbase);
    f4 hv1 = *(const f4*)(h + base + dbase + 4);
    float hres[8] = {hv0.x, hv0.y, hv0.z, hv0.w, hv1.x, hv1.y, hv1.z, hv1.w};
    f4 gb0 = *(const f4*)(gbias + dbase), gb1 = *(const f4*)(gbias + dbase + 4);
    float gb8[8] = {gb0.x, gb0.y, gb0.z, gb0.w, gb1.x, gb1.y, gb1.z, gb1.w};
    float o[8], sm = 0.f, sq = 0.f;
#pragma unroll
    for (int q = 0; q < 8; ++q) {
        o[q] = acc[q] * inv + gb8[q] + hres[q];
        sm += o[q]; sq += o[q] * o[q];
    }
#pragma unroll
    for (int k = 1; k < 16; k <<= 1) { sm += __shfl_xor(sm, k); sq += __shfl_xor(sq, k); }
    float mu = sm * (1.f / 128.f);
    float var = sq * (1.f / 128.f) - mu * mu;
    float rinv = rsqrtf(var + 1e-5f);
    f4 g0 = *(const f4*)(g + dbase), g1 = *(const f4*)(g + dbase + 4);
    float g8[8] = {g0.x, g0.y, g0.z, g0.w, g1.x, g1.y, g1.z, g1.w};
    f4 b0 = *(const f4*)(b + dbase), b1 = *(const f4*)(b + dbase + 4);
    float b8[8] = {b0.x, b0.y, b0.z, b0.w, b1.x, b1.y, b1.z, b1.w};
    float v8[8];
#pragma unroll
    for (int q = 0; q < 8; ++q) v8[q] = (o[q] - mu) * rinv * g8[q] + b8[q];
    if (grp == 0) {
        f4 s0 = {v8[0], v8[1], v8[2], v8[3]};
        f4 s1 = {v8[4], v8[5], v8[6], v8[7]};
        *(f4*)(h + base + dbase) = s0;
        *(f4*)(h + base + dbase + 4) = s1;
        u4 hu;
        hu.x = pk2(v8[0], v8[1]); hu.y = pk2(v8[2], v8[3]);
        hu.z = pk2(v8[4], v8[5]); hu.w = pk2(v8[6], v8[7]);
        *(u4*)(hb + base + dbase) = hu;
    }
}

// ---------------------------------------------------------------- per-store partial sums (no global atomics)
__global__ __launch_bounds__(256) void k_store_sum(const float* __restrict__ h,
                                                   const int* __restrict__ mask,
                                                   float* __restrict__ psums,   // [SSB][NSTORE*HID]
                                                   int* __restrict__ pcnts) {   // [SSB][NSTORE]
    __shared__ float ls[NSTORE * HID];
    __shared__ int lc[NSTORE];
    int t = threadIdx.x, bidx = blockIdx.x;
    for (int i = t; i < NSTORE * HID; i += 256) ls[i] = 0.f;
    if (t < NSTORE) lc[t] = 0;
    __syncthreads();
    int wid = bidx * 4 + (t >> 6);
    int lane = t & 63;
    int nw = SSB * 4;
    int d0 = lane * 2;
    for (int node = wid; node < NN; node += nw) {
        int s = mask[node];
        float2 hv = *(const float2*)(h + (size_t)node * HID + d0);
        atomicAdd(&ls[s * HID + d0], hv.x);
        atomicAdd(&ls[s * HID + d0 + 1], hv.y);
        if (lane == 0) atomicAdd(&lc[s], 1);
    }
    __syncthreads();
    for (int i = t; i < NSTORE * HID; i += 256) psums[(size_t)bidx * (NSTORE * HID) + i] = ls[i];
    if (t < NSTORE) pcnts[bidx * NSTORE + t] = lc[t];
}

// ---------------------------------------------------------------- gate (parallel reduction of partials)
__global__ __launch_bounds__(256) void k_gate(const float* __restrict__ psums,
                                              const int* __restrict__ pcnts,
                                              const float* __restrict__ ctxW,
                                              const float* __restrict__ ctxb,
                                              float* __restrict__ gm) {
    __shared__ float h1[HID];
    __shared__ float mloc[HID];
    __shared__ int cw4[4];
    int s = blockIdx.x, t = threadIdx.x;
    int d = t & 127, half = t >> 7;
    float s0 = 0.f, s1 = 0.f, s2 = 0.f, s3 = 0.f;
    for (int b = half * 4; b < SSB; b += 8) {
        s0 += psums[(size_t)(b + 0) * (NSTORE * HID) + s * HID + d];
        s1 += psums[(size_t)(b + 1) * (NSTORE * HID) + s * HID + d];
        s2 += psums[(size_t)(b + 2) * (NSTORE * HID) + s * HID + d];
        s3 += psums[(size_t)(b + 3) * (NSTORE * HID) + s * HID + d];
    }
    float sum = (s0 + s1) + (s2 + s3);
    int c = pcnts[t * NSTORE + s] + pcnts[(t + 256) * NSTORE + s];
#pragma unroll
    for (int k = 1; k < 64; k <<= 1) c += __shfl_xor(c, k);
    if ((t & 63) == 0) cw4[t >> 6] = c;
    if (half) h1[d] = sum;
    __syncthreads();
    if (half == 0) {
        float tot = sum + h1[d];
        float cnt = fmaxf((float)(cw4[0] + cw4[1] + cw4[2] + cw4[3]), 1.f);
        mloc[d] = tot / cnt;
    }
    __syncthreads();
    if (half == 0) {
        float acc = ctxb[d];
        for (int j = 0; j < HID; ++j) acc += mloc[j] * ctxW[j * HID + d];
        float gate = 1.f / (1.f + __expf(-acc));
        gm[s * HID + d] = gate * mloc[d];
    }
}

// ---------------------------------------------------------------- final: out = LN(h + gm[store])
__global__ __launch_bounds__(256) void k_final(const float* __restrict__ h,
                                               const int* __restrict__ mask,
                                               const float* __restrict__ gm,
                                               const float* __restrict__ g,
                                               const float* __restrict__ b,
                                               float* __restrict__ out) {
    int wid = (blockIdx.x * 256 + threadIdx.x) >> 6;
    int lane = threadIdx.x & 63;
    if (wid >= NN) return;
    size_t base = (size_t)wid * HID;
    int s = mask[wid];
    int d0 = lane * 2, d1 = d0 + 1;
    float v0 = h[base + d0] + gm[s * HID + d0];
    float v1 = h[base + d1] + gm[s * HID + d1];
    float sm = v0 + v1, sq = v0 * v0 + v1 * v1;
#pragma unroll
    for (int k = 1; k < 64; k <<= 1) { sm += __shfl_xor(sm, k); sq += __shfl_xor(sq, k); }
    float mu = sm * (1.f / 128.f);
    float var = sq * (1.f / 128.f) - mu * mu;
    float r = rsqrtf(var + 1e-5f);
    out[base + d0] = (v0 - mu) * r * g[d0] + b[d0];
    out[base + d1] = (v1 - mu) * r * g[d1] + b[d1];
}

// ---------------------------------------------------------------- launch
extern "C" void kernel_launch(void* const* d_in, const int* in_sizes, int n_in,
                              void* d_out, int out_size, void* d_ws, size_t ws_size,
                              hipStream_t stream) {
    const float* x      = (const float*)d_in[0];
    const int*   ei     = (const int*)d_in[1];
    const float* ew     = (const float*)d_in[2];
    const int*   smask  = (const int*)d_in[3];
    const float* inW    = (const float*)d_in[4];
    const float* inb    = (const float*)d_in[5];
    const float* ing    = (const float*)d_in[6];
    const float* inbeta = (const float*)d_in[7];
    const float* gWl    = (const float*)d_in[8];
    const float* gbl    = (const float*)d_in[9];
    const float* gWr    = (const float*)d_in[10];
    const float* gbr    = (const float*)d_in[11];
    const float* gWe    = (const float*)d_in[12];
    const float* gatt   = (const float*)d_in[13];
    const float* gbias  = (const float*)d_in[14];
    const float* blkg   = (const float*)d_in[15];
    const float* blkb   = (const float*)d_in[16];
    const float* ctxW   = (const float*)d_in[17];
    const float* ctxb   = (const float*)d_in[18];
    const float* fing   = (const float*)d_in[19];
    const float* finb   = (const float*)d_in[20];
    float* out = (float*)d_out;

    float* ws = (float*)d_ws;
    size_t o = 0;
    float*    h      = ws + o;              o += (size_t)NN * HID;
    int2*     csr    = (int2*)(ws + o);     o += (size_t)ET * 2;
    float*    gm     = ws + o;              o += NSTORE * HID;
    int*      offs   = (int*)(ws + o);      o += 50004;
    int*      rank   = (int*)(ws + o);      o += EE;
    ushort_t* hb     = (ushort_t*)(ws + o); o += (size_t)NN * HID / 2;
    ushort_t* xlb    = (ushort_t*)(ws + o); o += (size_t)NN * HID / 2;
    ushort_t* xrb    = (ushort_t*)(ws + o); o += (size_t)NN * HID / 2;
    ushort_t* Wlt    = (ushort_t*)(ws + o); o += 3 * 128 * 128 / 2;
    ushort_t* Wrt    = (ushort_t*)(ws + o); o += 3 * 128 * 128 / 2;
    int*      bsum   = (int*)(ws + o);      o += 256;
    int*      bbase  = (int*)(ws + o);      o += 256;
    float*    psums  = ws + o;              o += (size_t)SSB * NSTORE * HID;
    int*      pcnts  = (int*)(ws + o);      o += SSB * NSTORE;
    if (o & 1) ++o;
    float*    zbase  = ws + o;
    u64*      packed = (u64*)(ws + o);      o += (size_t)NN * 2;
    size_t zbytes = (size_t)(NN * 2) * 4;

    hipMemsetAsync((void*)zbase, 0, zbytes, stream);

    const int WB = NN / 4;                    // wave-per-node kernels

    k_count<<<CNT_B, 256, 0, stream>>>(ei, ew, packed, rank);
    k_prep<<<WCV_B + GEMB, 256, 0, stream>>>(x, inW, gWl, gWr, inb, ing, inbeta,
                                             Wlt, Wrt, h, hb);
    k_psum<<<NBL, 256, 0, stream>>>(packed, bsum);
    k_scanb<<<1, 256, 0, stream>>>(bsum, bbase, offs);
    k_offs<<<NBL, 256, 0, stream>>>(packed, bbase, offs);

    for (int l = 0; l < 3; ++l) {
        int nb = 2 * GEMB + (l == 0 ? SCT_B : 0);   // layer 0 carries the CSR scatter blocks
        k_gemm2<<<nb, 256, 0, stream>>>(hb, Wlt + (size_t)l * HID * HID, Wrt + (size_t)l * HID * HID,
                                        gbl + l * HID, gbr + l * HID, xlb, xrb, NN,
                                        ei, ew, offs, packed, rank, csr);
        k_attn<<<WB, 256, 0, stream>>>(xlb, xrb, h, hb, offs, csr,
                                       gWe + l * HID, gatt + l * HID, gbias + l * HID,
                                       blkg + l * HID, blkb + l * HID);
    }

    k_store_sum<<<SSB, 256, 0, stream>>>(h, smask, psums, pcnts);
    k_gate<<<NSTORE, 256, 0, stream>>>(psums, pcnts, ctxW, ctxb, gm);
    k_final<<<WB, 256, 0, stream>>>(h, smask, gm, fing, finb, out);
}

// Round 11
// 517.043 us; speedup vs baseline: 1.1907x; 1.0022x over previous
//
#include <hip/hip_runtime.h>
#include <math.h>

#define NN 50000
#define EE 800000
#define ET (EE + NN)
#define HID 128
#define NSTORE 50
#define NBL 196                      // ceil(NN/256)
#define CNT_B 3125                   // EE/256
#define WCV_B 192                    // 3*128*128/256 weight cvt blocks
#define SCT_B 3321                   // ceil(ET/256)
#define GEMB 391                     // ceil(NN/128) gemm tiles
#define SSB 512                      // store-sum partial blocks (2 blocks/CU)

typedef unsigned short ushort_t;
typedef unsigned long long u64;
typedef __attribute__((ext_vector_type(8))) short bf8;
typedef __attribute__((ext_vector_type(4))) float f4;
typedef __attribute__((ext_vector_type(2))) float f2;
typedef __attribute__((ext_vector_type(4))) unsigned int u4;

__device__ __forceinline__ ushort_t f2b(float f) {
    union { float f; unsigned int i; } v; v.f = f;
    unsigned int r = (v.i + 0x7fffu + ((v.i >> 16) & 1u)) >> 16;
    return (ushort_t)r;
}
__device__ __forceinline__ f2 b2f2v(unsigned int u) {
    union { unsigned int i; float f; } lo, hi;
    lo.i = u << 16; hi.i = u & 0xffff0000u;
    f2 r; r.x = lo.f; r.y = hi.f; return r;
}
__device__ __forceinline__ unsigned int pk2(float lo, float hi) {
    return (unsigned int)f2b(lo) | ((unsigned int)f2b(hi) << 16);
}
__device__ __forceinline__ f2 max2(f2 a, f2 b) {
#if __has_builtin(__builtin_elementwise_max)
    return __builtin_elementwise_max(a, b);
#else
    f2 r; r.x = fmaxf(a.x, b.x); r.y = fmaxf(a.y, b.y); return r;
#endif
}

// ---------------------------------------------------------------- edge count (standalone, low VGPR, high occupancy)
// packed[dst]: bits 44+: degree; bits 0..43: sum(ew) in 2^24 fixed point.
__global__ __launch_bounds__(256) void k_count(const int* __restrict__ ei, const float* __restrict__ ew,
                                               u64* __restrict__ packed, int* __restrict__ rank) {
    int i = blockIdx.x * 256 + threadIdx.x;     // grid = CNT_B covers EE exactly
    int dst = ei[EE + i];
    unsigned int wfix = __float2uint_rn(ew[i] * 16777216.0f);
    u64 old = atomicAdd(&packed[dst], (1ULL << 44) | (u64)wfix);
    rank[i] = (int)(old >> 44);
}

// ---------------------------------------------------------------- prep: weight cvt + input projection (MFMA)
// blocks [0,WCV_B): Wlt[l][n*128+k] = W[l][k*128+n] ; blocks [WCV_B,..): inproj GELU+LN -> hb (bf16 only).
__global__ __launch_bounds__(256) void k_prep(const float* __restrict__ x, const float* __restrict__ inW,
                                              const float* __restrict__ gWl, const float* __restrict__ gWr,
                                              const float* __restrict__ inb, const float* __restrict__ ing,
                                              const float* __restrict__ inbeta,
                                              ushort_t* __restrict__ Wlt, ushort_t* __restrict__ Wrt,
                                              ushort_t* __restrict__ hb) {
    int b = blockIdx.x, t = threadIdx.x;
    if (b < WCV_B) {                  // ---- weight transpose+cvt
        int i = b * 256 + t;
        int l = i >> 14, r = i & 16383, nn2 = r >> 7, k = r & 127;
        Wlt[i] = f2b(gWl[(size_t)l * 16384 + k * 128 + nn2]);
        Wrt[i] = f2b(gWr[(size_t)l * 16384 + k * 128 + nn2]);
        return;
    }
    // ---- input projection: GELU(x@inW + b) then LN, K=64, inline f32->bf16 cvt
    __shared__ float s1[2][128], s2[2][128];
    int bidx = b - WCV_B;
    int lane = t & 63, w = t >> 6;
    int rw = w >> 1, cw = w & 1;
    int q = lane >> 4, l16 = lane & 15;
    int row0 = bidx * 128 + rw * 64;
    int col0 = cw * 64;

    bf8 bfr[2][4];
#pragma unroll
    for (int kk = 0; kk < 2; ++kk)
#pragma unroll
        for (int j = 0; j < 4; ++j) {
            int col = col0 + j * 16 + l16;
            int k0 = kk * 32 + q * 8;
            bf8 f;
#pragma unroll
            for (int e = 0; e < 8; ++e) f[e] = (short)f2b(inW[(size_t)(k0 + e) * HID + col]);
            bfr[kk][j] = f;
        }

    f4 acc[4][4];
#pragma unroll
    for (int i = 0; i < 4; ++i)
#pragma unroll
        for (int j = 0; j < 4; ++j) acc[i][j] = (f4)(0.f);

#pragma unroll
    for (int kk = 0; kk < 2; ++kk) {
        bf8 af[4];
#pragma unroll
        for (int i = 0; i < 4; ++i) {
            int r = row0 + i * 16 + l16;
            bf8 f;
            if (r < NN) {
                const float* xp = x + (size_t)r * 64 + kk * 32 + q * 8;
                f4 lo = *(const f4*)xp, hi = *(const f4*)(xp + 4);
                f[0] = (short)f2b(lo.x); f[1] = (short)f2b(lo.y);
                f[2] = (short)f2b(lo.z); f[3] = (short)f2b(lo.w);
                f[4] = (short)f2b(hi.x); f[5] = (short)f2b(hi.y);
                f[6] = (short)f2b(hi.z); f[7] = (short)f2b(hi.w);
            } else {
                for (int e = 0; e < 8; ++e) f[e] = 0;
            }
            af[i] = f;
        }
#pragma unroll
        for (int i = 0; i < 4; ++i)
#pragma unroll
            for (int j = 0; j < 4; ++j)
                acc[i][j] = __builtin_amdgcn_mfma_f32_16x16x32_bf16(af[i], bfr[kk][j], acc[i][j], 0, 0, 0);
    }
#pragma unroll
    for (int i = 0; i < 4; ++i) {
#pragma unroll
        for (int j = 0; j < 4; ++j) {
            float bv = inb[col0 + j * 16 + l16];
#pragma unroll
            for (int r = 0; r < 4; ++r) {
                float v = acc[i][j][r] + bv;
                v = 0.5f * v * (1.f + erff(v * 0.70710678118654752f));
                acc[i][j][r] = v;
            }
        }
    }
#pragma unroll
    for (int i = 0; i < 4; ++i) {
#pragma unroll
        for (int r = 0; r < 4; ++r) {
            float sm = acc[i][0][r] + acc[i][1][r] + acc[i][2][r] + acc[i][3][r];
            float sq = acc[i][0][r] * acc[i][0][r] + acc[i][1][r] * acc[i][1][r]
                     + acc[i][2][r] * acc[i][2][r] + acc[i][3][r] * acc[i][3][r];
#pragma unroll
            for (int k = 1; k < 16; k <<= 1) { sm += __shfl_xor(sm, k); sq += __shfl_xor(sq, k); }
            if (l16 == 0) {
                int rl = rw * 64 + i * 16 + q * 4 + r;
                s1[cw][rl] = sm; s2[cw][rl] = sq;
            }
        }
    }
    __syncthreads();
#pragma unroll
    for (int i = 0; i < 4; ++i) {
#pragma unroll
        for (int r = 0; r < 4; ++r) {
            int rl = rw * 64 + i * 16 + q * 4 + r;
            int gr = bidx * 128 + rl;
            if (gr >= NN) continue;
            float sm = s1[0][rl] + s1[1][rl];
            float sq = s2[0][rl] + s2[1][rl];
            float mu = sm * (1.f / 128.f);
            float var = sq * (1.f / 128.f) - mu * mu;
            float rinv = rsqrtf(var + 1e-5f);
#pragma unroll
            for (int j = 0; j < 4; ++j) {
                int gc = col0 + j * 16 + l16;
                float v = (acc[i][j][r] - mu) * rinv * ing[gc] + inbeta[gc];
                hb[(size_t)gr * HID + gc] = f2b(v);
            }
        }
    }
}

// per-256-chunk sums of (deg+1)
__global__ __launch_bounds__(256) void k_psum(const u64* __restrict__ packed, int* __restrict__ bsum) {
    int t = threadIdx.x, bidx = blockIdx.x;
    int i = bidx * 256 + t;
    int v = (i < NN) ? (int)(packed[i] >> 44) + 1 : 0;
#pragma unroll
    for (int d = 1; d < 64; d <<= 1) v += __shfl_xor(v, d);
    __shared__ int ws4[4];
    if ((t & 63) == 0) ws4[t >> 6] = v;
    __syncthreads();
    if (t == 0) bsum[bidx] = ws4[0] + ws4[1] + ws4[2] + ws4[3];
}

__global__ __launch_bounds__(256) void k_scanb(const int* __restrict__ bsum,
                                               int* __restrict__ bbase, int* __restrict__ offs) {
    __shared__ int s[256];
    int t = threadIdx.x;
    int v = (t < NBL) ? bsum[t] : 0;
    s[t] = v;
    __syncthreads();
    for (int d = 1; d < 256; d <<= 1) {
        int u = (t >= d) ? s[t - d] : 0;
        __syncthreads();
        s[t] += u;
        __syncthreads();
    }
    if (t < NBL) bbase[t] = s[t] - v;    // exclusive base
    if (t == 0) offs[NN] = ET;
}

__global__ __launch_bounds__(256) void k_offs(const u64* __restrict__ packed,
                                              const int* __restrict__ bbase, int* __restrict__ offs) {
    __shared__ int wsum4[4];
    int t = threadIdx.x, bidx = blockIdx.x;
    int i = bidx * 256 + t;
    int v = (i < NN) ? (int)(packed[i] >> 44) + 1 : 0;
    int lane = t & 63, w = t >> 6;
    int sc = v;
#pragma unroll
    for (int d = 1; d < 64; d <<= 1) {
        int u = __shfl_up(sc, d);
        if (lane >= d) sc += u;
    }
    if (lane == 63) wsum4[w] = sc;
    __syncthreads();
    int wo = 0;
    for (int k = 0; k < w; ++k) wo += wsum4[k];
    if (i < NN) offs[i] = bbase[bidx] + wo + sc - v;
}

// ---------------------------------------------------------------- bf16 MFMA dual GEMM (K=128) + optional fused scatter
// blocks [0,GEMB): xlb ; [GEMB,2*GEMB): xrb ; >= 2*GEMB: CSR scatter (layer 0).
__global__ __launch_bounds__(256) void k_gemm2(const ushort_t* __restrict__ A,
                                               const ushort_t* __restrict__ Wt0,
                                               const ushort_t* __restrict__ Wt1,
                                               const float* __restrict__ b0,
                                               const float* __restrict__ b1,
                                               ushort_t* __restrict__ o0,
                                               ushort_t* __restrict__ o1, int n,
                                               const int* __restrict__ ei,
                                               const float* __restrict__ ew,
                                               const int* __restrict__ offs,
                                               const u64* __restrict__ packed,
                                               const int* __restrict__ rank,
                                               int2* __restrict__ csr) {
    int bid = blockIdx.x;
    if (bid >= 2 * GEMB) {
        int i = (bid - 2 * GEMB) * 256 + threadIdx.x;
        if (i < EE) {
            int src = ei[i], dst = ei[EE + i];
            int pos = offs[dst] + rank[i];
            int2 v; v.x = src; v.y = __float_as_int(ew[i]);
            csr[pos] = v;
        } else if (i < ET) {
            int nd = i - EE;
            u64 p = packed[nd];
            int deg = (int)(p >> 44);
            float wsf = (float)(p & ((1ULL << 44) - 1)) * (1.0f / 16777216.0f);
            float la = wsf / fmaxf((float)deg, 1.0f);
            int pos = offs[nd + 1] - 1;
            int2 v; v.x = nd; v.y = __float_as_int(la);
            csr[pos] = v;
        }
        return;
    }
    const int K = 128;
    int by = (bid >= GEMB) ? 1 : 0;
    int bx = by ? bid - GEMB : bid;
    const ushort_t* Wt = by ? Wt1 : Wt0;
    const float* bias = by ? b1 : b0;
    ushort_t* outb = by ? o1 : o0;
    int lane = threadIdx.x & 63, w = threadIdx.x >> 6;
    int rw = w >> 1, cw = w & 1;
    int q = lane >> 4, l16 = lane & 15;
    int row0 = bx * 128 + rw * 64;
    int col0 = cw * 64;
    bf8 z; for (int t = 0; t < 8; ++t) z[t] = 0;

    bf8 bfr[4][4];
#pragma unroll
    for (int kk = 0; kk < 4; ++kk)
#pragma unroll
        for (int j = 0; j < 4; ++j)
            bfr[kk][j] = *(const bf8*)(Wt + (size_t)(col0 + j * 16 + l16) * K + kk * 32 + q * 8);

    f4 acc[4][4];
#pragma unroll
    for (int i = 0; i < 4; ++i)
#pragma unroll
        for (int j = 0; j < 4; ++j) acc[i][j] = (f4)(0.f);

#pragma unroll
    for (int kk = 0; kk < 4; ++kk) {
        bf8 af[4];
#pragma unroll
        for (int i = 0; i < 4; ++i) {
            int r = row0 + i * 16 + l16;
            af[i] = (r < n) ? *(const bf8*)(A + (size_t)r * K + kk * 32 + q * 8) : z;
        }
#pragma unroll
        for (int i = 0; i < 4; ++i)
#pragma unroll
            for (int j = 0; j < 4; ++j)
                acc[i][j] = __builtin_amdgcn_mfma_f32_16x16x32_bf16(af[i], bfr[kk][j], acc[i][j], 0, 0, 0);
    }
#pragma unroll
    for (int i = 0; i < 4; ++i) {
        int gr0 = row0 + i * 16 + q * 4;
#pragma unroll
        for (int j = 0; j < 4; ++j) {
            int gc = col0 + j * 16 + l16;
            float bv = bias[gc];
#pragma unroll
            for (int r = 0; r < 4; ++r) {
                int gr = gr0 + r;
                if (gr < n) outb[(size_t)gr * HID + gc] = f2b(acc[i][j][r] + bv);
            }
        }
    }
}

// ---------------------------------------------------------------- GATv2 attention (packed-f32 VALU, bf16 residual)
__global__ __launch_bounds__(256) void k_attn(const ushort_t* __restrict__ xl,
                                              const ushort_t* __restrict__ xr,
                                              ushort_t* __restrict__ hb,
                                              const int* __restrict__ offs,
                                              const int2* __restrict__ csr,
                                              const float* __restrict__ We,
                                              const float* __restrict__ att,
                                              const float* __restrict__ gbias,
                                              const float* __restrict__ g,
                                              const float* __restrict__ b) {
    int wid = (blockIdx.x * 256 + threadIdx.x) >> 6;
    int lane = threadIdx.x & 63;
    if (wid >= NN) return;
    int hd = lane & 15;          // head index (16 heads; DH=8 in-lane)
    int grp = lane >> 4;         // edge subgroup 0..3
    int dbase = hd * 8;
    size_t base = (size_t)wid * HID;

    f2 xr2[4], at2[4], we2[4];
    {
        u4 uxr = *(const u4*)(xr + base + dbase);
        xr2[0] = b2f2v(uxr.x); xr2[1] = b2f2v(uxr.y);
        xr2[2] = b2f2v(uxr.z); xr2[3] = b2f2v(uxr.w);
        f4 a0 = *(const f4*)(att + dbase), a1 = *(const f4*)(att + dbase + 4);
        at2[0].x = a0.x; at2[0].y = a0.y; at2[1].x = a0.z; at2[1].y = a0.w;
        at2[2].x = a1.x; at2[2].y = a1.y; at2[3].x = a1.z; at2[3].y = a1.w;
        f4 w0 = *(const f4*)(We + dbase), w1 = *(const f4*)(We + dbase + 4);
        we2[0].x = w0.x; we2[0].y = w0.y; we2[1].x = w0.z; we2[1].y = w0.w;
        we2[2].x = w1.x; we2[2].y = w1.y; we2[3].x = w1.z; we2[3].y = w1.w;
    }
    int p0 = offs[wid], p1 = offs[wid + 1];
    float Z = 0.f;
    f2 acc2[4];
#pragma unroll
    for (int q = 0; q < 4; ++q) { acc2[q].x = 0.f; acc2[q].y = 0.f; }

#define QUAD(EJ, MASKED)                                                        \
    {                                                                           \
        int ei_ = (EJ) + grp;                                                   \
        int s_ = __shfl(sv, ei_);                                               \
        float ea_ = __shfl(evl, ei_);                                           \
        bool val_ = MASKED ? (ei_ < mm) : true;                                 \
        u4 ux_ = *(const u4*)(xl + (size_t)s_ * HID + dbase);                   \
        f2 x2_[4];                                                              \
        x2_[0] = b2f2v(ux_.x); x2_[1] = b2f2v(ux_.y);                           \
        x2_[2] = b2f2v(ux_.z); x2_[3] = b2f2v(ux_.w);                           \
        f2 lg2_; lg2_.x = 0.f; lg2_.y = 0.f;                                    \
        _Pragma("unroll")                                                       \
        for (int q_ = 0; q_ < 4; ++q_) {                                        \
            f2 t_ = (x2_[q_] + xr2[q_]) + ea_ * we2[q_];                        \
            t_ = max2(t_, t_ * 0.2f);                                           \
            lg2_ += at2[q_] * t_;                                               \
        }                                                                       \
        float w_ = val_ ? __expf(lg2_.x + lg2_.y) : 0.f;                        \
        Z += w_;                                                                \
        _Pragma("unroll")                                                       \
        for (int q_ = 0; q_ < 4; ++q_) acc2[q_] += w_ * x2_[q_];                \
    }

    for (int cb = p0; cb < p1; cb += 64) {
        int mm = min(64, p1 - cb);
        int2 m2 = (lane < mm) ? csr[cb + lane] : make_int2(0, 0);
        int sv = m2.x;
        float evl = __int_as_float(m2.y);
        int j = 0;
        for (; j + 8 <= mm; j += 8) { QUAD(j, false) QUAD(j + 4, false) }
        for (; j < mm; j += 4) QUAD(j, true)
    }
#undef QUAD

    Z += __shfl_xor(Z, 16); Z += __shfl_xor(Z, 32);
#pragma unroll
    for (int q = 0; q < 4; ++q) {
        acc2[q].x += __shfl_xor(acc2[q].x, 16);
        acc2[q].x += __shfl_xor(acc2[q].x, 32);
        acc2[q].y += __shfl_xor(acc2[q].y, 16);
        acc2[q].y += __shfl_xor(acc2[q].y, 32);
    }
    float inv = 1.f / (Z + 1e-16f);
    float acc[8] = {acc2[0].x, acc2[0].y, acc2[1].x, acc2[1].y,
                    acc2[2].x, acc2[2].y, acc2[3].x, acc2[3].y};

    // residual (bf16 h) + LN over the 128 dims held by the 16 head-lanes
    u4 uh = *(const u4*)(hb + base + dbase);
    f2 hr0 = b2f2v(uh.x), hr1 = b2f2v(uh.y), hr2 = b2f2v(uh.z), hr3 = b2f2v(uh.w);
    float hres[8] = {hr0.x, hr0.y, hr1.x, hr1.y, hr2.x, hr2.y, hr3.x, hr3.y};
    f4 gb0 = *(const f4*)(gbias + dbase), gb1 = *(const f4*)(gbias + dbase + 4);
    float gb8[8] = {gb0.x, gb0.y, gb0.z, gb0.w, gb1.x, gb1.y, gb1.z, gb1.w};
    float o[8], sm = 0.f, sq = 0.f;
#pragma unroll
    for (int q = 0; q < 8; ++q) {
        o[q] = acc[q] * inv + gb8[q] + hres[q];
        sm += o[q]; sq += o[q] * o[q];
    }
#pragma unroll
    for (int k = 1; k < 16; k <<= 1) { sm += __shfl_xor(sm, k); sq += __shfl_xor(sq, k); }
    float mu = sm * (1.f / 128.f);
    float var = sq * (1.f / 128.f) - mu * mu;
    float rinv = rsqrtf(var + 1e-5f);
    f4 g0 = *(const f4*)(g + dbase), g1 = *(const f4*)(g + dbase + 4);
    float g8[8] = {g0.x, g0.y, g0.z, g0.w, g1.x, g1.y, g1.z, g1.w};
    f4 b0 = *(const f4*)(b + dbase), b1 = *(const f4*)(b + dbase + 4);
    float b8[8] = {b0.x, b0.y, b0.z, b0.w, b1.x, b1.y, b1.z, b1.w};
    float v8[8];
#pragma unroll
    for (int q = 0; q < 8; ++q) v8[q] = (o[q] - mu) * rinv * g8[q] + b8[q];
    if (grp == 0) {
        u4 hu;
        hu.x = pk2(v8[0], v8[1]); hu.y = pk2(v8[2], v8[3]);
        hu.z = pk2(v8[4], v8[5]); hu.w = pk2(v8[6], v8[7]);
        *(u4*)(hb + base + dbase) = hu;
    }
}

// ---------------------------------------------------------------- per-store partial sums (bf16 h, no global atomics)
__global__ __launch_bounds__(256) void k_store_sum(const ushort_t* __restrict__ hb,
                                                   const int* __restrict__ mask,
                                                   float* __restrict__ psums,   // [SSB][NSTORE*HID]
                                                   int* __restrict__ pcnts) {   // [SSB][NSTORE]
    __shared__ float ls[NSTORE * HID];
    __shared__ int lc[NSTORE];
    int t = threadIdx.x, bidx = blockIdx.x;
    for (int i = t; i < NSTORE * HID; i += 256) ls[i] = 0.f;
    if (t < NSTORE) lc[t] = 0;
    __syncthreads();
    int wid = bidx * 4 + (t >> 6);
    int lane = t & 63;
    int nw = SSB * 4;
    int d0 = lane * 2;
    for (int node = wid; node < NN; node += nw) {
        int s = mask[node];
        unsigned int hv = ((const unsigned int*)(hb + (size_t)node * HID))[lane];
        f2 v = b2f2v(hv);
        atomicAdd(&ls[s * HID + d0], v.x);
        atomicAdd(&ls[s * HID + d0 + 1], v.y);
        if (lane == 0) atomicAdd(&lc[s], 1);
    }
    __syncthreads();
    for (int i = t; i < NSTORE * HID; i += 256) psums[(size_t)bidx * (NSTORE * HID) + i] = ls[i];
    if (t < NSTORE) pcnts[bidx * NSTORE + t] = lc[t];
}

// ---------------------------------------------------------------- gate (parallel reduction of partials)
__global__ __launch_bounds__(256) void k_gate(const float* __restrict__ psums,
                                              const int* __restrict__ pcnts,
                                              const float* __restrict__ ctxW,
                                              const float* __restrict__ ctxb,
                                              float* __restrict__ gm) {
    __shared__ float h1[HID];
    __shared__ float mloc[HID];
    __shared__ int cw4[4];
    int s = blockIdx.x, t = threadIdx.x;
    int d = t & 127, half = t >> 7;
    float s0 = 0.f, s1 = 0.f, s2 = 0.f, s3 = 0.f;
    for (int b = half * 4; b < SSB; b += 8) {
        s0 += psums[(size_t)(b + 0) * (NSTORE * HID) + s * HID + d];
        s1 += psums[(size_t)(b + 1) * (NSTORE * HID) + s * HID + d];
        s2 += psums[(size_t)(b + 2) * (NSTORE * HID) + s * HID + d];
        s3 += psums[(size_t)(b + 3) * (NSTORE * HID) + s * HID + d];
    }
    float sum = (s0 + s1) + (s2 + s3);
    int c = pcnts[t * NSTORE + s] + pcnts[(t + 256) * NSTORE + s];
#pragma unroll
    for (int k = 1; k < 64; k <<= 1) c += __shfl_xor(c, k);
    if ((t & 63) == 0) cw4[t >> 6] = c;
    if (half) h1[d] = sum;
    __syncthreads();
    if (half == 0) {
        float tot = sum + h1[d];
        float cnt = fmaxf((float)(cw4[0] + cw4[1] + cw4[2] + cw4[3]), 1.f);
        mloc[d] = tot / cnt;
    }
    __syncthreads();
    if (half == 0) {
        float acc = ctxb[d];
        for (int j = 0; j < HID; ++j) acc += mloc[j] * ctxW[j * HID + d];
        float gate = 1.f / (1.f + __expf(-acc));
        gm[s * HID + d] = gate * mloc[d];
    }
}

// ---------------------------------------------------------------- final: out = LN(hb + gm[store])
__global__ __launch_bounds__(256) void k_final(const ushort_t* __restrict__ hb,
                                               const int* __restrict__ mask,
                                               const float* __restrict__ gm,
                                               const float* __restrict__ g,
                                               const float* __restrict__ b,
                                               float* __restrict__ out) {
    int wid = (blockIdx.x * 256 + threadIdx.x) >> 6;
    int lane = threadIdx.x & 63;
    if (wid >= NN) return;
    size_t base = (size_t)wid * HID;
    int s = mask[wid];
    int d0 = lane * 2, d1 = d0 + 1;
    unsigned int hv = ((const unsigned int*)(hb + base))[lane];
    f2 hvv = b2f2v(hv);
    float v0 = hvv.x + gm[s * HID + d0];
    float v1 = hvv.y + gm[s * HID + d1];
    float sm = v0 + v1, sq = v0 * v0 + v1 * v1;
#pragma unroll
    for (int k = 1; k < 64; k <<= 1) { sm += __shfl_xor(sm, k); sq += __shfl_xor(sq, k); }
    float mu = sm * (1.f / 128.f);
    float var = sq * (1.f / 128.f) - mu * mu;
    float r = rsqrtf(var + 1e-5f);
    out[base + d0] = (v0 - mu) * r * g[d0] + b[d0];
    out[base + d1] = (v1 - mu) * r * g[d1] + b[d1];
}

// ---------------------------------------------------------------- launch
extern "C" void kernel_launch(void* const* d_in, const int* in_sizes, int n_in,
                              void* d_out, int out_size, void* d_ws, size_t ws_size,
                              hipStream_t stream) {
    const float* x      = (const float*)d_in[0];
    const int*   ei     = (const int*)d_in[1];
    const float* ew     = (const float*)d_in[2];
    const int*   smask  = (const int*)d_in[3];
    const float* inW    = (const float*)d_in[4];
    const float* inb    = (const float*)d_in[5];
    const float* ing    = (const float*)d_in[6];
    const float* inbeta = (const float*)d_in[7];
    const float* gWl    = (const float*)d_in[8];
    const float* gbl    = (const float*)d_in[9];
    const float* gWr    = (const float*)d_in[10];
    const float* gbr    = (const float*)d_in[11];
    const float* gWe    = (const float*)d_in[12];
    const float* gatt   = (const float*)d_in[13];
    const float* gbias  = (const float*)d_in[14];
    const float* blkg   = (const float*)d_in[15];
    const float* blkb   = (const float*)d_in[16];
    const float* ctxW   = (const float*)d_in[17];
    const float* ctxb   = (const float*)d_in[18];
    const float* fing   = (const float*)d_in[19];
    const float* finb   = (const float*)d_in[20];
    float* out = (float*)d_out;

    float* ws = (float*)d_ws;
    size_t o = 0;
    int2*     csr    = (int2*)(ws + o);     o += (size_t)ET * 2;
    float*    gm     = ws + o;              o += NSTORE * HID;
    int*      offs   = (int*)(ws + o);      o += 50004;
    int*      rank   = (int*)(ws + o);      o += EE;
    ushort_t* hb     = (ushort_t*)(ws + o); o += (size_t)NN * HID / 2;
    ushort_t* xlb    = (ushort_t*)(ws + o); o += (size_t)NN * HID / 2;
    ushort_t* xrb    = (ushort_t*)(ws + o); o += (size_t)NN * HID / 2;
    ushort_t* Wlt    = (ushort_t*)(ws + o); o += 3 * 128 * 128 / 2;
    ushort_t* Wrt    = (ushort_t*)(ws + o); o += 3 * 128 * 128 / 2;
    int*      bsum   = (int*)(ws + o);      o += 256;
    int*      bbase  = (int*)(ws + o);      o += 256;
    float*    psums  = ws + o;              o += (size_t)SSB * NSTORE * HID;
    int*      pcnts  = (int*)(ws + o);      o += SSB * NSTORE;
    if (o & 1) ++o;
    float*    zbase  = ws + o;
    u64*      packed = (u64*)(ws + o);      o += (size_t)NN * 2;
    size_t zbytes = (size_t)(NN * 2) * 4;

    hipMemsetAsync((void*)zbase, 0, zbytes, stream);

    const int WB = NN / 4;                    // wave-per-node kernels

    k_count<<<CNT_B, 256, 0, stream>>>(ei, ew, packed, rank);
    k_prep<<<WCV_B + GEMB, 256, 0, stream>>>(x, inW, gWl, gWr, inb, ing, inbeta,
                                             Wlt, Wrt, hb);
    k_psum<<<NBL, 256, 0, stream>>>(packed, bsum);
    k_scanb<<<1, 256, 0, stream>>>(bsum, bbase, offs);
    k_offs<<<NBL, 256, 0, stream>>>(packed, bbase, offs);

    for (int l = 0; l < 3; ++l) {
        int nb = 2 * GEMB + (l == 0 ? SCT_B : 0);   // layer 0 carries the CSR scatter blocks
        k_gemm2<<<nb, 256, 0, stream>>>(hb, Wlt + (size_t)l * HID * HID, Wrt + (size_t)l * HID * HID,
                                        gbl + l * HID, gbr + l * HID, xlb, xrb, NN,
                                        ei, ew, offs, packed, rank, csr);
        k_attn<<<WB, 256, 0, stream>>>(xlb, xrb, hb, offs, csr,
                                       gWe + l * HID, gatt + l * HID, gbias + l * HID,
                                       blkg + l * HID, blkb + l * HID);
    }

    k_store_sum<<<SSB, 256, 0, stream>>>(hb, smask, psums, pcnts);
    k_gate<<<NSTORE, 256, 0, stream>>>(psums, pcnts, ctxW, ctxb, gm);
    k_final<<<WB, 256, 0, stream>>>(hb, smask, gm, fing, finb, out);
}

// Round 12
// 506.488 us; speedup vs baseline: 1.2155x; 1.0208x over previous
//
#include <hip/hip_runtime.h>
#include <math.h>

#define NN 50000
#define EE 800000
#define ET (EE + NN)
#define HID 128
#define NSTORE 50
#define NBL 196                      // ceil(NN/256)
#define CNT_B 3125                   // EE/256 edge-count blocks
#define XCV_B 3125                   // NN*64/(256*4) x->bf16 cvt blocks
#define WCV_B 192                    // 3*128*128/256 weight cvt blocks
#define IWC_B 32                     // 128*64/256 inW cvt blocks
#define SCT_B 3321                   // ceil(ET/256)
#define GEMB 391                     // ceil(NN/128) gemm tiles
#define SSB 512                      // store-sum partial blocks (2 blocks/CU)

typedef unsigned short ushort_t;
typedef unsigned long long u64;
typedef __attribute__((ext_vector_type(8))) short bf8;
typedef __attribute__((ext_vector_type(4))) float f4;
typedef __attribute__((ext_vector_type(2))) float f2;
typedef __attribute__((ext_vector_type(4))) unsigned int u4;

__device__ __forceinline__ ushort_t f2b(float f) {
    union { float f; unsigned int i; } v; v.f = f;
    unsigned int r = (v.i + 0x7fffu + ((v.i >> 16) & 1u)) >> 16;
    return (ushort_t)r;
}
__device__ __forceinline__ f2 b2f2v(unsigned int u) {
    union { unsigned int i; float f; } lo, hi;
    lo.i = u << 16; hi.i = u & 0xffff0000u;
    f2 r; r.x = lo.f; r.y = hi.f; return r;
}
__device__ __forceinline__ unsigned int pk2(float lo, float hi) {
    return (unsigned int)f2b(lo) | ((unsigned int)f2b(hi) << 16);
}
__device__ __forceinline__ f2 max2(f2 a, f2 b) {
#if __has_builtin(__builtin_elementwise_max)
    return __builtin_elementwise_max(a, b);
#else
    f2 r; r.x = fmaxf(a.x, b.x); r.y = fmaxf(a.y, b.y); return r;
#endif
}

// ---------------------------------------------------------------- build: all low-VGPR streaming work in one launch.
// blocks [0,CNT_B): edge count (latency long-pole, FIRST);
// [CNT_B,+XCV_B): x -> bf16 xb (coalesced, 4 elems/thread);
// [+WCV_B): Wl/Wr transpose+cvt; [+IWC_B): inW transpose+cvt.
// packed[dst]: bits 44+: degree; bits 0..43: sum(ew) in 2^24 fixed point.
__global__ __launch_bounds__(256) void k_build(const int* __restrict__ ei, const float* __restrict__ ew,
                                               const float* __restrict__ x, const float* __restrict__ inW,
                                               const float* __restrict__ gWl, const float* __restrict__ gWr,
                                               ushort_t* __restrict__ xb, ushort_t* __restrict__ inWt,
                                               ushort_t* __restrict__ Wlt, ushort_t* __restrict__ Wrt,
                                               u64* __restrict__ packed, int* __restrict__ rank) {
    int b = blockIdx.x, t = threadIdx.x;
    if (b < CNT_B) {                               // ---- edge count
        int i = b * 256 + t;
        int dst = ei[EE + i];
        unsigned int wfix = __float2uint_rn(ew[i] * 16777216.0f);
        u64 old = atomicAdd(&packed[dst], (1ULL << 44) | (u64)wfix);
        rank[i] = (int)(old >> 44);
        return;
    }
    if (b < CNT_B + XCV_B) {                       // ---- x -> bf16 (float4 -> 2 packed u32)
        int i = ((b - CNT_B) * 256 + t) * 4;
        f4 v = *(const f4*)(x + i);
        uint2 p; p.x = pk2(v.x, v.y); p.y = pk2(v.z, v.w);
        *(uint2*)(xb + i) = p;
        return;
    }
    if (b < CNT_B + XCV_B + WCV_B) {               // ---- Wlt[l][n*128+k] = W[l][k*128+n]
        int i = (b - CNT_B - XCV_B) * 256 + t;
        int l = i >> 14, r = i & 16383, nn2 = r >> 7, k = r & 127;
        Wlt[i] = f2b(gWl[(size_t)l * 16384 + k * 128 + nn2]);
        Wrt[i] = f2b(gWr[(size_t)l * 16384 + k * 128 + nn2]);
        return;
    }
    {                                              // ---- inWt[c*64+k] = inW[k*128+c]
        int i = (b - CNT_B - XCV_B - WCV_B) * 256 + t;
        int c = i >> 6, k = i & 63;
        inWt[i] = f2b(inW[k * 128 + c]);
    }
}

// ---------------------------------------------------------------- input proj: GELU + LN fused, K=64, bf16 in, hb out
__global__ __launch_bounds__(256) void k_inproj(const ushort_t* __restrict__ A,
                                                const ushort_t* __restrict__ Wt,
                                                const float* __restrict__ bias,
                                                const float* __restrict__ g,
                                                const float* __restrict__ be,
                                                ushort_t* __restrict__ hb) {
    const int K = 64;
    __shared__ float s1[2][128], s2[2][128];
    int lane = threadIdx.x & 63, w = threadIdx.x >> 6;
    int rw = w >> 1, cw = w & 1;
    int q = lane >> 4, l16 = lane & 15;
    int row0 = blockIdx.x * 128 + rw * 64;
    int col0 = cw * 64;
    bf8 z; for (int t = 0; t < 8; ++t) z[t] = 0;

    bf8 bfr[2][4];
#pragma unroll
    for (int kk = 0; kk < 2; ++kk)
#pragma unroll
        for (int j = 0; j < 4; ++j)
            bfr[kk][j] = *(const bf8*)(Wt + (size_t)(col0 + j * 16 + l16) * K + kk * 32 + q * 8);

    f4 acc[4][4];
#pragma unroll
    for (int i = 0; i < 4; ++i)
#pragma unroll
        for (int j = 0; j < 4; ++j) acc[i][j] = (f4)(0.f);

#pragma unroll
    for (int kk = 0; kk < 2; ++kk) {
        bf8 af[4];
#pragma unroll
        for (int i = 0; i < 4; ++i) {
            int r = row0 + i * 16 + l16;
            af[i] = (r < NN) ? *(const bf8*)(A + (size_t)r * K + kk * 32 + q * 8) : z;
        }
#pragma unroll
        for (int i = 0; i < 4; ++i)
#pragma unroll
            for (int j = 0; j < 4; ++j)
                acc[i][j] = __builtin_amdgcn_mfma_f32_16x16x32_bf16(af[i], bfr[kk][j], acc[i][j], 0, 0, 0);
    }
#pragma unroll
    for (int i = 0; i < 4; ++i) {
#pragma unroll
        for (int j = 0; j < 4; ++j) {
            float bv = bias[col0 + j * 16 + l16];
#pragma unroll
            for (int r = 0; r < 4; ++r) {
                float v = acc[i][j][r] + bv;
                v = 0.5f * v * (1.f + erff(v * 0.70710678118654752f));
                acc[i][j][r] = v;
            }
        }
    }
#pragma unroll
    for (int i = 0; i < 4; ++i) {
#pragma unroll
        for (int r = 0; r < 4; ++r) {
            float sm = acc[i][0][r] + acc[i][1][r] + acc[i][2][r] + acc[i][3][r];
            float sq = acc[i][0][r] * acc[i][0][r] + acc[i][1][r] * acc[i][1][r]
                     + acc[i][2][r] * acc[i][2][r] + acc[i][3][r] * acc[i][3][r];
#pragma unroll
            for (int k = 1; k < 16; k <<= 1) { sm += __shfl_xor(sm, k); sq += __shfl_xor(sq, k); }
            if (l16 == 0) {
                int rl = rw * 64 + i * 16 + q * 4 + r;
                s1[cw][rl] = sm; s2[cw][rl] = sq;
            }
        }
    }
    __syncthreads();
#pragma unroll
    for (int i = 0; i < 4; ++i) {
#pragma unroll
        for (int r = 0; r < 4; ++r) {
            int rl = rw * 64 + i * 16 + q * 4 + r;
            int gr = blockIdx.x * 128 + rl;
            if (gr >= NN) continue;
            float sm = s1[0][rl] + s1[1][rl];
            float sq = s2[0][rl] + s2[1][rl];
            float mu = sm * (1.f / 128.f);
            float var = sq * (1.f / 128.f) - mu * mu;
            float rinv = rsqrtf(var + 1e-5f);
#pragma unroll
            for (int j = 0; j < 4; ++j) {
                int gc = col0 + j * 16 + l16;
                float v = (acc[i][j][r] - mu) * rinv * g[gc] + be[gc];
                hb[(size_t)gr * HID + gc] = f2b(v);
            }
        }
    }
}

// per-256-chunk sums of (deg+1)
__global__ __launch_bounds__(256) void k_psum(const u64* __restrict__ packed, int* __restrict__ bsum) {
    int t = threadIdx.x, bidx = blockIdx.x;
    int i = bidx * 256 + t;
    int v = (i < NN) ? (int)(packed[i] >> 44) + 1 : 0;
#pragma unroll
    for (int d = 1; d < 64; d <<= 1) v += __shfl_xor(v, d);
    __shared__ int ws4[4];
    if ((t & 63) == 0) ws4[t >> 6] = v;
    __syncthreads();
    if (t == 0) bsum[bidx] = ws4[0] + ws4[1] + ws4[2] + ws4[3];
}

__global__ __launch_bounds__(256) void k_scanb(const int* __restrict__ bsum,
                                               int* __restrict__ bbase, int* __restrict__ offs) {
    __shared__ int s[256];
    int t = threadIdx.x;
    int v = (t < NBL) ? bsum[t] : 0;
    s[t] = v;
    __syncthreads();
    for (int d = 1; d < 256; d <<= 1) {
        int u = (t >= d) ? s[t - d] : 0;
        __syncthreads();
        s[t] += u;
        __syncthreads();
    }
    if (t < NBL) bbase[t] = s[t] - v;    // exclusive base
    if (t == 0) offs[NN] = ET;
}

__global__ __launch_bounds__(256) void k_offs(const u64* __restrict__ packed,
                                              const int* __restrict__ bbase, int* __restrict__ offs) {
    __shared__ int wsum4[4];
    int t = threadIdx.x, bidx = blockIdx.x;
    int i = bidx * 256 + t;
    int v = (i < NN) ? (int)(packed[i] >> 44) + 1 : 0;
    int lane = t & 63, w = t >> 6;
    int sc = v;
#pragma unroll
    for (int d = 1; d < 64; d <<= 1) {
        int u = __shfl_up(sc, d);
        if (lane >= d) sc += u;
    }
    if (lane == 63) wsum4[w] = sc;
    __syncthreads();
    int wo = 0;
    for (int k = 0; k < w; ++k) wo += wsum4[k];
    if (i < NN) offs[i] = bbase[bidx] + wo + sc - v;
}

// ---------------------------------------------------------------- bf16 MFMA dual GEMM (K=128) + optional fused scatter
// blocks [0,GEMB): xlb ; [GEMB,2*GEMB): xrb ; >= 2*GEMB: CSR scatter (layer 0).
__global__ __launch_bounds__(256) void k_gemm2(const ushort_t* __restrict__ A,
                                               const ushort_t* __restrict__ Wt0,
                                               const ushort_t* __restrict__ Wt1,
                                               const float* __restrict__ b0,
                                               const float* __restrict__ b1,
                                               ushort_t* __restrict__ o0,
                                               ushort_t* __restrict__ o1, int n,
                                               const int* __restrict__ ei,
                                               const float* __restrict__ ew,
                                               const int* __restrict__ offs,
                                               const u64* __restrict__ packed,
                                               const int* __restrict__ rank,
                                               int2* __restrict__ csr) {
    int bid = blockIdx.x;
    if (bid >= 2 * GEMB) {
        int i = (bid - 2 * GEMB) * 256 + threadIdx.x;
        if (i < EE) {
            int src = ei[i], dst = ei[EE + i];
            int pos = offs[dst] + rank[i];
            int2 v; v.x = src; v.y = __float_as_int(ew[i]);
            csr[pos] = v;
        } else if (i < ET) {
            int nd = i - EE;
            u64 p = packed[nd];
            int deg = (int)(p >> 44);
            float wsf = (float)(p & ((1ULL << 44) - 1)) * (1.0f / 16777216.0f);
            float la = wsf / fmaxf((float)deg, 1.0f);
            int pos = offs[nd + 1] - 1;
            int2 v; v.x = nd; v.y = __float_as_int(la);
            csr[pos] = v;
        }
        return;
    }
    const int K = 128;
    int by = (bid >= GEMB) ? 1 : 0;
    int bx = by ? bid - GEMB : bid;
    const ushort_t* Wt = by ? Wt1 : Wt0;
    const float* bias = by ? b1 : b0;
    ushort_t* outb = by ? o1 : o0;
    int lane = threadIdx.x & 63, w = threadIdx.x >> 6;
    int rw = w >> 1, cw = w & 1;
    int q = lane >> 4, l16 = lane & 15;
    int row0 = bx * 128 + rw * 64;
    int col0 = cw * 64;
    bf8 z; for (int t = 0; t < 8; ++t) z[t] = 0;

    bf8 bfr[4][4];
#pragma unroll
    for (int kk = 0; kk < 4; ++kk)
#pragma unroll
        for (int j = 0; j < 4; ++j)
            bfr[kk][j] = *(const bf8*)(Wt + (size_t)(col0 + j * 16 + l16) * K + kk * 32 + q * 8);

    f4 acc[4][4];
#pragma unroll
    for (int i = 0; i < 4; ++i)
#pragma unroll
        for (int j = 0; j < 4; ++j) acc[i][j] = (f4)(0.f);

#pragma unroll
    for (int kk = 0; kk < 4; ++kk) {
        bf8 af[4];
#pragma unroll
        for (int i = 0; i < 4; ++i) {
            int r = row0 + i * 16 + l16;
            af[i] = (r < n) ? *(const bf8*)(A + (size_t)r * K + kk * 32 + q * 8) : z;
        }
#pragma unroll
        for (int i = 0; i < 4; ++i)
#pragma unroll
            for (int j = 0; j < 4; ++j)
                acc[i][j] = __builtin_amdgcn_mfma_f32_16x16x32_bf16(af[i], bfr[kk][j], acc[i][j], 0, 0, 0);
    }
#pragma unroll
    for (int i = 0; i < 4; ++i) {
        int gr0 = row0 + i * 16 + q * 4;
#pragma unroll
        for (int j = 0; j < 4; ++j) {
            int gc = col0 + j * 16 + l16;
            float bv = bias[gc];
#pragma unroll
            for (int r = 0; r < 4; ++r) {
                int gr = gr0 + r;
                if (gr < n) outb[(size_t)gr * HID + gc] = f2b(acc[i][j][r] + bv);
            }
        }
    }
}

// ---------------------------------------------------------------- GATv2 attention (packed-f32 VALU, bf16 residual)
__global__ __launch_bounds__(256) void k_attn(const ushort_t* __restrict__ xl,
                                              const ushort_t* __restrict__ xr,
                                              ushort_t* __restrict__ hb,
                                              const int* __restrict__ offs,
                                              const int2* __restrict__ csr,
                                              const float* __restrict__ We,
                                              const float* __restrict__ att,
                                              const float* __restrict__ gbias,
                                              const float* __restrict__ g,
                                              const float* __restrict__ b) {
    int wid = (blockIdx.x * 256 + threadIdx.x) >> 6;
    int lane = threadIdx.x & 63;
    if (wid >= NN) return;
    int hd = lane & 15;          // head index (16 heads; DH=8 in-lane)
    int grp = lane >> 4;         // edge subgroup 0..3
    int dbase = hd * 8;
    size_t base = (size_t)wid * HID;

    f2 xr2[4], at2[4], we2[4];
    {
        u4 uxr = *(const u4*)(xr + base + dbase);
        xr2[0] = b2f2v(uxr.x); xr2[1] = b2f2v(uxr.y);
        xr2[2] = b2f2v(uxr.z); xr2[3] = b2f2v(uxr.w);
        f4 a0 = *(const f4*)(att + dbase), a1 = *(const f4*)(att + dbase + 4);
        at2[0].x = a0.x; at2[0].y = a0.y; at2[1].x = a0.z; at2[1].y = a0.w;
        at2[2].x = a1.x; at2[2].y = a1.y; at2[3].x = a1.z; at2[3].y = a1.w;
        f4 w0 = *(const f4*)(We + dbase), w1 = *(const f4*)(We + dbase + 4);
        we2[0].x = w0.x; we2[0].y = w0.y; we2[1].x = w0.z; we2[1].y = w0.w;
        we2[2].x = w1.x; we2[2].y = w1.y; we2[3].x = w1.z; we2[3].y = w1.w;
    }
    int p0 = offs[wid], p1 = offs[wid + 1];
    float Z = 0.f;
    f2 acc2[4];
#pragma unroll
    for (int q = 0; q < 4; ++q) { acc2[q].x = 0.f; acc2[q].y = 0.f; }

#define QUAD(EJ, MASKED)                                                        \
    {                                                                           \
        int ei_ = (EJ) + grp;                                                   \
        int s_ = __shfl(sv, ei_);                                               \
        float ea_ = __shfl(evl, ei_);                                           \
        bool val_ = MASKED ? (ei_ < mm) : true;                                 \
        u4 ux_ = *(const u4*)(xl + (size_t)s_ * HID + dbase);                   \
        f2 x2_[4];                                                              \
        x2_[0] = b2f2v(ux_.x); x2_[1] = b2f2v(ux_.y);                           \
        x2_[2] = b2f2v(ux_.z); x2_[3] = b2f2v(ux_.w);                           \
        f2 lg2_; lg2_.x = 0.f; lg2_.y = 0.f;                                    \
        _Pragma("unroll")                                                       \
        for (int q_ = 0; q_ < 4; ++q_) {                                        \
            f2 t_ = (x2_[q_] + xr2[q_]) + ea_ * we2[q_];                        \
            t_ = max2(t_, t_ * 0.2f);                                           \
            lg2_ += at2[q_] * t_;                                               \
        }                                                                       \
        float w_ = val_ ? __expf(lg2_.x + lg2_.y) : 0.f;                        \
        Z += w_;                                                                \
        _Pragma("unroll")                                                       \
        for (int q_ = 0; q_ < 4; ++q_) acc2[q_] += w_ * x2_[q_];                \
    }

    for (int cb = p0; cb < p1; cb += 64) {
        int mm = min(64, p1 - cb);
        int2 m2 = (lane < mm) ? csr[cb + lane] : make_int2(0, 0);
        int sv = m2.x;
        float evl = __int_as_float(m2.y);
        int j = 0;
        for (; j + 8 <= mm; j += 8) { QUAD(j, false) QUAD(j + 4, false) }
        for (; j < mm; j += 4) QUAD(j, true)
    }
#undef QUAD

    Z += __shfl_xor(Z, 16); Z += __shfl_xor(Z, 32);
#pragma unroll
    for (int q = 0; q < 4; ++q) {
        acc2[q].x += __shfl_xor(acc2[q].x, 16);
        acc2[q].x += __shfl_xor(acc2[q].x, 32);
        acc2[q].y += __shfl_xor(acc2[q].y, 16);
        acc2[q].y += __shfl_xor(acc2[q].y, 32);
    }
    float inv = 1.f / (Z + 1e-16f);
    float acc[8] = {acc2[0].x, acc2[0].y, acc2[1].x, acc2[1].y,
                    acc2[2].x, acc2[2].y, acc2[3].x, acc2[3].y};

    // residual (bf16 h) + LN over the 128 dims held by the 16 head-lanes
    u4 uh = *(const u4*)(hb + base + dbase);
    f2 hr0 = b2f2v(uh.x), hr1 = b2f2v(uh.y), hr2 = b2f2v(uh.z), hr3 = b2f2v(uh.w);
    float hres[8] = {hr0.x, hr0.y, hr1.x, hr1.y, hr2.x, hr2.y, hr3.x, hr3.y};
    f4 gb0 = *(const f4*)(gbias + dbase), gb1 = *(const f4*)(gbias + dbase + 4);
    float gb8[8] = {gb0.x, gb0.y, gb0.z, gb0.w, gb1.x, gb1.y, gb1.z, gb1.w};
    float o[8], sm = 0.f, sq = 0.f;
#pragma unroll
    for (int q = 0; q < 8; ++q) {
        o[q] = acc[q] * inv + gb8[q] + hres[q];
        sm += o[q]; sq += o[q] * o[q];
    }
#pragma unroll
    for (int k = 1; k < 16; k <<= 1) { sm += __shfl_xor(sm, k); sq += __shfl_xor(sq, k); }
    float mu = sm * (1.f / 128.f);
    float var = sq * (1.f / 128.f) - mu * mu;
    float rinv = rsqrtf(var + 1e-5f);
    f4 g0 = *(const f4*)(g + dbase), g1 = *(const f4*)(g + dbase + 4);
    float g8[8] = {g0.x, g0.y, g0.z, g0.w, g1.x, g1.y, g1.z, g1.w};
    f4 b0 = *(const f4*)(b + dbase), b1 = *(const f4*)(b + dbase + 4);
    float b8[8] = {b0.x, b0.y, b0.z, b0.w, b1.x, b1.y, b1.z, b1.w};
    float v8[8];
#pragma unroll
    for (int q = 0; q < 8; ++q) v8[q] = (o[q] - mu) * rinv * g8[q] + b8[q];
    if (grp == 0) {
        u4 hu;
        hu.x = pk2(v8[0], v8[1]); hu.y = pk2(v8[2], v8[3]);
        hu.z = pk2(v8[4], v8[5]); hu.w = pk2(v8[6], v8[7]);
        *(u4*)(hb + base + dbase) = hu;
    }
}

// ---------------------------------------------------------------- per-store partial sums (bf16 h, no global atomics)
__global__ __launch_bounds__(256) void k_store_sum(const ushort_t* __restrict__ hb,
                                                   const int* __restrict__ mask,
                                                   float* __restrict__ psums,   // [SSB][NSTORE*HID]
                                                   int* __restrict__ pcnts) {   // [SSB][NSTORE]
    __shared__ float ls[NSTORE * HID];
    __shared__ int lc[NSTORE];
    int t = threadIdx.x, bidx = blockIdx.x;
    for (int i = t; i < NSTORE * HID; i += 256) ls[i] = 0.f;
    if (t < NSTORE) lc[t] = 0;
    __syncthreads();
    int wid = bidx * 4 + (t >> 6);
    int lane = t & 63;
    int nw = SSB * 4;
    int d0 = lane * 2;
    for (int node = wid; node < NN; node += nw) {
        int s = mask[node];
        unsigned int hv = ((const unsigned int*)(hb + (size_t)node * HID))[lane];
        f2 v = b2f2v(hv);
        atomicAdd(&ls[s * HID + d0], v.x);
        atomicAdd(&ls[s * HID + d0 + 1], v.y);
        if (lane == 0) atomicAdd(&lc[s], 1);
    }
    __syncthreads();
    for (int i = t; i < NSTORE * HID; i += 256) psums[(size_t)bidx * (NSTORE * HID) + i] = ls[i];
    if (t < NSTORE) pcnts[bidx * NSTORE + t] = lc[t];
}

// ---------------------------------------------------------------- gate (parallel reduction of partials)
__global__ __launch_bounds__(256) void k_gate(const float* __restrict__ psums,
                                              const int* __restrict__ pcnts,
                                              const float* __restrict__ ctxW,
                                              const float* __restrict__ ctxb,
                                              float* __restrict__ gm) {
    __shared__ float h1[HID];
    __shared__ float mloc[HID];
    __shared__ int cw4[4];
    int s = blockIdx.x, t = threadIdx.x;
    int d = t & 127, half = t >> 7;
    float s0 = 0.f, s1 = 0.f, s2 = 0.f, s3 = 0.f;
    for (int b = half * 4; b < SSB; b += 8) {
        s0 += psums[(size_t)(b + 0) * (NSTORE * HID) + s * HID + d];
        s1 += psums[(size_t)(b + 1) * (NSTORE * HID) + s * HID + d];
        s2 += psums[(size_t)(b + 2) * (NSTORE * HID) + s * HID + d];
        s3 += psums[(size_t)(b + 3) * (NSTORE * HID) + s * HID + d];
    }
    float sum = (s0 + s1) + (s2 + s3);
    int c = pcnts[t * NSTORE + s] + pcnts[(t + 256) * NSTORE + s];
#pragma unroll
    for (int k = 1; k < 64; k <<= 1) c += __shfl_xor(c, k);
    if ((t & 63) == 0) cw4[t >> 6] = c;
    if (half) h1[d] = sum;
    __syncthreads();
    if (half == 0) {
        float tot = sum + h1[d];
        float cnt = fmaxf((float)(cw4[0] + cw4[1] + cw4[2] + cw4[3]), 1.f);
        mloc[d] = tot / cnt;
    }
    __syncthreads();
    if (half == 0) {
        float acc = ctxb[d];
        for (int j = 0; j < HID; ++j) acc += mloc[j] * ctxW[j * HID + d];
        float gate = 1.f / (1.f + __expf(-acc));
        gm[s * HID + d] = gate * mloc[d];
    }
}

// ---------------------------------------------------------------- final: out = LN(hb + gm[store])
__global__ __launch_bounds__(256) void k_final(const ushort_t* __restrict__ hb,
                                               const int* __restrict__ mask,
                                               const float* __restrict__ gm,
                                               const float* __restrict__ g,
                                               const float* __restrict__ b,
                                               float* __restrict__ out) {
    int wid = (blockIdx.x * 256 + threadIdx.x) >> 6;
    int lane = threadIdx.x & 63;
    if (wid >= NN) return;
    size_t base = (size_t)wid * HID;
    int s = mask[wid];
    int d0 = lane * 2, d1 = d0 + 1;
    unsigned int hv = ((const unsigned int*)(hb + base))[lane];
    f2 hvv = b2f2v(hv);
    float v0 = hvv.x + gm[s * HID + d0];
    float v1 = hvv.y + gm[s * HID + d1];
    float sm = v0 + v1, sq = v0 * v0 + v1 * v1;
#pragma unroll
    for (int k = 1; k < 64; k <<= 1) { sm += __shfl_xor(sm, k); sq += __shfl_xor(sq, k); }
    float mu = sm * (1.f / 128.f);
    float var = sq * (1.f / 128.f) - mu * mu;
    float r = rsqrtf(var + 1e-5f);
    out[base + d0] = (v0 - mu) * r * g[d0] + b[d0];
    out[base + d1] = (v1 - mu) * r * g[d1] + b[d1];
}

// ---------------------------------------------------------------- launch
extern "C" void kernel_launch(void* const* d_in, const int* in_sizes, int n_in,
                              void* d_out, int out_size, void* d_ws, size_t ws_size,
                              hipStream_t stream) {
    const float* x      = (const float*)d_in[0];
    const int*   ei     = (const int*)d_in[1];
    const float* ew     = (const float*)d_in[2];
    const int*   smask  = (const int*)d_in[3];
    const float* inW    = (const float*)d_in[4];
    const float* inb    = (const float*)d_in[5];
    const float* ing    = (const float*)d_in[6];
    const float* inbeta = (const float*)d_in[7];
    const float* gWl    = (const float*)d_in[8];
    const float* gbl    = (const float*)d_in[9];
    const float* gWr    = (const float*)d_in[10];
    const float* gbr    = (const float*)d_in[11];
    const float* gWe    = (const float*)d_in[12];
    const float* gatt   = (const float*)d_in[13];
    const float* gbias  = (const float*)d_in[14];
    const float* blkg   = (const float*)d_in[15];
    const float* blkb   = (const float*)d_in[16];
    const float* ctxW   = (const float*)d_in[17];
    const float* ctxb   = (const float*)d_in[18];
    const float* fing   = (const float*)d_in[19];
    const float* finb   = (const float*)d_in[20];
    float* out = (float*)d_out;

    float* ws = (float*)d_ws;
    size_t o = 0;
    int2*     csr    = (int2*)(ws + o);     o += (size_t)ET * 2;
    float*    gm     = ws + o;              o += NSTORE * HID;
    int*      offs   = (int*)(ws + o);      o += 50004;
    int*      rank   = (int*)(ws + o);      o += EE;
    ushort_t* xb     = (ushort_t*)(ws + o); o += (size_t)NN * 64 / 2;
    ushort_t* hb     = (ushort_t*)(ws + o); o += (size_t)NN * HID / 2;
    ushort_t* xlb    = (ushort_t*)(ws + o); o += (size_t)NN * HID / 2;
    ushort_t* xrb    = (ushort_t*)(ws + o); o += (size_t)NN * HID / 2;
    ushort_t* inWt   = (ushort_t*)(ws + o); o += 128 * 64 / 2;
    ushort_t* Wlt    = (ushort_t*)(ws + o); o += 3 * 128 * 128 / 2;
    ushort_t* Wrt    = (ushort_t*)(ws + o); o += 3 * 128 * 128 / 2;
    int*      bsum   = (int*)(ws + o);      o += 256;
    int*      bbase  = (int*)(ws + o);      o += 256;
    float*    psums  = ws + o;              o += (size_t)SSB * NSTORE * HID;
    int*      pcnts  = (int*)(ws + o);      o += SSB * NSTORE;
    if (o & 1) ++o;
    float*    zbase  = ws + o;
    u64*      packed = (u64*)(ws + o);      o += (size_t)NN * 2;
    size_t zbytes = (size_t)(NN * 2) * 4;

    hipMemsetAsync((void*)zbase, 0, zbytes, stream);

    const int WB = NN / 4;                    // wave-per-node kernels

    k_build<<<CNT_B + XCV_B + WCV_B + IWC_B, 256, 0, stream>>>(ei, ew, x, inW, gWl, gWr,
                                                               xb, inWt, Wlt, Wrt, packed, rank);
    k_inproj<<<GEMB, 256, 0, stream>>>(xb, inWt, inb, ing, inbeta, hb);
    k_psum<<<NBL, 256, 0, stream>>>(packed, bsum);
    k_scanb<<<1, 256, 0, stream>>>(bsum, bbase, offs);
    k_offs<<<NBL, 256, 0, stream>>>(packed, bbase, offs);

    for (int l = 0; l < 3; ++l) {
        int nb = 2 * GEMB + (l == 0 ? SCT_B : 0);   // layer 0 carries the CSR scatter blocks
        k_gemm2<<<nb, 256, 0, stream>>>(hb, Wlt + (size_t)l * HID * HID, Wrt + (size_t)l * HID * HID,
                                        gbl + l * HID, gbr + l * HID, xlb, xrb, NN,
                                        ei, ew, offs, packed, rank, csr);
        k_attn<<<WB, 256, 0, stream>>>(xlb, xrb, hb, offs, csr,
                                       gWe + l * HID, gatt + l * HID, gbias + l * HID,
                                       blkg + l * HID, blkb + l * HID);
    }

    k_store_sum<<<SSB, 256, 0, stream>>>(hb, smask, psums, pcnts);
    k_gate<<<NSTORE, 256, 0, stream>>>(psums, pcnts, ctxW, ctxb, gm);
    k_final<<<WB, 256, 0, stream>>>(hb, smask, gm, fing, finb, out);
}